// Round 7
// baseline (796.422 us; speedup 1.0000x reference)
//
#include <hip/hip_runtime.h>
#include <hip/hip_bf16.h>
#include <cstdint>
#include <cstddef>

#define N_NODES   100000
#define N_EDGES   3200000
#define IN_FEATS  256
#define N_HIDDEN  128
#define OUT_FEATS 40

#define NCHUNK    391             // scan chunks of 256 nodes (391*256 = 100096)
#define HISTB     391             // histogram blocks
#define N_TILES   3125            // 100000 / 32
#define TPB       2               // gemm0 tiles per block
#define G0BLKS    ((N_TILES + TPB - 1) / TPB)   // 1563

typedef __attribute__((ext_vector_type(8))) __bf16 bf16x8;
typedef __attribute__((ext_vector_type(4))) float f32x4;
typedef __attribute__((ext_vector_type(2))) float f32x2;

// packed fp32 FMA: acc(2 feats) += unpack2_bf16(u) * w2.
// Native vector arithmetic (no inline asm): clang contracts to v_pk_fma_f32
// or 2x v_fma_f32 under HIP's default -ffp-contract.
__device__ __forceinline__ void pkfma(f32x2& a, unsigned int u, f32x2 w2) {
  f32x2 b;
  b.x = __uint_as_float(u << 16);
  b.y = __uint_as_float(u & 0xFFFF0000u);
  a += b * w2;
}

// accumulate a uint4 (8 bf16 feats) into f32x2 A_[4]
#define ACC8P(A_, V_, W2_)   \
  pkfma(A_[0], (V_).x, W2_); \
  pkfma(A_[1], (V_).y, W2_); \
  pkfma(A_[2], (V_).z, W2_); \
  pkfma(A_[3], (V_).w, W2_);

// ---------------------------------------------------------------------------
// GEMM0 block body (MFMA): h0 = bf16(bf16(x) @ bf16(W0)), 32 rows x 128 cols
// per tile, TPB tiles/block. W0 pre-swizzled as bf16 B-fragments (w0f).
// ---------------------------------------------------------------------------
__device__ __forceinline__ void gemm0_block(
    int bid, const float* __restrict__ x, const uint4* __restrict__ w0f,
    unsigned short* __restrict__ h0) {
  __shared__ __align__(16) unsigned short xb[32 * 264];
  const int tid  = threadIdx.x;
  const int lane = tid & 63;
  const int wave = tid >> 6;
  const int rb   = wave & 1;
  const int ch   = wave >> 1;
  const int l15  = lane & 15;
  const int g    = lane >> 4;

  bf16x8 Bf[4][8];
#pragma unroll
  for (int cb = 0; cb < 4; ++cb)
#pragma unroll
    for (int q = 0; q < 8; ++q)
      Bf[cb][q] = __builtin_bit_cast(bf16x8, w0f[((ch * 4 + cb) * 8 + q) * 64 + lane]);

  for (int t = 0; t < TPB; ++t) {
    const int tile = bid * TPB + t;
    if (tile >= N_TILES) break;
    const int row0 = tile * 32;
    __syncthreads();
    for (int i = tid; i < 32 * 128; i += 256) {
      const int row = i >> 7, kp = i & 127;
      const float2 v = *(const float2*)(x + (size_t)(row0 + row) * IN_FEATS + kp * 2);
      __hip_bfloat162 p;
      p.x = __float2bfloat16(v.x);
      p.y = __float2bfloat16(v.y);
      *(unsigned int*)&xb[row * 264 + kp * 2] = *(unsigned int*)&p;
    }
    __syncthreads();

    f32x4 acc[4];
#pragma unroll
    for (int cb = 0; cb < 4; ++cb) acc[cb] = (f32x4){0.f, 0.f, 0.f, 0.f};

#pragma unroll
    for (int q = 0; q < 8; ++q) {
      const bf16x8 a = *(const bf16x8*)&xb[(rb * 16 + l15) * 264 + q * 32 + g * 8];
      acc[0] = __builtin_amdgcn_mfma_f32_16x16x32_bf16(a, Bf[0][q], acc[0], 0, 0, 0);
      acc[1] = __builtin_amdgcn_mfma_f32_16x16x32_bf16(a, Bf[1][q], acc[1], 0, 0, 0);
      acc[2] = __builtin_amdgcn_mfma_f32_16x16x32_bf16(a, Bf[2][q], acc[2], 0, 0, 0);
      acc[3] = __builtin_amdgcn_mfma_f32_16x16x32_bf16(a, Bf[3][q], acc[3], 0, 0, 0);
    }

#pragma unroll
    for (int cb = 0; cb < 4; ++cb) {
      const int col = ch * 64 + cb * 16 + l15;
#pragma unroll
      for (int r = 0; r < 4; ++r) {
        const int row = row0 + rb * 16 + g * 4 + r;
        __hip_bfloat16 hb = __float2bfloat16(acc[cb][r]);
        h0[(size_t)row * N_HIDDEN + col] = *(unsigned short*)&hb;
      }
    }
  }
}

// ---------------------------------------------------------------------------
// hist_prep: blocks 0..HISTB-1 = node-level histogram (global atomics,
// cnt L2-resident); block HISTB = W1 pre-swizzle; HISTB+1..+8 = W0 pre-swizzle.
// ---------------------------------------------------------------------------
__global__ __launch_bounds__(256) void hist_prep_kernel(
    const int* __restrict__ dst, int* __restrict__ cnt,
    const float* __restrict__ W1, uint4* __restrict__ w1f,
    const float* __restrict__ W0, uint4* __restrict__ w0f) {
  const int tid = threadIdx.x;
  const int blk = blockIdx.x;

  if (blk >= HISTB) {
    if (blk == HISTB) {                   // W1 fragment converter (40 cols, pad)
      for (int t = tid; t < 3 * 4 * 64; t += 256) {
        const int ln  = t & 63;
        const int qq  = (t >> 6) & 3;
        const int nt  = t >> 8;
        const int l15 = ln & 15;
        const int gg  = ln >> 4;
        const int c   = nt * 16 + l15;
        const int k0  = qq * 32 + gg * 8;
        uint4 u;
        __hip_bfloat162 p;
#define W1AT(i_) ((c < OUT_FEATS) ? W1[(size_t)(k0 + (i_)) * OUT_FEATS + c] : 0.f)
        p.x = __float2bfloat16(W1AT(0)); p.y = __float2bfloat16(W1AT(1));
        u.x = *(unsigned int*)&p;
        p.x = __float2bfloat16(W1AT(2)); p.y = __float2bfloat16(W1AT(3));
        u.y = *(unsigned int*)&p;
        p.x = __float2bfloat16(W1AT(4)); p.y = __float2bfloat16(W1AT(5));
        u.z = *(unsigned int*)&p;
        p.x = __float2bfloat16(W1AT(6)); p.y = __float2bfloat16(W1AT(7));
        u.w = *(unsigned int*)&p;
#undef W1AT
        w1f[t] = u;
      }
    } else {                              // W0 fragment converter (128 cols)
      const int pb = blk - HISTB - 1;     // 0..7
      for (int fi = pb * 512 + tid; fi < pb * 512 + 512; fi += 256) {
        const int ln  = fi & 63;
        const int qq  = (fi >> 6) & 7;
        const int ct  = fi >> 9;
        const int col = ct * 16 + (ln & 15);
        const int k0  = qq * 32 + (ln >> 4) * 8;
        uint4 u;
        __hip_bfloat162 p;
        p.x = __float2bfloat16(W0[(size_t)(k0 + 0) * N_HIDDEN + col]);
        p.y = __float2bfloat16(W0[(size_t)(k0 + 1) * N_HIDDEN + col]);
        u.x = *(unsigned int*)&p;
        p.x = __float2bfloat16(W0[(size_t)(k0 + 2) * N_HIDDEN + col]);
        p.y = __float2bfloat16(W0[(size_t)(k0 + 3) * N_HIDDEN + col]);
        u.y = *(unsigned int*)&p;
        p.x = __float2bfloat16(W0[(size_t)(k0 + 4) * N_HIDDEN + col]);
        p.y = __float2bfloat16(W0[(size_t)(k0 + 5) * N_HIDDEN + col]);
        u.z = *(unsigned int*)&p;
        p.x = __float2bfloat16(W0[(size_t)(k0 + 6) * N_HIDDEN + col]);
        p.y = __float2bfloat16(W0[(size_t)(k0 + 7) * N_HIDDEN + col]);
        u.w = *(unsigned int*)&p;
        w0f[fi] = u;
      }
    }
    return;
  }

#pragma unroll 4
  for (int i = blk * 256 + tid; i < N_EDGES; i += HISTB * 256)
    atomicAdd(&cnt[dst[i]], 1);
}

// ---------------------------------------------------------------------------
// psum: per-chunk (256-node) totals of cnt. Tiny (400 KB read).
// ---------------------------------------------------------------------------
__global__ __launch_bounds__(256) void psum_kernel(
    const int* __restrict__ cnt, int* __restrict__ psum) {
  __shared__ int sh[256];
  const int b = blockIdx.x, t = threadIdx.x;
  const int n = b * 256 + t;
  sh[t] = (n < N_NODES) ? cnt[n] : 0;
  __syncthreads();
#pragma unroll
  for (int off = 128; off > 0; off >>= 1) {
    if (t < off) sh[t] += sh[t + off];
    __syncthreads();
  }
  if (t == 0) psum[b] = sh[0];
}

// ---------------------------------------------------------------------------
// node_scan: block b -> base = sum(psum[0..b-1]) (L2-hit), then LDS scan of
// its 256 node counts; writes offsets[] and curs[] (scatter cursors).
// ---------------------------------------------------------------------------
__device__ __forceinline__ void node_scan_block(
    int b, const int* __restrict__ cnt, const int* __restrict__ psum,
    int* __restrict__ offsets, int* __restrict__ curs) {
  __shared__ int sh[256];
  __shared__ int pr[256];
  const int t = threadIdx.x;

  int v = (t < b) ? psum[t] : 0;
  if (t + 256 < b) v += psum[t + 256];
  sh[t] = v;
  __syncthreads();
#pragma unroll
  for (int off = 128; off > 0; off >>= 1) {
    if (t < off) sh[t] += sh[t + off];
    __syncthreads();
  }
  const int base = sh[0];

  const int node = b * 256 + t;
  const int c = (node < N_NODES) ? cnt[node] : 0;
  pr[t] = c;
  __syncthreads();
  for (int off = 1; off < 256; off <<= 1) {
    int u = (t >= off) ? pr[t - off] : 0;
    __syncthreads();
    pr[t] += u;
    __syncthreads();
  }
  const int excl = base + pr[t] - c;
  if (node < N_NODES) { offsets[node] = excl; curs[node] = excl; }
  if (b == NCHUNK - 1 && t == 255) offsets[N_NODES] = base + pr[255];
}

// Combo: blocks 0..390 = node scans, blocks 391.. = gemm0.
__global__ __launch_bounds__(256) void nscan_gemm0_kernel(
    const int* __restrict__ cnt, const int* __restrict__ psum,
    int* __restrict__ offsets, int* __restrict__ curs,
    const float* __restrict__ x, const uint4* __restrict__ w0f,
    unsigned short* __restrict__ h0) {
  if (blockIdx.x < NCHUNK) node_scan_block(blockIdx.x, cnt, psum, offsets, curs);
  else                     gemm0_block(blockIdx.x - NCHUNK, x, w0f, h0);
}

// ---------------------------------------------------------------------------
// Direct scatter: pos = atomicAdd(curs[dst]) (L2-resident 400 KB), write edge
// to its final CSR slot. Replaces p1scatter+p2place (no bucketed round-trip,
// no second pass). srcw order within a node is arbitrary (sum commutes).
// ---------------------------------------------------------------------------
__global__ __launch_bounds__(256) void scatter_kernel(
    const int* __restrict__ src, const int* __restrict__ dst,
    const float* __restrict__ ew, int* __restrict__ curs,
    int2* __restrict__ srcw) {
#pragma unroll 4
  for (int i = blockIdx.x * 256 + threadIdx.x; i < N_EDGES;
       i += gridDim.x * 256) {
    const int d = dst[i];
    const int pos = atomicAdd(&curs[d], 1);
    srcw[pos] = make_int2(src[i], __float_as_int(ew[i]));
  }
}

// ---------------------------------------------------------------------------
// Fused gather0 + bias + ReLU + MFMA GEMM1 epilogue.
// Gather: 16 lanes/edge, dwordx4, 2 groups in flight, packed f32x2 FMA.
// hs rows padded to 132 floats (epilogue LDS reads: 4-way -> ~conflict-free).
// ---------------------------------------------------------------------------
__global__ __launch_bounds__(256) void gather0_gemm1_kernel(
    const uint4* __restrict__ h0q, const int2* __restrict__ srcw,
    const int* __restrict__ offsets, const float* __restrict__ b0,
    const uint4* __restrict__ w1f, unsigned short* __restrict__ h1a,
    unsigned short* __restrict__ h1c) {
  __shared__ float hs[4][132];
  const int wave = threadIdx.x >> 6;
  const int lane = threadIdx.x & 63;
  const int node = blockIdx.x * 4 + wave;
  const int q    = lane >> 4;       // edge slot 0..3 within a 4-edge group
  const int fl   = lane & 15;       // feature chunk: feats [fl*8, fl*8+8)

  const int beg = __builtin_amdgcn_readfirstlane(offsets[node]);
  const int end = __builtin_amdgcn_readfirstlane(offsets[node + 1]);

  f32x2 acc[4];
#pragma unroll
  for (int i = 0; i < 4; ++i) acc[i] = (f32x2){0.f, 0.f};

  if (end > beg) {
    const int e1 = end - 1;
    int2 sA = srcw[min(beg + q, e1)];
    int2 sB = srcw[min(beg + 4 + q, e1)];
    for (int j = beg; j < end; j += 8) {
      const float wA = (j + q < end)     ? __int_as_float(sA.y) : 0.f;
      const float wB = (j + 4 + q < end) ? __int_as_float(sB.y) : 0.f;
      const f32x2 w2A = {wA, wA};
      const f32x2 w2B = {wB, wB};
      const uint4 vA = h0q[(size_t)(unsigned)sA.x * 16 + fl];
      const uint4 vB = h0q[(size_t)(unsigned)sB.x * 16 + fl];
      const int jn = j + 8;
      if (jn < end) {                 // prefetch next groups' meta
        sA = srcw[min(jn + q, e1)];
        sB = srcw[min(jn + 4 + q, e1)];
      }
      ACC8P(acc, vA, w2A)
      ACC8P(acc, vB, w2B)
    }
  }

  // reduce the 4 edge-groups (lanes xor 16, 32 hold same features)
#pragma unroll
  for (int i = 0; i < 4; ++i) {
    acc[i].x += __shfl_xor(acc[i].x, 16);
    acc[i].x += __shfl_xor(acc[i].x, 32);
    acc[i].y += __shfl_xor(acc[i].y, 16);
    acc[i].y += __shfl_xor(acc[i].y, 32);
  }

  // bias + ReLU, one quarter-wave writes the 128-float row to LDS
  if (q == 0) {
    const int f0 = fl * 8;
    float t[8];
#pragma unroll
    for (int i = 0; i < 8; ++i) {
      const float a = ((i & 1) ? acc[i >> 1].y : acc[i >> 1].x);
      const float v = a + b0[f0 + i];
      t[i] = v > 0.f ? v : 0.f;
    }
    *(float4*)&hs[wave][f0]     = make_float4(t[0], t[1], t[2], t[3]);
    *(float4*)&hs[wave][f0 + 4] = make_float4(t[4], t[5], t[6], t[7]);
  }
  __syncthreads();

  // --- MFMA epilogue: h1 = hs(4x128) @ W1(128x40), waves 0-2 = N-tiles ---
  if (wave < 3) {
    const int l15 = lane & 15;
    const int g   = lane >> 4;
    f32x4 c = {0.f, 0.f, 0.f, 0.f};
#pragma unroll
    for (int qq = 0; qq < 4; ++qq) {
      uint4 ua = make_uint4(0, 0, 0, 0);
      if (l15 < 4) {                      // A rows 0-3 = this block's nodes
        const float* hrow = &hs[l15][qq * 32 + g * 8];
        __hip_bfloat162 p;
        p.x = __float2bfloat16(hrow[0]); p.y = __float2bfloat16(hrow[1]);
        ua.x = *(unsigned int*)&p;
        p.x = __float2bfloat16(hrow[2]); p.y = __float2bfloat16(hrow[3]);
        ua.y = *(unsigned int*)&p;
        p.x = __float2bfloat16(hrow[4]); p.y = __float2bfloat16(hrow[5]);
        ua.z = *(unsigned int*)&p;
        p.x = __float2bfloat16(hrow[6]); p.y = __float2bfloat16(hrow[7]);
        ua.w = *(unsigned int*)&p;
      }
      const uint4 ub = w1f[(wave * 4 + qq) * 64 + lane];
      c = __builtin_amdgcn_mfma_f32_16x16x32_bf16(
            __builtin_bit_cast(bf16x8, ua), __builtin_bit_cast(bf16x8, ub),
            c, 0, 0, 0);
    }
    // C: col = lane&15 (feat within tile), row = (lane>>4)*4 + r (node)
    if (g == 0) {
#pragma unroll
      for (int r = 0; r < 4; ++r) {
        const int nodeR = blockIdx.x * 4 + r;
        const int f = wave * 16 + l15;
        __hip_bfloat16 hb = __float2bfloat16(c[r]);
        const unsigned short v16 = *(unsigned short*)&hb;
        if (f < 32)              h1a[(size_t)nodeR * 32 + f] = v16;
        else if (f < OUT_FEATS)  h1c[(size_t)nodeR * 8 + (f - 32)] = v16;
      }
    }
  }
}

// ---------------------------------------------------------------------------
// Fused gather1 + bias + log_softmax, split h1 (64 B + 16 B rows), packed FMA.
// ---------------------------------------------------------------------------
__global__ __launch_bounds__(256) void gather1_lsm_kernel(
    const uint4* __restrict__ h1aq, const uint4* __restrict__ h1cq,
    const int2* __restrict__ srcw, const int* __restrict__ offsets,
    const float* __restrict__ b1, float* __restrict__ out) {
  const int wave = threadIdx.x >> 6;
  const int lane = threadIdx.x & 63;
  const int node = blockIdx.x * 4 + wave;
  const int g  = lane >> 2;         // edge slot 0..15 within a 16-edge group
  const int fl = lane & 3;          // feats [fl*8, fl*8+8) of h1a

  const int beg = __builtin_amdgcn_readfirstlane(offsets[node]);
  const int end = __builtin_amdgcn_readfirstlane(offsets[node + 1]);

  f32x2 a1[4], a2[4];
#pragma unroll
  for (int i = 0; i < 4; ++i) { a1[i] = (f32x2){0.f, 0.f}; a2[i] = (f32x2){0.f, 0.f}; }

  if (end > beg) {
    const int e1 = end - 1;
    int2 sA = srcw[min(beg + g, e1)];
    int2 sB = srcw[min(beg + 16 + g, e1)];
    for (int j = beg; j < end; j += 32) {
      const float wA = (j + g < end)      ? __int_as_float(sA.y) : 0.f;
      const float wB = (j + 16 + g < end) ? __int_as_float(sB.y) : 0.f;
      const f32x2 w2A = {wA, wA};
      const f32x2 w2B = {wB, wB};
      const uint4 vA = h1aq[(size_t)(unsigned)sA.x * 4 + fl];
      const uint4 vB = h1aq[(size_t)(unsigned)sB.x * 4 + fl];
      uint4 cA = make_uint4(0, 0, 0, 0), cB = make_uint4(0, 0, 0, 0);
      if (fl == 0) {
        cA = h1cq[(unsigned)sA.x];
        cB = h1cq[(unsigned)sB.x];
      }
      const int jn = j + 32;
      if (jn < end) {
        sA = srcw[min(jn + g, e1)];
        sB = srcw[min(jn + 16 + g, e1)];
      }
      ACC8P(a1, vA, w2A)
      ACC8P(a1, vB, w2B)
      if (fl == 0) {
        ACC8P(a2, cA, w2A)
        ACC8P(a2, cB, w2B)
      }
    }
  }

  // reduce across the 16 edge-groups; broadcast a2 across fl via xor 1,2
  float o[8], o2[8];
#pragma unroll
  for (int i = 0; i < 4; ++i) {
    float x0 = a1[i].x, y0 = a1[i].y, x2 = a2[i].x, y2 = a2[i].y;
    x0 += __shfl_xor(x0, 4);  x0 += __shfl_xor(x0, 8);
    x0 += __shfl_xor(x0, 16); x0 += __shfl_xor(x0, 32);
    y0 += __shfl_xor(y0, 4);  y0 += __shfl_xor(y0, 8);
    y0 += __shfl_xor(y0, 16); y0 += __shfl_xor(y0, 32);
    x2 += __shfl_xor(x2, 4);  x2 += __shfl_xor(x2, 8);
    x2 += __shfl_xor(x2, 16); x2 += __shfl_xor(x2, 32);
    x2 += __shfl_xor(x2, 1);  x2 += __shfl_xor(x2, 2);
    y2 += __shfl_xor(y2, 4);  y2 += __shfl_xor(y2, 8);
    y2 += __shfl_xor(y2, 16); y2 += __shfl_xor(y2, 32);
    y2 += __shfl_xor(y2, 1);  y2 += __shfl_xor(y2, 2);
    o[2 * i] = x0; o[2 * i + 1] = y0;
    o2[2 * i] = x2; o2[2 * i + 1] = y2;
  }

  const int f0 = fl * 8;
  float m = -INFINITY;
#pragma unroll
  for (int i = 0; i < 8; ++i) {
    o[i]  += b1[f0 + i];
    o2[i] += b1[32 + i];
    m = fmaxf(m, o[i]);
    m = fmaxf(m, o2[i]);
  }
  m = fmaxf(m, __shfl_xor(m, 1));
  m = fmaxf(m, __shfl_xor(m, 2));

  float s = 0.f;
#pragma unroll
  for (int i = 0; i < 8; ++i) s += expf(o[i] - m);
  s += __shfl_xor(s, 1);
  s += __shfl_xor(s, 2);
  float s2 = 0.f;
#pragma unroll
  for (int i = 0; i < 8; ++i) s2 += expf(o2[i] - m);
  s += s2;

  const float lse = m + logf(s);
  if (lane < 4) {
    float* op = out + (size_t)node * OUT_FEATS + fl * 8;
    *(float4*)op       = make_float4(o[0] - lse, o[1] - lse,
                                     o[2] - lse, o[3] - lse);
    *(float4*)(op + 4) = make_float4(o[4] - lse, o[5] - lse,
                                     o[6] - lse, o[7] - lse);
  } else if (lane == 4) {
    float* op = out + (size_t)node * OUT_FEATS + 32;
    *(float4*)op       = make_float4(o2[0] - lse, o2[1] - lse,
                                     o2[2] - lse, o2[3] - lse);
    *(float4*)(op + 4) = make_float4(o2[4] - lse, o2[5] - lse,
                                     o2[6] - lse, o2[7] - lse);
  }
}

// ---------------------------------------------------------------------------
extern "C" void kernel_launch(void* const* d_in, const int* in_sizes, int n_in,
                              void* d_out, int out_size, void* d_ws, size_t ws_size,
                              hipStream_t stream) {
  const float* x   = (const float*)d_in[0];
  const float* W0  = (const float*)d_in[1];
  const float* b0  = (const float*)d_in[2];
  const float* W1  = (const float*)d_in[3];
  const float* b1  = (const float*)d_in[4];
  const float* ew  = (const float*)d_in[5];
  const int*   src = (const int*)d_in[6];
  const int*   dst = (const int*)d_in[7];
  float* out = (float*)d_out;

  // Workspace layout, peak ~60.5 MB (ws >= 102.4 MB):
  //   h0b2     [0,          25,600,000)   N*128 bf16
  //   srcw     [25,600,000, 51,200,000)   E int2, dst-CSR order
  //   offsets  [51,200,000, 51,600,016)   N+1 int
  //   cnt      [51,600,016, 52,000,016)   N int (node histogram)
  //   curs     [52,000,016, 52,400,016)   N int (scatter cursors)
  //   psum     [52,400,016, 52,401,600)   NCHUNK int (chunk totals)
  //   h1a      [52,401,600, 58,801,600)   N*32 bf16 (64 B rows, feats 0-31)
  //   h1c      [58,801,600, 60,401,600)   N*8  bf16 (16 B rows, feats 32-39)
  //   w1f      [60,401,600, 60,413,888)   768 uint4 (pre-swizzled W1 B-frags)
  //   w0f      [60,413,888, 60,479,424)   4096 uint4 (pre-swizzled W0 B-frags)
  char* ws = (char*)d_ws;
  unsigned int* h0b2 = (unsigned int*)(ws);
  int2* srcw     = (int2*)(ws + 25600000);
  int*  offsets  = (int*)(ws + 51200000);
  int*  cnt      = (int*)(ws + 51600016);
  int*  curs     = (int*)(ws + 52000016);
  int*  psum     = (int*)(ws + 52400016);
  unsigned short* h1a = (unsigned short*)(ws + 52401600);
  unsigned short* h1c = (unsigned short*)(ws + 58801600);
  uint4* w1f     = (uint4*)(ws + 60401600);
  uint4* w0f     = (uint4*)(ws + 60413888);

  hipMemsetAsync(cnt, 0, N_NODES * sizeof(int), stream);
  hist_prep_kernel<<<HISTB + 9, 256, 0, stream>>>(dst, cnt, W1, w1f, W0, w0f);
  psum_kernel<<<NCHUNK, 256, 0, stream>>>(cnt, psum);
  nscan_gemm0_kernel<<<NCHUNK + G0BLKS, 256, 0, stream>>>(
      cnt, psum, offsets, curs, x, w0f, (unsigned short*)h0b2);
  scatter_kernel<<<782, 256, 0, stream>>>(src, dst, ew, curs, srcw);

  gather0_gemm1_kernel<<<N_NODES / 4, 256, 0, stream>>>(
      (const uint4*)h0b2, srcw, offsets, b0, (const uint4*)w1f, h1a, h1c);
  gather1_lsm_kernel<<<N_NODES / 4, 256, 0, stream>>>(
      (const uint4*)h1a, (const uint4*)h1c, srcw, offsets, b1, out);
}

// Round 8
// 511.991 us; speedup vs baseline: 1.5555x; 1.5555x over previous
//
#include <hip/hip_runtime.h>
#include <hip/hip_bf16.h>
#include <cstdint>
#include <cstddef>

#define N_NODES   100000
#define N_EDGES   3200000
#define IN_FEATS  256
#define N_HIDDEN  128
#define OUT_FEATS 40

// Bucket partition: bucket = dst >> 9 (512 nodes/bucket)
#define NB        196
#define EPB       8192
#define NBLK      391
#define HIST_M    (NB * NBLK)
#define N_TILES   3125            // 100000 / 32
#define TPB       2               // gemm0 tiles per block
#define G0BLKS    ((N_TILES + TPB - 1) / TPB)   // 1563

typedef __attribute__((ext_vector_type(8))) __bf16 bf16x8;
typedef __attribute__((ext_vector_type(4))) float f32x4;
typedef __attribute__((ext_vector_type(2))) float f32x2;

// packed fp32 FMA: acc(2 feats) += unpack2_bf16(u) * w2.
// Native vector arithmetic (no inline asm): clang contracts to v_pk_fma_f32.
__device__ __forceinline__ void pkfma(f32x2& a, unsigned int u, f32x2 w2) {
  f32x2 b;
  b.x = __uint_as_float(u << 16);
  b.y = __uint_as_float(u & 0xFFFF0000u);
  a += b * w2;
}

// accumulate a uint4 (8 bf16 feats) into f32x2 A_[4]
#define ACC8P(A_, V_, W2_)   \
  pkfma(A_[0], (V_).x, W2_); \
  pkfma(A_[1], (V_).y, W2_); \
  pkfma(A_[2], (V_).z, W2_); \
  pkfma(A_[3], (V_).w, W2_);

// ---------------------------------------------------------------------------
// GEMM0 block body (MFMA): h0 = bf16(bf16(x) @ bf16(W0)), 32 rows x 128 cols
// per tile, TPB tiles/block. W0 pre-swizzled as bf16 B-fragments (w0f).
// ---------------------------------------------------------------------------
__device__ __forceinline__ void gemm0_block(
    int bid, const float* __restrict__ x, const uint4* __restrict__ w0f,
    unsigned short* __restrict__ h0) {
  __shared__ __align__(16) unsigned short xb[32 * 264];
  const int tid  = threadIdx.x;
  const int lane = tid & 63;
  const int wave = tid >> 6;
  const int rb   = wave & 1;
  const int ch   = wave >> 1;
  const int l15  = lane & 15;
  const int g    = lane >> 4;

  bf16x8 Bf[4][8];
#pragma unroll
  for (int cb = 0; cb < 4; ++cb)
#pragma unroll
    for (int q = 0; q < 8; ++q)
      Bf[cb][q] = __builtin_bit_cast(bf16x8, w0f[((ch * 4 + cb) * 8 + q) * 64 + lane]);

  for (int t = 0; t < TPB; ++t) {
    const int tile = bid * TPB + t;
    if (tile >= N_TILES) break;
    const int row0 = tile * 32;
    __syncthreads();
    for (int i = tid; i < 32 * 128; i += 256) {
      const int row = i >> 7, kp = i & 127;
      const float2 v = *(const float2*)(x + (size_t)(row0 + row) * IN_FEATS + kp * 2);
      __hip_bfloat162 p;
      p.x = __float2bfloat16(v.x);
      p.y = __float2bfloat16(v.y);
      *(unsigned int*)&xb[row * 264 + kp * 2] = *(unsigned int*)&p;
    }
    __syncthreads();

    f32x4 acc[4];
#pragma unroll
    for (int cb = 0; cb < 4; ++cb) acc[cb] = (f32x4){0.f, 0.f, 0.f, 0.f};

#pragma unroll
    for (int q = 0; q < 8; ++q) {
      const bf16x8 a = *(const bf16x8*)&xb[(rb * 16 + l15) * 264 + q * 32 + g * 8];
      acc[0] = __builtin_amdgcn_mfma_f32_16x16x32_bf16(a, Bf[0][q], acc[0], 0, 0, 0);
      acc[1] = __builtin_amdgcn_mfma_f32_16x16x32_bf16(a, Bf[1][q], acc[1], 0, 0, 0);
      acc[2] = __builtin_amdgcn_mfma_f32_16x16x32_bf16(a, Bf[2][q], acc[2], 0, 0, 0);
      acc[3] = __builtin_amdgcn_mfma_f32_16x16x32_bf16(a, Bf[3][q], acc[3], 0, 0, 0);
    }

#pragma unroll
    for (int cb = 0; cb < 4; ++cb) {
      const int col = ch * 64 + cb * 16 + l15;
#pragma unroll
      for (int r = 0; r < 4; ++r) {
        const int row = row0 + rb * 16 + g * 4 + r;
        __hip_bfloat16 hb = __float2bfloat16(acc[cb][r]);
        h0[(size_t)row * N_HIDDEN + col] = *(unsigned short*)&hb;
      }
    }
  }
}

// ---------------------------------------------------------------------------
// Parallel 2-level scan: block b computes bucket b's base by reducing
// bsum[0..b-1] (L2-hit), then pair-scans its own 391 contiguous entries.
// ---------------------------------------------------------------------------
__device__ __forceinline__ void bucket_scan_block(
    int b, const int* __restrict__ bsum, int* __restrict__ histG) {
  __shared__ int sh[256];
  __shared__ int pr[256];
  const int t = threadIdx.x;

  sh[t] = (t < b) ? bsum[t] : 0;          // b <= 195 < 256
  __syncthreads();
#pragma unroll
  for (int off = 128; off > 0; off >>= 1) {
    if (t < off) sh[t] += sh[t + off];
    __syncthreads();
  }
  const int base = sh[0];

  const int row = b * NBLK;
  const int i0 = 2 * t, i1 = 2 * t + 1;
  int a = 0, c = 0;
  if (t < 196) {
    a = histG[row + i0];                  // i0 <= 390
    if (i1 < NBLK) c = histG[row + i1];
  }
  pr[t] = a + c;
  __syncthreads();
  for (int off = 1; off < 256; off <<= 1) {
    int v = (t >= off) ? pr[t - off] : 0;
    __syncthreads();
    pr[t] += v;
    __syncthreads();
  }
  if (t < 196) {
    const int ebase = (t > 0) ? pr[t - 1] : 0;
    histG[row + i0] = base + ebase;
    if (i1 < NBLK) histG[row + i1] = base + ebase + a;
  }
}

// Combo: blocks 0..195 = parallel bucket scans, blocks 196.. = gemm0.
__global__ __launch_bounds__(256) void bscan_gemm0_kernel(
    const int* __restrict__ bsum, int* __restrict__ histG,
    const float* __restrict__ x, const uint4* __restrict__ w0f,
    unsigned short* __restrict__ h0) {
  if (blockIdx.x < NB) bucket_scan_block(blockIdx.x, bsum, histG);
  else                 gemm0_block(blockIdx.x - NB, x, w0f, h0);
}

// ---------------------------------------------------------------------------
// p1hist: blocks 0..NBLK-1 = histogram (+ bsum accumulate);
// block NBLK = W1 pre-swizzle; blocks NBLK+1..NBLK+8 = W0 pre-swizzle.
// ---------------------------------------------------------------------------
__global__ __launch_bounds__(256) void p1hist_kernel(
    const int* __restrict__ dst, int* __restrict__ histG,
    const float* __restrict__ W1, uint4* __restrict__ w1f,
    const float* __restrict__ W0, uint4* __restrict__ w0f,
    int* __restrict__ bsum) {
  const int tid = threadIdx.x;
  const int blk = blockIdx.x;

  if (blk >= NBLK) {
    if (blk == NBLK) {                    // W1 fragment converter (40 cols, pad)
      for (int t = tid; t < 3 * 4 * 64; t += 256) {
        const int ln  = t & 63;
        const int qq  = (t >> 6) & 3;
        const int nt  = t >> 8;
        const int l15 = ln & 15;
        const int gg  = ln >> 4;
        const int c   = nt * 16 + l15;
        const int k0  = qq * 32 + gg * 8;
        uint4 u;
        __hip_bfloat162 p;
#define W1AT(i_) ((c < OUT_FEATS) ? W1[(size_t)(k0 + (i_)) * OUT_FEATS + c] : 0.f)
        p.x = __float2bfloat16(W1AT(0)); p.y = __float2bfloat16(W1AT(1));
        u.x = *(unsigned int*)&p;
        p.x = __float2bfloat16(W1AT(2)); p.y = __float2bfloat16(W1AT(3));
        u.y = *(unsigned int*)&p;
        p.x = __float2bfloat16(W1AT(4)); p.y = __float2bfloat16(W1AT(5));
        u.z = *(unsigned int*)&p;
        p.x = __float2bfloat16(W1AT(6)); p.y = __float2bfloat16(W1AT(7));
        u.w = *(unsigned int*)&p;
#undef W1AT
        w1f[t] = u;
      }
    } else {                              // W0 fragment converter (128 cols)
      const int pb = blk - NBLK - 1;      // 0..7
      for (int fi = pb * 512 + tid; fi < pb * 512 + 512; fi += 256) {
        const int ln  = fi & 63;
        const int qq  = (fi >> 6) & 7;
        const int ct  = fi >> 9;
        const int col = ct * 16 + (ln & 15);
        const int k0  = qq * 32 + (ln >> 4) * 8;
        uint4 u;
        __hip_bfloat162 p;
        p.x = __float2bfloat16(W0[(size_t)(k0 + 0) * N_HIDDEN + col]);
        p.y = __float2bfloat16(W0[(size_t)(k0 + 1) * N_HIDDEN + col]);
        u.x = *(unsigned int*)&p;
        p.x = __float2bfloat16(W0[(size_t)(k0 + 2) * N_HIDDEN + col]);
        p.y = __float2bfloat16(W0[(size_t)(k0 + 3) * N_HIDDEN + col]);
        u.y = *(unsigned int*)&p;
        p.x = __float2bfloat16(W0[(size_t)(k0 + 4) * N_HIDDEN + col]);
        p.y = __float2bfloat16(W0[(size_t)(k0 + 5) * N_HIDDEN + col]);
        u.z = *(unsigned int*)&p;
        p.x = __float2bfloat16(W0[(size_t)(k0 + 6) * N_HIDDEN + col]);
        p.y = __float2bfloat16(W0[(size_t)(k0 + 7) * N_HIDDEN + col]);
        u.w = *(unsigned int*)&p;
        w0f[fi] = u;
      }
    }
    return;
  }

  __shared__ int lh[NB];
  for (int i = tid; i < NB; i += 256) lh[i] = 0;
  __syncthreads();

  const int e0 = blk * EPB;
  const int e1 = min(e0 + EPB, N_EDGES);
  for (int i = e0 + tid; i < e1; i += 256)
    atomicAdd(&lh[dst[i] >> 9], 1);
  __syncthreads();

  for (int i = tid; i < NB; i += 256) {
    histG[i * NBLK + blk] = lh[i];
    atomicAdd(&bsum[i], lh[i]);
  }
}

// ---------------------------------------------------------------------------
// p1scatter: LDS-staged, bucket-contiguous global writes (no random 8B
// scatter: R7 measured node-level direct scatter at 7.7x write amplification
// + cross-XCD atomic bounce = 290 us; this bucketed path is the fix).
// ---------------------------------------------------------------------------
__global__ __launch_bounds__(256) void p1scatter_kernel(
    const int* __restrict__ src, const int* __restrict__ dst,
    const float* __restrict__ ew, const int* __restrict__ histG,
    uint2* __restrict__ bucketed) {
  __shared__ uint2 stage[EPB];          // 64 KB
  __shared__ unsigned char sbkt[EPB];   // 8 KB
  __shared__ int lcnt[NB];
  __shared__ int lbase[NB];
  __shared__ int spart[256];
  const int tid = threadIdx.x;
  const int blk = blockIdx.x;
  const int e0 = blk * EPB;
  const int e1 = min(e0 + EPB, N_EDGES);

  for (int i = tid; i < NB; i += 256) lcnt[i] = 0;
  __syncthreads();

  for (int i = e0 + tid; i < e1; i += 256)
    atomicAdd(&lcnt[dst[i] >> 9], 1);
  __syncthreads();

  const int myv = (tid < NB) ? lcnt[tid] : 0;
  spart[tid] = myv;
  __syncthreads();
  for (int off = 1; off < 256; off <<= 1) {
    int u = (tid >= off) ? spart[tid - off] : 0;
    __syncthreads();
    spart[tid] += u;
    __syncthreads();
  }
  if (tid < NB) { lbase[tid] = spart[tid] - myv; lcnt[tid] = spart[tid] - myv; }
  __syncthreads();

  for (int i = e0 + tid; i < e1; i += 256) {
    const int d = dst[i];
    const int b = d >> 9;
    const int pos = atomicAdd(&lcnt[b], 1);
    stage[pos] = make_uint2((unsigned)src[i] | ((unsigned)(d & 511) << 17),
                            __float_as_uint(ew[i]));
    sbkt[pos] = (unsigned char)b;
  }
  __syncthreads();

  const int n = e1 - e0;
  for (int i = tid; i < n; i += 256) {
    const int b = sbkt[i];
    const int gpos = histG[b * NBLK + blk] + (i - lbase[b]);
    bucketed[gpos] = stage[i];
  }
}

__global__ __launch_bounds__(256) void p2place_kernel(
    const uint2* __restrict__ bucketed, const int* __restrict__ histG,
    int* __restrict__ offsets, int2* __restrict__ srcw) {
  __shared__ int cnt[512];
  __shared__ int part[256];
  const int t = threadIdx.x;
  const int b = blockIdx.x;
  const int node0 = b << 9;
  const int beg = histG[b * NBLK];
  const int end = (b == NB - 1) ? N_EDGES : histG[(b + 1) * NBLK];

  cnt[t] = 0; cnt[t + 256] = 0;
  __syncthreads();

  for (int j = beg + t; j < end; j += 256)
    atomicAdd(&cnt[bucketed[j].x >> 17], 1);
  __syncthreads();

  const int a0 = cnt[2 * t];
  const int a1 = cnt[2 * t + 1];
  part[t] = a0 + a1;
  __syncthreads();
  for (int off = 1; off < 256; off <<= 1) {
    int v = (t >= off) ? part[t - off] : 0;
    __syncthreads();
    part[t] += v;
    __syncthreads();
  }
  const int base = (t > 0) ? part[t - 1] : 0;

  const int o0 = beg + base;
  const int o1 = o0 + a0;
  cnt[2 * t]     = o0;
  cnt[2 * t + 1] = o1;
  const int n0 = node0 + 2 * t;
  if (n0 < N_NODES)     offsets[n0]     = o0;
  if (n0 + 1 < N_NODES) offsets[n0 + 1] = o1;
  if (b == NB - 1 && t == 0) offsets[N_NODES] = N_EDGES;
  __syncthreads();

  for (int j = beg + t; j < end; j += 256) {
    const uint2 en = bucketed[j];
    const int slot = atomicAdd(&cnt[en.x >> 17], 1);
    srcw[slot] = make_int2((int)(en.x & 0x1FFFFu), (int)en.y);
  }
}

// ---------------------------------------------------------------------------
// Fused gather0 + bias + ReLU + MFMA GEMM1 epilogue.
// Gather: 16 lanes/edge, dwordx4, 2 groups in flight, packed f32x2 FMA.
// hs rows padded to 132 floats (epilogue LDS reads ~conflict-free).
// ---------------------------------------------------------------------------
__global__ __launch_bounds__(256) void gather0_gemm1_kernel(
    const uint4* __restrict__ h0q, const int2* __restrict__ srcw,
    const int* __restrict__ offsets, const float* __restrict__ b0,
    const uint4* __restrict__ w1f, unsigned short* __restrict__ h1a,
    unsigned short* __restrict__ h1c) {
  __shared__ float hs[4][132];
  const int wave = threadIdx.x >> 6;
  const int lane = threadIdx.x & 63;
  const int node = blockIdx.x * 4 + wave;
  const int q    = lane >> 4;       // edge slot 0..3 within a 4-edge group
  const int fl   = lane & 15;       // feature chunk: feats [fl*8, fl*8+8)

  const int beg = __builtin_amdgcn_readfirstlane(offsets[node]);
  const int end = __builtin_amdgcn_readfirstlane(offsets[node + 1]);

  f32x2 acc[4];
#pragma unroll
  for (int i = 0; i < 4; ++i) acc[i] = (f32x2){0.f, 0.f};

  if (end > beg) {
    const int e1 = end - 1;
    int2 sA = srcw[min(beg + q, e1)];
    int2 sB = srcw[min(beg + 4 + q, e1)];
    for (int j = beg; j < end; j += 8) {
      const float wA = (j + q < end)     ? __int_as_float(sA.y) : 0.f;
      const float wB = (j + 4 + q < end) ? __int_as_float(sB.y) : 0.f;
      const f32x2 w2A = {wA, wA};
      const f32x2 w2B = {wB, wB};
      const uint4 vA = h0q[(size_t)(unsigned)sA.x * 16 + fl];
      const uint4 vB = h0q[(size_t)(unsigned)sB.x * 16 + fl];
      const int jn = j + 8;
      if (jn < end) {                 // prefetch next groups' meta
        sA = srcw[min(jn + q, e1)];
        sB = srcw[min(jn + 4 + q, e1)];
      }
      ACC8P(acc, vA, w2A)
      ACC8P(acc, vB, w2B)
    }
  }

  // reduce the 4 edge-groups (lanes xor 16, 32 hold same features)
#pragma unroll
  for (int i = 0; i < 4; ++i) {
    acc[i].x += __shfl_xor(acc[i].x, 16);
    acc[i].x += __shfl_xor(acc[i].x, 32);
    acc[i].y += __shfl_xor(acc[i].y, 16);
    acc[i].y += __shfl_xor(acc[i].y, 32);
  }

  // bias + ReLU, one quarter-wave writes the 128-float row to LDS
  if (q == 0) {
    const int f0 = fl * 8;
    float t[8];
#pragma unroll
    for (int i = 0; i < 8; ++i) {
      const float a = ((i & 1) ? acc[i >> 1].y : acc[i >> 1].x);
      const float v = a + b0[f0 + i];
      t[i] = v > 0.f ? v : 0.f;
    }
    *(float4*)&hs[wave][f0]     = make_float4(t[0], t[1], t[2], t[3]);
    *(float4*)&hs[wave][f0 + 4] = make_float4(t[4], t[5], t[6], t[7]);
  }
  __syncthreads();

  // --- MFMA epilogue: h1 = hs(4x128) @ W1(128x40), waves 0-2 = N-tiles ---
  if (wave < 3) {
    const int l15 = lane & 15;
    const int g   = lane >> 4;
    f32x4 c = {0.f, 0.f, 0.f, 0.f};
#pragma unroll
    for (int qq = 0; qq < 4; ++qq) {
      uint4 ua = make_uint4(0, 0, 0, 0);
      if (l15 < 4) {                      // A rows 0-3 = this block's nodes
        const float* hrow = &hs[l15][qq * 32 + g * 8];
        __hip_bfloat162 p;
        p.x = __float2bfloat16(hrow[0]); p.y = __float2bfloat16(hrow[1]);
        ua.x = *(unsigned int*)&p;
        p.x = __float2bfloat16(hrow[2]); p.y = __float2bfloat16(hrow[3]);
        ua.y = *(unsigned int*)&p;
        p.x = __float2bfloat16(hrow[4]); p.y = __float2bfloat16(hrow[5]);
        ua.z = *(unsigned int*)&p;
        p.x = __float2bfloat16(hrow[6]); p.y = __float2bfloat16(hrow[7]);
        ua.w = *(unsigned int*)&p;
      }
      const uint4 ub = w1f[(wave * 4 + qq) * 64 + lane];
      c = __builtin_amdgcn_mfma_f32_16x16x32_bf16(
            __builtin_bit_cast(bf16x8, ua), __builtin_bit_cast(bf16x8, ub),
            c, 0, 0, 0);
    }
    // C: col = lane&15 (feat within tile), row = (lane>>4)*4 + r (node)
    if (g == 0) {
#pragma unroll
      for (int r = 0; r < 4; ++r) {
        const int nodeR = blockIdx.x * 4 + r;
        const int f = wave * 16 + l15;
        __hip_bfloat16 hb = __float2bfloat16(c[r]);
        const unsigned short v16 = *(unsigned short*)&hb;
        if (f < 32)              h1a[(size_t)nodeR * 32 + f] = v16;
        else if (f < OUT_FEATS)  h1c[(size_t)nodeR * 8 + (f - 32)] = v16;
      }
    }
  }
}

// ---------------------------------------------------------------------------
// Fused gather1 + bias + log_softmax, split h1 (64 B + 16 B rows), packed FMA.
// ---------------------------------------------------------------------------
__global__ __launch_bounds__(256) void gather1_lsm_kernel(
    const uint4* __restrict__ h1aq, const uint4* __restrict__ h1cq,
    const int2* __restrict__ srcw, const int* __restrict__ offsets,
    const float* __restrict__ b1, float* __restrict__ out) {
  const int wave = threadIdx.x >> 6;
  const int lane = threadIdx.x & 63;
  const int node = blockIdx.x * 4 + wave;
  const int g  = lane >> 2;         // edge slot 0..15 within a 16-edge group
  const int fl = lane & 3;          // feats [fl*8, fl*8+8) of h1a

  const int beg = __builtin_amdgcn_readfirstlane(offsets[node]);
  const int end = __builtin_amdgcn_readfirstlane(offsets[node + 1]);

  f32x2 a1[4], a2[4];
#pragma unroll
  for (int i = 0; i < 4; ++i) { a1[i] = (f32x2){0.f, 0.f}; a2[i] = (f32x2){0.f, 0.f}; }

  if (end > beg) {
    const int e1 = end - 1;
    int2 sA = srcw[min(beg + g, e1)];
    int2 sB = srcw[min(beg + 16 + g, e1)];
    for (int j = beg; j < end; j += 32) {
      const float wA = (j + g < end)      ? __int_as_float(sA.y) : 0.f;
      const float wB = (j + 16 + g < end) ? __int_as_float(sB.y) : 0.f;
      const f32x2 w2A = {wA, wA};
      const f32x2 w2B = {wB, wB};
      const uint4 vA = h1aq[(size_t)(unsigned)sA.x * 4 + fl];
      const uint4 vB = h1aq[(size_t)(unsigned)sB.x * 4 + fl];
      uint4 cA = make_uint4(0, 0, 0, 0), cB = make_uint4(0, 0, 0, 0);
      if (fl == 0) {
        cA = h1cq[(unsigned)sA.x];
        cB = h1cq[(unsigned)sB.x];
      }
      const int jn = j + 32;
      if (jn < end) {
        sA = srcw[min(jn + g, e1)];
        sB = srcw[min(jn + 16 + g, e1)];
      }
      ACC8P(a1, vA, w2A)
      ACC8P(a1, vB, w2B)
      if (fl == 0) {
        ACC8P(a2, cA, w2A)
        ACC8P(a2, cB, w2B)
      }
    }
  }

  // reduce across the 16 edge-groups; broadcast a2 across fl via xor 1,2
  float o[8], o2[8];
#pragma unroll
  for (int i = 0; i < 4; ++i) {
    float x0 = a1[i].x, y0 = a1[i].y, x2 = a2[i].x, y2 = a2[i].y;
    x0 += __shfl_xor(x0, 4);  x0 += __shfl_xor(x0, 8);
    x0 += __shfl_xor(x0, 16); x0 += __shfl_xor(x0, 32);
    y0 += __shfl_xor(y0, 4);  y0 += __shfl_xor(y0, 8);
    y0 += __shfl_xor(y0, 16); y0 += __shfl_xor(y0, 32);
    x2 += __shfl_xor(x2, 4);  x2 += __shfl_xor(x2, 8);
    x2 += __shfl_xor(x2, 16); x2 += __shfl_xor(x2, 32);
    x2 += __shfl_xor(x2, 1);  x2 += __shfl_xor(x2, 2);
    y2 += __shfl_xor(y2, 4);  y2 += __shfl_xor(y2, 8);
    y2 += __shfl_xor(y2, 16); y2 += __shfl_xor(y2, 32);
    y2 += __shfl_xor(y2, 1);  y2 += __shfl_xor(y2, 2);
    o[2 * i] = x0; o[2 * i + 1] = y0;
    o2[2 * i] = x2; o2[2 * i + 1] = y2;
  }

  const int f0 = fl * 8;
  float m = -INFINITY;
#pragma unroll
  for (int i = 0; i < 8; ++i) {
    o[i]  += b1[f0 + i];
    o2[i] += b1[32 + i];
    m = fmaxf(m, o[i]);
    m = fmaxf(m, o2[i]);
  }
  m = fmaxf(m, __shfl_xor(m, 1));
  m = fmaxf(m, __shfl_xor(m, 2));

  float s = 0.f;
#pragma unroll
  for (int i = 0; i < 8; ++i) s += expf(o[i] - m);
  s += __shfl_xor(s, 1);
  s += __shfl_xor(s, 2);
  float s2 = 0.f;
#pragma unroll
  for (int i = 0; i < 8; ++i) s2 += expf(o2[i] - m);
  s += s2;

  const float lse = m + logf(s);
  if (lane < 4) {
    float* op = out + (size_t)node * OUT_FEATS + fl * 8;
    *(float4*)op       = make_float4(o[0] - lse, o[1] - lse,
                                     o[2] - lse, o[3] - lse);
    *(float4*)(op + 4) = make_float4(o[4] - lse, o[5] - lse,
                                     o[6] - lse, o[7] - lse);
  } else if (lane == 4) {
    float* op = out + (size_t)node * OUT_FEATS + 32;
    *(float4*)op       = make_float4(o2[0] - lse, o2[1] - lse,
                                     o2[2] - lse, o2[3] - lse);
    *(float4*)(op + 4) = make_float4(o2[4] - lse, o2[5] - lse,
                                     o2[6] - lse, o2[7] - lse);
  }
}

// ---------------------------------------------------------------------------
extern "C" void kernel_launch(void* const* d_in, const int* in_sizes, int n_in,
                              void* d_out, int out_size, void* d_ws, size_t ws_size,
                              hipStream_t stream) {
  const float* x   = (const float*)d_in[0];
  const float* W0  = (const float*)d_in[1];
  const float* b0  = (const float*)d_in[2];
  const float* W1  = (const float*)d_in[3];
  const float* b1  = (const float*)d_in[4];
  const float* ew  = (const float*)d_in[5];
  const int*   src = (const int*)d_in[6];
  const int*   dst = (const int*)d_in[7];
  float* out = (float*)d_out;

  // Workspace layout, peak ~85.6 MB (ws >= 102.4 MB):
  //   h0b2     [0,          25,600,000)   N*128 bf16
  //   srcw     [25,600,000, 51,200,000)   E int2, dst-sorted
  //   bucketed [51,200,000, 76,800,000)   E uint2, bucket-partitioned
  //   offsets  [76,800,000, 77,200,064)   N+1 int
  //   histG    [77,200,064, 77,506,624)   NB*NBLK int
  //   h1a      [77,506,624, 83,906,624)   N*32 bf16 (64 B rows, feats 0-31)
  //   h1c      [83,906,624, 85,506,624)   N*8  bf16 (16 B rows, feats 32-39)
  //   w1f      [85,506,624, 85,518,912)   768 uint4 (pre-swizzled W1 B-frags)
  //   w0f      [85,518,912, 85,584,448)   4096 uint4 (pre-swizzled W0 B-frags)
  //   bsum     [85,584,448, 85,585,232)   NB int (per-bucket edge totals)
  char* ws = (char*)d_ws;
  unsigned int* h0b2 = (unsigned int*)(ws);
  int2*  srcw     = (int2*)(ws + 25600000);
  uint2* bucketed = (uint2*)(ws + 51200000);
  int*   offsets  = (int*)(ws + 76800000);
  int*   histG    = (int*)(ws + 77200064);
  unsigned short* h1a = (unsigned short*)(ws + 77506624);
  unsigned short* h1c = (unsigned short*)(ws + 83906624);
  uint4* w1f      = (uint4*)(ws + 85506624);
  uint4* w0f      = (uint4*)(ws + 85518912);
  int*   bsum     = (int*)(ws + 85584448);

  hipMemsetAsync(bsum, 0, NB * sizeof(int), stream);
  p1hist_kernel<<<NBLK + 9, 256, 0, stream>>>(dst, histG, W1, w1f, W0, w0f, bsum);
  bscan_gemm0_kernel<<<NB + G0BLKS, 256, 0, stream>>>(
      bsum, histG, x, w0f, (unsigned short*)h0b2);
  p1scatter_kernel<<<NBLK, 256, 0, stream>>>(src, dst, ew, histG, bucketed);
  p2place_kernel<<<NB, 256, 0, stream>>>(bucketed, histG, offsets, srcw);

  gather0_gemm1_kernel<<<N_NODES / 4, 256, 0, stream>>>(
      (const uint4*)h0b2, srcw, offsets, b0, (const uint4*)w1f, h1a, h1c);
  gather1_lsm_kernel<<<N_NODES / 4, 256, 0, stream>>>(
      (const uint4*)h1a, (const uint4*)h1c, srcw, offsets, b1, out);
}

// Round 9
// 503.614 us; speedup vs baseline: 1.5814x; 1.0166x over previous
//
#include <hip/hip_runtime.h>
#include <hip/hip_bf16.h>
#include <cstdint>
#include <cstddef>

#define N_NODES   100000
#define N_EDGES   3200000
#define IN_FEATS  256
#define N_HIDDEN  128
#define OUT_FEATS 40

// Bucket partition: bucket = dst >> 9 (512 nodes/bucket)
#define NB        196
#define EPB       8192
#define NBLK      391
#define HIST_M    (NB * NBLK)
#define N_TILES   3125            // 100000 / 32
#define TPB       2               // gemm0 tiles per block
#define G0BLKS    ((N_TILES + TPB - 1) / TPB)   // 1563

typedef __attribute__((ext_vector_type(8))) __bf16 bf16x8;
typedef __attribute__((ext_vector_type(4))) float f32x4;
typedef __attribute__((ext_vector_type(2))) float f32x2;

// packed fp32 FMA: acc(2 feats) += unpack2_bf16(u) * w2.
// Native vector arithmetic (no inline asm): clang contracts to v_pk_fma_f32.
__device__ __forceinline__ void pkfma(f32x2& a, unsigned int u, f32x2 w2) {
  f32x2 b;
  b.x = __uint_as_float(u << 16);
  b.y = __uint_as_float(u & 0xFFFF0000u);
  a += b * w2;
}

// accumulate a uint4 (8 bf16 feats) into f32x2 A_[4]
#define ACC8P(A_, V_, W2_)   \
  pkfma(A_[0], (V_).x, W2_); \
  pkfma(A_[1], (V_).y, W2_); \
  pkfma(A_[2], (V_).z, W2_); \
  pkfma(A_[3], (V_).w, W2_);

// ---------------------------------------------------------------------------
// GEMM0 block body (MFMA): h0 = bf16(bf16(x) @ bf16(W0)), 32 rows x 128 cols
// per tile, TPB tiles/block. W0 pre-swizzled as bf16 B-fragments (w0f).
// ---------------------------------------------------------------------------
__device__ __forceinline__ void gemm0_block(
    int bid, const float* __restrict__ x, const uint4* __restrict__ w0f,
    unsigned short* __restrict__ h0) {
  __shared__ __align__(16) unsigned short xb[32 * 264];
  const int tid  = threadIdx.x;
  const int lane = tid & 63;
  const int wave = tid >> 6;
  const int rb   = wave & 1;
  const int ch   = wave >> 1;
  const int l15  = lane & 15;
  const int g    = lane >> 4;

  bf16x8 Bf[4][8];
#pragma unroll
  for (int cb = 0; cb < 4; ++cb)
#pragma unroll
    for (int q = 0; q < 8; ++q)
      Bf[cb][q] = __builtin_bit_cast(bf16x8, w0f[((ch * 4 + cb) * 8 + q) * 64 + lane]);

  for (int t = 0; t < TPB; ++t) {
    const int tile = bid * TPB + t;
    if (tile >= N_TILES) break;
    const int row0 = tile * 32;
    __syncthreads();
    for (int i = tid; i < 32 * 128; i += 256) {
      const int row = i >> 7, kp = i & 127;
      const float2 v = *(const float2*)(x + (size_t)(row0 + row) * IN_FEATS + kp * 2);
      __hip_bfloat162 p;
      p.x = __float2bfloat16(v.x);
      p.y = __float2bfloat16(v.y);
      *(unsigned int*)&xb[row * 264 + kp * 2] = *(unsigned int*)&p;
    }
    __syncthreads();

    f32x4 acc[4];
#pragma unroll
    for (int cb = 0; cb < 4; ++cb) acc[cb] = (f32x4){0.f, 0.f, 0.f, 0.f};

#pragma unroll
    for (int q = 0; q < 8; ++q) {
      const bf16x8 a = *(const bf16x8*)&xb[(rb * 16 + l15) * 264 + q * 32 + g * 8];
      acc[0] = __builtin_amdgcn_mfma_f32_16x16x32_bf16(a, Bf[0][q], acc[0], 0, 0, 0);
      acc[1] = __builtin_amdgcn_mfma_f32_16x16x32_bf16(a, Bf[1][q], acc[1], 0, 0, 0);
      acc[2] = __builtin_amdgcn_mfma_f32_16x16x32_bf16(a, Bf[2][q], acc[2], 0, 0, 0);
      acc[3] = __builtin_amdgcn_mfma_f32_16x16x32_bf16(a, Bf[3][q], acc[3], 0, 0, 0);
    }

#pragma unroll
    for (int cb = 0; cb < 4; ++cb) {
      const int col = ch * 64 + cb * 16 + l15;
#pragma unroll
      for (int r = 0; r < 4; ++r) {
        const int row = row0 + rb * 16 + g * 4 + r;
        __hip_bfloat16 hb = __float2bfloat16(acc[cb][r]);
        h0[(size_t)row * N_HIDDEN + col] = *(unsigned short*)&hb;
      }
    }
  }
}

// ---------------------------------------------------------------------------
// Parallel 2-level scan: block b computes bucket b's base by reducing
// bsum[0..b-1] (L2-hit), then pair-scans its own 391 contiguous entries.
// ---------------------------------------------------------------------------
__device__ __forceinline__ void bucket_scan_block(
    int b, const int* __restrict__ bsum, int* __restrict__ histG) {
  __shared__ int sh[256];
  __shared__ int pr[256];
  const int t = threadIdx.x;

  sh[t] = (t < b) ? bsum[t] : 0;          // b <= 195 < 256
  __syncthreads();
#pragma unroll
  for (int off = 128; off > 0; off >>= 1) {
    if (t < off) sh[t] += sh[t + off];
    __syncthreads();
  }
  const int base = sh[0];

  const int row = b * NBLK;
  const int i0 = 2 * t, i1 = 2 * t + 1;
  int a = 0, c = 0;
  if (t < 196) {
    a = histG[row + i0];                  // i0 <= 390
    if (i1 < NBLK) c = histG[row + i1];
  }
  pr[t] = a + c;
  __syncthreads();
  for (int off = 1; off < 256; off <<= 1) {
    int v = (t >= off) ? pr[t - off] : 0;
    __syncthreads();
    pr[t] += v;
    __syncthreads();
  }
  if (t < 196) {
    const int ebase = (t > 0) ? pr[t - 1] : 0;
    histG[row + i0] = base + ebase;
    if (i1 < NBLK) histG[row + i1] = base + ebase + a;
  }
}

// Combo: blocks 0..195 = parallel bucket scans, blocks 196.. = gemm0.
__global__ __launch_bounds__(256) void bscan_gemm0_kernel(
    const int* __restrict__ bsum, int* __restrict__ histG,
    const float* __restrict__ x, const uint4* __restrict__ w0f,
    unsigned short* __restrict__ h0) {
  if (blockIdx.x < NB) bucket_scan_block(blockIdx.x, bsum, histG);
  else                 gemm0_block(blockIdx.x - NB, x, w0f, h0);
}

// ---------------------------------------------------------------------------
// p1hist: blocks 0..NBLK-1 = histogram (+ bsum accumulate);
// block NBLK = W1 pre-swizzle; blocks NBLK+1..NBLK+8 = W0 pre-swizzle.
// ---------------------------------------------------------------------------
__global__ __launch_bounds__(256) void p1hist_kernel(
    const int* __restrict__ dst, int* __restrict__ histG,
    const float* __restrict__ W1, uint4* __restrict__ w1f,
    const float* __restrict__ W0, uint4* __restrict__ w0f,
    int* __restrict__ bsum) {
  const int tid = threadIdx.x;
  const int blk = blockIdx.x;

  if (blk >= NBLK) {
    if (blk == NBLK) {                    // W1 fragment converter (40 cols, pad)
      for (int t = tid; t < 3 * 4 * 64; t += 256) {
        const int ln  = t & 63;
        const int qq  = (t >> 6) & 3;
        const int nt  = t >> 8;
        const int l15 = ln & 15;
        const int gg  = ln >> 4;
        const int c   = nt * 16 + l15;
        const int k0  = qq * 32 + gg * 8;
        uint4 u;
        __hip_bfloat162 p;
#define W1AT(i_) ((c < OUT_FEATS) ? W1[(size_t)(k0 + (i_)) * OUT_FEATS + c] : 0.f)
        p.x = __float2bfloat16(W1AT(0)); p.y = __float2bfloat16(W1AT(1));
        u.x = *(unsigned int*)&p;
        p.x = __float2bfloat16(W1AT(2)); p.y = __float2bfloat16(W1AT(3));
        u.y = *(unsigned int*)&p;
        p.x = __float2bfloat16(W1AT(4)); p.y = __float2bfloat16(W1AT(5));
        u.z = *(unsigned int*)&p;
        p.x = __float2bfloat16(W1AT(6)); p.y = __float2bfloat16(W1AT(7));
        u.w = *(unsigned int*)&p;
#undef W1AT
        w1f[t] = u;
      }
    } else {                              // W0 fragment converter (128 cols)
      const int pb = blk - NBLK - 1;      // 0..7
      for (int fi = pb * 512 + tid; fi < pb * 512 + 512; fi += 256) {
        const int ln  = fi & 63;
        const int qq  = (fi >> 6) & 7;
        const int ct  = fi >> 9;
        const int col = ct * 16 + (ln & 15);
        const int k0  = qq * 32 + (ln >> 4) * 8;
        uint4 u;
        __hip_bfloat162 p;
        p.x = __float2bfloat16(W0[(size_t)(k0 + 0) * N_HIDDEN + col]);
        p.y = __float2bfloat16(W0[(size_t)(k0 + 1) * N_HIDDEN + col]);
        u.x = *(unsigned int*)&p;
        p.x = __float2bfloat16(W0[(size_t)(k0 + 2) * N_HIDDEN + col]);
        p.y = __float2bfloat16(W0[(size_t)(k0 + 3) * N_HIDDEN + col]);
        u.y = *(unsigned int*)&p;
        p.x = __float2bfloat16(W0[(size_t)(k0 + 4) * N_HIDDEN + col]);
        p.y = __float2bfloat16(W0[(size_t)(k0 + 5) * N_HIDDEN + col]);
        u.z = *(unsigned int*)&p;
        p.x = __float2bfloat16(W0[(size_t)(k0 + 6) * N_HIDDEN + col]);
        p.y = __float2bfloat16(W0[(size_t)(k0 + 7) * N_HIDDEN + col]);
        u.w = *(unsigned int*)&p;
        w0f[fi] = u;
      }
    }
    return;
  }

  __shared__ int lh[NB];
  for (int i = tid; i < NB; i += 256) lh[i] = 0;
  __syncthreads();

  const int e0 = blk * EPB;
  const int e1 = min(e0 + EPB, N_EDGES);
  for (int i = e0 + tid; i < e1; i += 256)
    atomicAdd(&lh[dst[i] >> 9], 1);
  __syncthreads();

  for (int i = tid; i < NB; i += 256) {
    histG[i * NBLK + blk] = lh[i];
    atomicAdd(&bsum[i], lh[i]);
  }
}

// ---------------------------------------------------------------------------
// p1scatter: LDS-staged, bucket-contiguous global writes (R7 lesson: direct
// node-level scatter = 7.7x write amplification + cross-XCD atomic bounce).
// ---------------------------------------------------------------------------
__global__ __launch_bounds__(256) void p1scatter_kernel(
    const int* __restrict__ src, const int* __restrict__ dst,
    const float* __restrict__ ew, const int* __restrict__ histG,
    uint2* __restrict__ bucketed) {
  __shared__ uint2 stage[EPB];          // 64 KB
  __shared__ unsigned char sbkt[EPB];   // 8 KB
  __shared__ int lcnt[NB];
  __shared__ int lbase[NB];
  __shared__ int spart[256];
  const int tid = threadIdx.x;
  const int blk = blockIdx.x;
  const int e0 = blk * EPB;
  const int e1 = min(e0 + EPB, N_EDGES);

  for (int i = tid; i < NB; i += 256) lcnt[i] = 0;
  __syncthreads();

  for (int i = e0 + tid; i < e1; i += 256)
    atomicAdd(&lcnt[dst[i] >> 9], 1);
  __syncthreads();

  const int myv = (tid < NB) ? lcnt[tid] : 0;
  spart[tid] = myv;
  __syncthreads();
  for (int off = 1; off < 256; off <<= 1) {
    int u = (tid >= off) ? spart[tid - off] : 0;
    __syncthreads();
    spart[tid] += u;
    __syncthreads();
  }
  if (tid < NB) { lbase[tid] = spart[tid] - myv; lcnt[tid] = spart[tid] - myv; }
  __syncthreads();

  for (int i = e0 + tid; i < e1; i += 256) {
    const int d = dst[i];
    const int b = d >> 9;
    const int pos = atomicAdd(&lcnt[b], 1);
    stage[pos] = make_uint2((unsigned)src[i] | ((unsigned)(d & 511) << 17),
                            __float_as_uint(ew[i]));
    sbkt[pos] = (unsigned char)b;
  }
  __syncthreads();

  const int n = e1 - e0;
  for (int i = tid; i < n; i += 256) {
    const int b = sbkt[i];
    const int gpos = histG[b * NBLK + blk] + (i - lbase[b]);
    bucketed[gpos] = stage[i];
  }
}

__global__ __launch_bounds__(256) void p2place_kernel(
    const uint2* __restrict__ bucketed, const int* __restrict__ histG,
    int* __restrict__ offsets, int2* __restrict__ srcw) {
  __shared__ int cnt[512];
  __shared__ int part[256];
  const int t = threadIdx.x;
  const int b = blockIdx.x;
  const int node0 = b << 9;
  const int beg = histG[b * NBLK];
  const int end = (b == NB - 1) ? N_EDGES : histG[(b + 1) * NBLK];

  cnt[t] = 0; cnt[t + 256] = 0;
  __syncthreads();

  for (int j = beg + t; j < end; j += 256)
    atomicAdd(&cnt[bucketed[j].x >> 17], 1);
  __syncthreads();

  const int a0 = cnt[2 * t];
  const int a1 = cnt[2 * t + 1];
  part[t] = a0 + a1;
  __syncthreads();
  for (int off = 1; off < 256; off <<= 1) {
    int v = (t >= off) ? part[t - off] : 0;
    __syncthreads();
    part[t] += v;
    __syncthreads();
  }
  const int base = (t > 0) ? part[t - 1] : 0;

  const int o0 = beg + base;
  const int o1 = o0 + a0;
  cnt[2 * t]     = o0;
  cnt[2 * t + 1] = o1;
  const int n0 = node0 + 2 * t;
  if (n0 < N_NODES)     offsets[n0]     = o0;
  if (n0 + 1 < N_NODES) offsets[n0 + 1] = o1;
  if (b == NB - 1 && t == 0) offsets[N_NODES] = N_EDGES;
  __syncthreads();

  for (int j = beg + t; j < end; j += 256) {
    const uint2 en = bucketed[j];
    const int slot = atomicAdd(&cnt[en.x >> 17], 1);
    srcw[slot] = make_int2((int)(en.x & 0x1FFFFu), (int)en.y);
  }
}

// ---------------------------------------------------------------------------
// Fused gather0 + bias + ReLU + MFMA GEMM1 epilogue.
// h1 now written as a single pitch-64 bf16 row (128 B): waves 0-2 store
// feats 0-47 (40-47 compute to 0 via padded w1f), wave 3 zero-fills 48-63.
// ---------------------------------------------------------------------------
__global__ __launch_bounds__(256) void gather0_gemm1_kernel(
    const uint4* __restrict__ h0q, const int2* __restrict__ srcw,
    const int* __restrict__ offsets, const float* __restrict__ b0,
    const uint4* __restrict__ w1f, unsigned short* __restrict__ h1b) {
  __shared__ float hs[4][132];
  const int wave = threadIdx.x >> 6;
  const int lane = threadIdx.x & 63;
  const int node = blockIdx.x * 4 + wave;
  const int q    = lane >> 4;       // edge slot 0..3 within a 4-edge group
  const int fl   = lane & 15;       // feature chunk: feats [fl*8, fl*8+8)

  const int beg = __builtin_amdgcn_readfirstlane(offsets[node]);
  const int end = __builtin_amdgcn_readfirstlane(offsets[node + 1]);

  f32x2 acc[4];
#pragma unroll
  for (int i = 0; i < 4; ++i) acc[i] = (f32x2){0.f, 0.f};

  if (end > beg) {
    const int e1 = end - 1;
    int2 sA = srcw[min(beg + q, e1)];
    int2 sB = srcw[min(beg + 4 + q, e1)];
    for (int j = beg; j < end; j += 8) {
      const float wA = (j + q < end)     ? __int_as_float(sA.y) : 0.f;
      const float wB = (j + 4 + q < end) ? __int_as_float(sB.y) : 0.f;
      const f32x2 w2A = {wA, wA};
      const f32x2 w2B = {wB, wB};
      const uint4 vA = h0q[(size_t)(unsigned)sA.x * 16 + fl];
      const uint4 vB = h0q[(size_t)(unsigned)sB.x * 16 + fl];
      const int jn = j + 8;
      if (jn < end) {                 // prefetch next groups' meta
        sA = srcw[min(jn + q, e1)];
        sB = srcw[min(jn + 4 + q, e1)];
      }
      ACC8P(acc, vA, w2A)
      ACC8P(acc, vB, w2B)
    }
  }

  // reduce the 4 edge-groups (lanes xor 16, 32 hold same features)
#pragma unroll
  for (int i = 0; i < 4; ++i) {
    acc[i].x += __shfl_xor(acc[i].x, 16);
    acc[i].x += __shfl_xor(acc[i].x, 32);
    acc[i].y += __shfl_xor(acc[i].y, 16);
    acc[i].y += __shfl_xor(acc[i].y, 32);
  }

  // bias + ReLU, one quarter-wave writes the 128-float row to LDS
  if (q == 0) {
    const int f0 = fl * 8;
    float t[8];
#pragma unroll
    for (int i = 0; i < 8; ++i) {
      const float a = ((i & 1) ? acc[i >> 1].y : acc[i >> 1].x);
      const float v = a + b0[f0 + i];
      t[i] = v > 0.f ? v : 0.f;
    }
    *(float4*)&hs[wave][f0]     = make_float4(t[0], t[1], t[2], t[3]);
    *(float4*)&hs[wave][f0 + 4] = make_float4(t[4], t[5], t[6], t[7]);
  }
  __syncthreads();

  // --- MFMA epilogue: h1 = hs(4x128) @ W1(128x40), waves 0-2 = N-tiles ---
  const int l15 = lane & 15;
  const int g   = lane >> 4;
  if (wave < 3) {
    f32x4 c = {0.f, 0.f, 0.f, 0.f};
#pragma unroll
    for (int qq = 0; qq < 4; ++qq) {
      uint4 ua = make_uint4(0, 0, 0, 0);
      if (l15 < 4) {                      // A rows 0-3 = this block's nodes
        const float* hrow = &hs[l15][qq * 32 + g * 8];
        __hip_bfloat162 p;
        p.x = __float2bfloat16(hrow[0]); p.y = __float2bfloat16(hrow[1]);
        ua.x = *(unsigned int*)&p;
        p.x = __float2bfloat16(hrow[2]); p.y = __float2bfloat16(hrow[3]);
        ua.y = *(unsigned int*)&p;
        p.x = __float2bfloat16(hrow[4]); p.y = __float2bfloat16(hrow[5]);
        ua.z = *(unsigned int*)&p;
        p.x = __float2bfloat16(hrow[6]); p.y = __float2bfloat16(hrow[7]);
        ua.w = *(unsigned int*)&p;
      }
      const uint4 ub = w1f[(wave * 4 + qq) * 64 + lane];
      c = __builtin_amdgcn_mfma_f32_16x16x32_bf16(
            __builtin_bit_cast(bf16x8, ua), __builtin_bit_cast(bf16x8, ub),
            c, 0, 0, 0);
    }
    // C: col = lane&15 (feat within tile), row = (lane>>4)*4 + r (node)
    if (g == 0) {
#pragma unroll
      for (int r = 0; r < 4; ++r) {
        const int nodeR = blockIdx.x * 4 + r;
        const int f = wave * 16 + l15;    // 0..47
        __hip_bfloat16 hb = __float2bfloat16(c[r]);
        h1b[(size_t)nodeR * 64 + f] = *(unsigned short*)&hb;
      }
    }
  } else {
    // wave 3: zero-fill cols 48..63 so gather1 rows are fully valid 128 B
    if (g == 0) {
#pragma unroll
      for (int r = 0; r < 4; ++r) {
        const int nodeR = blockIdx.x * 4 + r;
        h1b[(size_t)nodeR * 64 + 48 + l15] = 0;
      }
    }
  }
}

// ---------------------------------------------------------------------------
// Fused gather1 + bias + log_softmax on uniform pitch-64 h1 rows.
// 8 lanes/edge x uint4 (full 128 B row), no divergent side-path; reduction is
// 3 xor rounds (edge groups) + 3 xor rounds (lsm across feature chunks).
// ---------------------------------------------------------------------------
__global__ __launch_bounds__(256) void gather1_lsm_kernel(
    const uint4* __restrict__ h1q, const int2* __restrict__ srcw,
    const int* __restrict__ offsets, const float* __restrict__ b1,
    float* __restrict__ out) {
  const int wave = threadIdx.x >> 6;
  const int lane = threadIdx.x & 63;
  const int node = blockIdx.x * 4 + wave;
  const int g  = lane >> 3;         // edge slot 0..7 within an 8-edge group
  const int fl = lane & 7;          // feats [fl*8, fl*8+8) of the 64-pitch row

  const int beg = __builtin_amdgcn_readfirstlane(offsets[node]);
  const int end = __builtin_amdgcn_readfirstlane(offsets[node + 1]);

  f32x2 acc[4];
#pragma unroll
  for (int i = 0; i < 4; ++i) acc[i] = (f32x2){0.f, 0.f};

  if (end > beg) {
    const int e1 = end - 1;
    int2 sA = srcw[min(beg + g, e1)];
    int2 sB = srcw[min(beg + 8 + g, e1)];
    for (int j = beg; j < end; j += 16) {
      const float wA = (j + g < end)     ? __int_as_float(sA.y) : 0.f;
      const float wB = (j + 8 + g < end) ? __int_as_float(sB.y) : 0.f;
      const f32x2 w2A = {wA, wA};
      const f32x2 w2B = {wB, wB};
      const uint4 vA = h1q[(size_t)(unsigned)sA.x * 8 + fl];
      const uint4 vB = h1q[(size_t)(unsigned)sB.x * 8 + fl];
      const int jn = j + 16;
      if (jn < end) {
        sA = srcw[min(jn + g, e1)];
        sB = srcw[min(jn + 8 + g, e1)];
      }
      ACC8P(acc, vA, w2A)
      ACC8P(acc, vB, w2B)
    }
  }

  // reduce across the 8 edge-groups (lane bits 3,4,5)
  float o[8];
#pragma unroll
  for (int i = 0; i < 4; ++i) {
    float x0 = acc[i].x, y0 = acc[i].y;
    x0 += __shfl_xor(x0, 8); x0 += __shfl_xor(x0, 16); x0 += __shfl_xor(x0, 32);
    y0 += __shfl_xor(y0, 8); y0 += __shfl_xor(y0, 16); y0 += __shfl_xor(y0, 32);
    o[2 * i] = x0; o[2 * i + 1] = y0;
  }

  const bool valid = (fl < 5);      // feats fl*8..fl*8+7 < 40
  float m = -INFINITY;
  if (valid) {
    const int f0 = fl * 8;
#pragma unroll
    for (int i = 0; i < 8; ++i) {
      o[i] += b1[f0 + i];
      m = fmaxf(m, o[i]);
    }
  }
  m = fmaxf(m, __shfl_xor(m, 1));
  m = fmaxf(m, __shfl_xor(m, 2));
  m = fmaxf(m, __shfl_xor(m, 4));

  float s = 0.f;
  if (valid) {
#pragma unroll
    for (int i = 0; i < 8; ++i) s += expf(o[i] - m);
  }
  s += __shfl_xor(s, 1);
  s += __shfl_xor(s, 2);
  s += __shfl_xor(s, 4);

  if (lane < 5) {                   // g==0 && fl<5: write all 40 outputs
    const float lse = m + logf(s);
    float* op = out + (size_t)node * OUT_FEATS + fl * 8;
    *(float4*)op       = make_float4(o[0] - lse, o[1] - lse,
                                     o[2] - lse, o[3] - lse);
    *(float4*)(op + 4) = make_float4(o[4] - lse, o[5] - lse,
                                     o[6] - lse, o[7] - lse);
  }
}

// ---------------------------------------------------------------------------
extern "C" void kernel_launch(void* const* d_in, const int* in_sizes, int n_in,
                              void* d_out, int out_size, void* d_ws, size_t ws_size,
                              hipStream_t stream) {
  const float* x   = (const float*)d_in[0];
  const float* W0  = (const float*)d_in[1];
  const float* b0  = (const float*)d_in[2];
  const float* W1  = (const float*)d_in[3];
  const float* b1  = (const float*)d_in[4];
  const float* ew  = (const float*)d_in[5];
  const int*   src = (const int*)d_in[6];
  const int*   dst = (const int*)d_in[7];
  float* out = (float*)d_out;

  // Workspace layout, peak ~90.4 MB (ws >= 102.4 MB):
  //   h0b2     [0,          25,600,000)   N*128 bf16
  //   srcw     [25,600,000, 51,200,000)   E int2, dst-sorted
  //   bucketed [51,200,000, 76,800,000)   E uint2, bucket-partitioned
  //   offsets  [76,800,000, 77,200,064)   N+1 int
  //   histG    [77,200,064, 77,506,624)   NB*NBLK int
  //   h1b      [77,506,624, 90,306,624)   N*64 bf16 (pitch-64, 128 B rows)
  //   w1f      [90,306,624, 90,318,912)   768 uint4 (pre-swizzled W1 B-frags)
  //   w0f      [90,318,912, 90,384,448)   4096 uint4 (pre-swizzled W0 B-frags)
  //   bsum     [90,384,448, 90,385,232)   NB int (per-bucket edge totals)
  char* ws = (char*)d_ws;
  unsigned int* h0b2 = (unsigned int*)(ws);
  int2*  srcw     = (int2*)(ws + 25600000);
  uint2* bucketed = (uint2*)(ws + 51200000);
  int*   offsets  = (int*)(ws + 76800000);
  int*   histG    = (int*)(ws + 77200064);
  unsigned short* h1b = (unsigned short*)(ws + 77506624);
  uint4* w1f      = (uint4*)(ws + 90306624);
  uint4* w0f      = (uint4*)(ws + 90318912);
  int*   bsum     = (int*)(ws + 90384448);

  hipMemsetAsync(bsum, 0, NB * sizeof(int), stream);
  p1hist_kernel<<<NBLK + 9, 256, 0, stream>>>(dst, histG, W1, w1f, W0, w0f, bsum);
  bscan_gemm0_kernel<<<NB + G0BLKS, 256, 0, stream>>>(
      bsum, histG, x, w0f, (unsigned short*)h0b2);
  p1scatter_kernel<<<NBLK, 256, 0, stream>>>(src, dst, ew, histG, bucketed);
  p2place_kernel<<<NB, 256, 0, stream>>>(bucketed, histG, offsets, srcw);

  gather0_gemm1_kernel<<<N_NODES / 4, 256, 0, stream>>>(
      (const uint4*)h0b2, srcw, offsets, b0, (const uint4*)w1f, h1b);
  gather1_lsm_kernel<<<N_NODES / 4, 256, 0, stream>>>(
      (const uint4*)h1b, srcw, offsets, b1, out);
}

// Round 10
// 502.769 us; speedup vs baseline: 1.5841x; 1.0017x over previous
//
#include <hip/hip_runtime.h>
#include <hip/hip_bf16.h>
#include <cstdint>
#include <cstddef>

#define N_NODES   100000
#define N_EDGES   3200000
#define IN_FEATS  256
#define N_HIDDEN  128
#define OUT_FEATS 40

// Bucket partition: bucket = dst >> 9 (512 nodes/bucket)
#define NB        196
#define EPB       8192
#define NBLK      391
#define HIST_M    (NB * NBLK)
#define N_TILES   3125            // 100000 / 32
#define TPB       2               // gemm0 tiles per block
#define G0BLKS    ((N_TILES + TPB - 1) / TPB)   // 1563

typedef __attribute__((ext_vector_type(8))) __bf16 bf16x8;
typedef __attribute__((ext_vector_type(4))) float f32x4;
typedef __attribute__((ext_vector_type(2))) float f32x2;

// packed fp32 FMA: acc(2 feats) += unpack2_bf16(u) * w2.
// Native vector arithmetic (no inline asm): clang contracts to v_pk_fma_f32.
__device__ __forceinline__ void pkfma(f32x2& a, unsigned int u, f32x2 w2) {
  f32x2 b;
  b.x = __uint_as_float(u << 16);
  b.y = __uint_as_float(u & 0xFFFF0000u);
  a += b * w2;
}

// accumulate a uint4 (8 bf16 feats) into f32x2 A_[4]
#define ACC8P(A_, V_, W2_)   \
  pkfma(A_[0], (V_).x, W2_); \
  pkfma(A_[1], (V_).y, W2_); \
  pkfma(A_[2], (V_).z, W2_); \
  pkfma(A_[3], (V_).w, W2_);

// ---------------------------------------------------------------------------
// GEMM0 block body (MFMA): h0 = bf16(bf16(x) @ bf16(W0)), 32 rows x 128 cols
// per tile, TPB tiles/block. W0 pre-swizzled as bf16 B-fragments (w0f).
// ---------------------------------------------------------------------------
__device__ __forceinline__ void gemm0_block(
    int bid, const float* __restrict__ x, const uint4* __restrict__ w0f,
    unsigned short* __restrict__ h0) {
  __shared__ __align__(16) unsigned short xb[32 * 264];
  const int tid  = threadIdx.x;
  const int lane = tid & 63;
  const int wave = tid >> 6;
  const int rb   = wave & 1;
  const int ch   = wave >> 1;
  const int l15  = lane & 15;
  const int g    = lane >> 4;

  bf16x8 Bf[4][8];
#pragma unroll
  for (int cb = 0; cb < 4; ++cb)
#pragma unroll
    for (int q = 0; q < 8; ++q)
      Bf[cb][q] = __builtin_bit_cast(bf16x8, w0f[((ch * 4 + cb) * 8 + q) * 64 + lane]);

  for (int t = 0; t < TPB; ++t) {
    const int tile = bid * TPB + t;
    if (tile >= N_TILES) break;
    const int row0 = tile * 32;
    __syncthreads();
    for (int i = tid; i < 32 * 128; i += 256) {
      const int row = i >> 7, kp = i & 127;
      const float2 v = *(const float2*)(x + (size_t)(row0 + row) * IN_FEATS + kp * 2);
      __hip_bfloat162 p;
      p.x = __float2bfloat16(v.x);
      p.y = __float2bfloat16(v.y);
      *(unsigned int*)&xb[row * 264 + kp * 2] = *(unsigned int*)&p;
    }
    __syncthreads();

    f32x4 acc[4];
#pragma unroll
    for (int cb = 0; cb < 4; ++cb) acc[cb] = (f32x4){0.f, 0.f, 0.f, 0.f};

#pragma unroll
    for (int q = 0; q < 8; ++q) {
      const bf16x8 a = *(const bf16x8*)&xb[(rb * 16 + l15) * 264 + q * 32 + g * 8];
      acc[0] = __builtin_amdgcn_mfma_f32_16x16x32_bf16(a, Bf[0][q], acc[0], 0, 0, 0);
      acc[1] = __builtin_amdgcn_mfma_f32_16x16x32_bf16(a, Bf[1][q], acc[1], 0, 0, 0);
      acc[2] = __builtin_amdgcn_mfma_f32_16x16x32_bf16(a, Bf[2][q], acc[2], 0, 0, 0);
      acc[3] = __builtin_amdgcn_mfma_f32_16x16x32_bf16(a, Bf[3][q], acc[3], 0, 0, 0);
    }

#pragma unroll
    for (int cb = 0; cb < 4; ++cb) {
      const int col = ch * 64 + cb * 16 + l15;
#pragma unroll
      for (int r = 0; r < 4; ++r) {
        const int row = row0 + rb * 16 + g * 4 + r;
        __hip_bfloat16 hb = __float2bfloat16(acc[cb][r]);
        h0[(size_t)row * N_HIDDEN + col] = *(unsigned short*)&hb;
      }
    }
  }
}

// ---------------------------------------------------------------------------
// Parallel 2-level scan: block b computes bucket b's base by reducing
// bsum[0..b-1] (L2-hit), then pair-scans its own 391 contiguous entries.
// ---------------------------------------------------------------------------
__device__ __forceinline__ void bucket_scan_block(
    int b, const int* __restrict__ bsum, int* __restrict__ histG) {
  __shared__ int sh[256];
  __shared__ int pr[256];
  const int t = threadIdx.x;

  sh[t] = (t < b) ? bsum[t] : 0;          // b <= 195 < 256
  __syncthreads();
#pragma unroll
  for (int off = 128; off > 0; off >>= 1) {
    if (t < off) sh[t] += sh[t + off];
    __syncthreads();
  }
  const int base = sh[0];

  const int row = b * NBLK;
  const int i0 = 2 * t, i1 = 2 * t + 1;
  int a = 0, c = 0;
  if (t < 196) {
    a = histG[row + i0];                  // i0 <= 390
    if (i1 < NBLK) c = histG[row + i1];
  }
  pr[t] = a + c;
  __syncthreads();
  for (int off = 1; off < 256; off <<= 1) {
    int v = (t >= off) ? pr[t - off] : 0;
    __syncthreads();
    pr[t] += v;
    __syncthreads();
  }
  if (t < 196) {
    const int ebase = (t > 0) ? pr[t - 1] : 0;
    histG[row + i0] = base + ebase;
    if (i1 < NBLK) histG[row + i1] = base + ebase + a;
  }
}

// Combo: blocks 0..195 = parallel bucket scans, blocks 196.. = gemm0.
__global__ __launch_bounds__(256) void bscan_gemm0_kernel(
    const int* __restrict__ bsum, int* __restrict__ histG,
    const float* __restrict__ x, const uint4* __restrict__ w0f,
    unsigned short* __restrict__ h0) {
  if (blockIdx.x < NB) bucket_scan_block(blockIdx.x, bsum, histG);
  else                 gemm0_block(blockIdx.x - NB, x, w0f, h0);
}

// ---------------------------------------------------------------------------
// p1hist: blocks 0..NBLK-1 = histogram (+ bsum accumulate);
// block NBLK = W1 pre-swizzle; blocks NBLK+1..NBLK+8 = W0 pre-swizzle.
// ---------------------------------------------------------------------------
__global__ __launch_bounds__(256) void p1hist_kernel(
    const int* __restrict__ dst, int* __restrict__ histG,
    const float* __restrict__ W1, uint4* __restrict__ w1f,
    const float* __restrict__ W0, uint4* __restrict__ w0f,
    int* __restrict__ bsum) {
  const int tid = threadIdx.x;
  const int blk = blockIdx.x;

  if (blk >= NBLK) {
    if (blk == NBLK) {                    // W1 fragment converter (40 cols, pad)
      for (int t = tid; t < 3 * 4 * 64; t += 256) {
        const int ln  = t & 63;
        const int qq  = (t >> 6) & 3;
        const int nt  = t >> 8;
        const int l15 = ln & 15;
        const int gg  = ln >> 4;
        const int c   = nt * 16 + l15;
        const int k0  = qq * 32 + gg * 8;
        uint4 u;
        __hip_bfloat162 p;
#define W1AT(i_) ((c < OUT_FEATS) ? W1[(size_t)(k0 + (i_)) * OUT_FEATS + c] : 0.f)
        p.x = __float2bfloat16(W1AT(0)); p.y = __float2bfloat16(W1AT(1));
        u.x = *(unsigned int*)&p;
        p.x = __float2bfloat16(W1AT(2)); p.y = __float2bfloat16(W1AT(3));
        u.y = *(unsigned int*)&p;
        p.x = __float2bfloat16(W1AT(4)); p.y = __float2bfloat16(W1AT(5));
        u.z = *(unsigned int*)&p;
        p.x = __float2bfloat16(W1AT(6)); p.y = __float2bfloat16(W1AT(7));
        u.w = *(unsigned int*)&p;
#undef W1AT
        w1f[t] = u;
      }
    } else {                              // W0 fragment converter (128 cols)
      const int pb = blk - NBLK - 1;      // 0..7
      for (int fi = pb * 512 + tid; fi < pb * 512 + 512; fi += 256) {
        const int ln  = fi & 63;
        const int qq  = (fi >> 6) & 7;
        const int ct  = fi >> 9;
        const int col = ct * 16 + (ln & 15);
        const int k0  = qq * 32 + (ln >> 4) * 8;
        uint4 u;
        __hip_bfloat162 p;
        p.x = __float2bfloat16(W0[(size_t)(k0 + 0) * N_HIDDEN + col]);
        p.y = __float2bfloat16(W0[(size_t)(k0 + 1) * N_HIDDEN + col]);
        u.x = *(unsigned int*)&p;
        p.x = __float2bfloat16(W0[(size_t)(k0 + 2) * N_HIDDEN + col]);
        p.y = __float2bfloat16(W0[(size_t)(k0 + 3) * N_HIDDEN + col]);
        u.y = *(unsigned int*)&p;
        p.x = __float2bfloat16(W0[(size_t)(k0 + 4) * N_HIDDEN + col]);
        p.y = __float2bfloat16(W0[(size_t)(k0 + 5) * N_HIDDEN + col]);
        u.z = *(unsigned int*)&p;
        p.x = __float2bfloat16(W0[(size_t)(k0 + 6) * N_HIDDEN + col]);
        p.y = __float2bfloat16(W0[(size_t)(k0 + 7) * N_HIDDEN + col]);
        u.w = *(unsigned int*)&p;
        w0f[fi] = u;
      }
    }
    return;
  }

  __shared__ int lh[NB];
  for (int i = tid; i < NB; i += 256) lh[i] = 0;
  __syncthreads();

  const int e0 = blk * EPB;
  const int e1 = min(e0 + EPB, N_EDGES);
  for (int i = e0 + tid; i < e1; i += 256)
    atomicAdd(&lh[dst[i] >> 9], 1);
  __syncthreads();

  for (int i = tid; i < NB; i += 256) {
    histG[i * NBLK + blk] = lh[i];
    atomicAdd(&bsum[i], lh[i]);
  }
}

// ---------------------------------------------------------------------------
// p1scatter: LDS-staged, bucket-contiguous global writes (R7 lesson: direct
// node-level scatter = 7.7x write amplification + cross-XCD atomic bounce).
// ---------------------------------------------------------------------------
__global__ __launch_bounds__(256) void p1scatter_kernel(
    const int* __restrict__ src, const int* __restrict__ dst,
    const float* __restrict__ ew, const int* __restrict__ histG,
    uint2* __restrict__ bucketed) {
  __shared__ uint2 stage[EPB];          // 64 KB
  __shared__ unsigned char sbkt[EPB];   // 8 KB
  __shared__ int lcnt[NB];
  __shared__ int lbase[NB];
  __shared__ int spart[256];
  const int tid = threadIdx.x;
  const int blk = blockIdx.x;
  const int e0 = blk * EPB;
  const int e1 = min(e0 + EPB, N_EDGES);

  for (int i = tid; i < NB; i += 256) lcnt[i] = 0;
  __syncthreads();

  for (int i = e0 + tid; i < e1; i += 256)
    atomicAdd(&lcnt[dst[i] >> 9], 1);
  __syncthreads();

  const int myv = (tid < NB) ? lcnt[tid] : 0;
  spart[tid] = myv;
  __syncthreads();
  for (int off = 1; off < 256; off <<= 1) {
    int u = (tid >= off) ? spart[tid - off] : 0;
    __syncthreads();
    spart[tid] += u;
    __syncthreads();
  }
  if (tid < NB) { lbase[tid] = spart[tid] - myv; lcnt[tid] = spart[tid] - myv; }
  __syncthreads();

  for (int i = e0 + tid; i < e1; i += 256) {
    const int d = dst[i];
    const int b = d >> 9;
    const int pos = atomicAdd(&lcnt[b], 1);
    stage[pos] = make_uint2((unsigned)src[i] | ((unsigned)(d & 511) << 17),
                            __float_as_uint(ew[i]));
    sbkt[pos] = (unsigned char)b;
  }
  __syncthreads();

  const int n = e1 - e0;
  for (int i = tid; i < n; i += 256) {
    const int b = sbkt[i];
    const int gpos = histG[b * NBLK + blk] + (i - lbase[b]);
    bucketed[gpos] = stage[i];
  }
}

__global__ __launch_bounds__(256) void p2place_kernel(
    const uint2* __restrict__ bucketed, const int* __restrict__ histG,
    int* __restrict__ offsets, int2* __restrict__ srcw) {
  __shared__ int cnt[512];
  __shared__ int part[256];
  const int t = threadIdx.x;
  const int b = blockIdx.x;
  const int node0 = b << 9;
  const int beg = histG[b * NBLK];
  const int end = (b == NB - 1) ? N_EDGES : histG[(b + 1) * NBLK];

  cnt[t] = 0; cnt[t + 256] = 0;
  __syncthreads();

  for (int j = beg + t; j < end; j += 256)
    atomicAdd(&cnt[bucketed[j].x >> 17], 1);
  __syncthreads();

  const int a0 = cnt[2 * t];
  const int a1 = cnt[2 * t + 1];
  part[t] = a0 + a1;
  __syncthreads();
  for (int off = 1; off < 256; off <<= 1) {
    int v = (t >= off) ? part[t - off] : 0;
    __syncthreads();
    part[t] += v;
    __syncthreads();
  }
  const int base = (t > 0) ? part[t - 1] : 0;

  const int o0 = beg + base;
  const int o1 = o0 + a0;
  cnt[2 * t]     = o0;
  cnt[2 * t + 1] = o1;
  const int n0 = node0 + 2 * t;
  if (n0 < N_NODES)     offsets[n0]     = o0;
  if (n0 + 1 < N_NODES) offsets[n0 + 1] = o1;
  if (b == NB - 1 && t == 0) offsets[N_NODES] = N_EDGES;
  __syncthreads();

  for (int j = beg + t; j < end; j += 256) {
    const uint2 en = bucketed[j];
    const int slot = atomicAdd(&cnt[en.x >> 17], 1);
    srcw[slot] = make_int2((int)(en.x & 0x1FFFFu), (int)en.y);
  }
}

// ---------------------------------------------------------------------------
// Fused gather0 + bias + ReLU + MFMA GEMM1 epilogue.
// Gather: 16 lanes/edge, 4 edge-groups in flight (16 edges/iter, 4
// independent dwordx4 gathers) to overlap HBM latency with the FMA stream.
// ---------------------------------------------------------------------------
__global__ __launch_bounds__(256) void gather0_gemm1_kernel(
    const uint4* __restrict__ h0q, const int2* __restrict__ srcw,
    const int* __restrict__ offsets, const float* __restrict__ b0,
    const uint4* __restrict__ w1f, unsigned short* __restrict__ h1b) {
  __shared__ float hs[4][132];
  const int wave = threadIdx.x >> 6;
  const int lane = threadIdx.x & 63;
  const int node = blockIdx.x * 4 + wave;
  const int q    = lane >> 4;       // edge slot 0..3 within a 4-edge group
  const int fl   = lane & 15;       // feature chunk: feats [fl*8, fl*8+8)

  const int beg = __builtin_amdgcn_readfirstlane(offsets[node]);
  const int end = __builtin_amdgcn_readfirstlane(offsets[node + 1]);

  f32x2 acc[4];
#pragma unroll
  for (int i = 0; i < 4; ++i) acc[i] = (f32x2){0.f, 0.f};

  if (end > beg) {
    const int e1 = end - 1;
    int2 sa = srcw[min(beg + q, e1)];
    int2 sb = srcw[min(beg + 4 + q, e1)];
    int2 sc = srcw[min(beg + 8 + q, e1)];
    int2 sd = srcw[min(beg + 12 + q, e1)];
    for (int j = beg; j < end; j += 16) {
      const float wa = (j + q < end)      ? __int_as_float(sa.y) : 0.f;
      const float wb = (j + 4 + q < end)  ? __int_as_float(sb.y) : 0.f;
      const float wc = (j + 8 + q < end)  ? __int_as_float(sc.y) : 0.f;
      const float wd = (j + 12 + q < end) ? __int_as_float(sd.y) : 0.f;
      const uint4 va = h0q[(size_t)(unsigned)sa.x * 16 + fl];
      const uint4 vb = h0q[(size_t)(unsigned)sb.x * 16 + fl];
      const uint4 vc = h0q[(size_t)(unsigned)sc.x * 16 + fl];
      const uint4 vd = h0q[(size_t)(unsigned)sd.x * 16 + fl];
      const int jn = j + 16;
      if (jn < end) {                 // prefetch next groups' meta
        sa = srcw[min(jn + q, e1)];
        sb = srcw[min(jn + 4 + q, e1)];
        sc = srcw[min(jn + 8 + q, e1)];
        sd = srcw[min(jn + 12 + q, e1)];
      }
      const f32x2 pa = {wa, wa};
      const f32x2 pb = {wb, wb};
      const f32x2 pc = {wc, wc};
      const f32x2 pd = {wd, wd};
      ACC8P(acc, va, pa)
      ACC8P(acc, vb, pb)
      ACC8P(acc, vc, pc)
      ACC8P(acc, vd, pd)
    }
  }

  // reduce the 4 edge-groups (lanes xor 16, 32 hold same features)
#pragma unroll
  for (int i = 0; i < 4; ++i) {
    acc[i].x += __shfl_xor(acc[i].x, 16);
    acc[i].x += __shfl_xor(acc[i].x, 32);
    acc[i].y += __shfl_xor(acc[i].y, 16);
    acc[i].y += __shfl_xor(acc[i].y, 32);
  }

  // bias + ReLU, one quarter-wave writes the 128-float row to LDS
  if (q == 0) {
    const int f0 = fl * 8;
    float t[8];
#pragma unroll
    for (int i = 0; i < 8; ++i) {
      const float a = ((i & 1) ? acc[i >> 1].y : acc[i >> 1].x);
      const float v = a + b0[f0 + i];
      t[i] = v > 0.f ? v : 0.f;
    }
    *(float4*)&hs[wave][f0]     = make_float4(t[0], t[1], t[2], t[3]);
    *(float4*)&hs[wave][f0 + 4] = make_float4(t[4], t[5], t[6], t[7]);
  }
  __syncthreads();

  // --- MFMA epilogue: h1 = hs(4x128) @ W1(128x40), waves 0-2 = N-tiles ---
  const int l15 = lane & 15;
  const int g   = lane >> 4;
  if (wave < 3) {
    f32x4 c = {0.f, 0.f, 0.f, 0.f};
#pragma unroll
    for (int qq = 0; qq < 4; ++qq) {
      uint4 ua = make_uint4(0, 0, 0, 0);
      if (l15 < 4) {                      // A rows 0-3 = this block's nodes
        const float* hrow = &hs[l15][qq * 32 + g * 8];
        __hip_bfloat162 p;
        p.x = __float2bfloat16(hrow[0]); p.y = __float2bfloat16(hrow[1]);
        ua.x = *(unsigned int*)&p;
        p.x = __float2bfloat16(hrow[2]); p.y = __float2bfloat16(hrow[3]);
        ua.y = *(unsigned int*)&p;
        p.x = __float2bfloat16(hrow[4]); p.y = __float2bfloat16(hrow[5]);
        ua.z = *(unsigned int*)&p;
        p.x = __float2bfloat16(hrow[6]); p.y = __float2bfloat16(hrow[7]);
        ua.w = *(unsigned int*)&p;
      }
      const uint4 ub = w1f[(wave * 4 + qq) * 64 + lane];
      c = __builtin_amdgcn_mfma_f32_16x16x32_bf16(
            __builtin_bit_cast(bf16x8, ua), __builtin_bit_cast(bf16x8, ub),
            c, 0, 0, 0);
    }
    // C: col = lane&15 (feat within tile), row = (lane>>4)*4 + r (node)
    if (g == 0) {
#pragma unroll
      for (int r = 0; r < 4; ++r) {
        const int nodeR = blockIdx.x * 4 + r;
        const int f = wave * 16 + l15;    // 0..47
        __hip_bfloat16 hb = __float2bfloat16(c[r]);
        h1b[(size_t)nodeR * 64 + f] = *(unsigned short*)&hb;
      }
    }
  } else {
    // wave 3: zero-fill cols 48..63 so gather1 rows are fully valid 128 B
    if (g == 0) {
#pragma unroll
      for (int r = 0; r < 4; ++r) {
        const int nodeR = blockIdx.x * 4 + r;
        h1b[(size_t)nodeR * 64 + 48 + l15] = 0;
      }
    }
  }
}

// ---------------------------------------------------------------------------
// Fused gather1 + bias + log_softmax on uniform pitch-64 h1 rows.
// 8 lanes/edge x uint4, 4 edge-groups in flight (32 edges/iter).
// ---------------------------------------------------------------------------
__global__ __launch_bounds__(256) void gather1_lsm_kernel(
    const uint4* __restrict__ h1q, const int2* __restrict__ srcw,
    const int* __restrict__ offsets, const float* __restrict__ b1,
    float* __restrict__ out) {
  const int wave = threadIdx.x >> 6;
  const int lane = threadIdx.x & 63;
  const int node = blockIdx.x * 4 + wave;
  const int g  = lane >> 3;         // edge slot 0..7 within an 8-edge group
  const int fl = lane & 7;          // feats [fl*8, fl*8+8) of the 64-pitch row

  const int beg = __builtin_amdgcn_readfirstlane(offsets[node]);
  const int end = __builtin_amdgcn_readfirstlane(offsets[node + 1]);

  f32x2 acc[4];
#pragma unroll
  for (int i = 0; i < 4; ++i) acc[i] = (f32x2){0.f, 0.f};

  if (end > beg) {
    const int e1 = end - 1;
    int2 sa = srcw[min(beg + g, e1)];
    int2 sb = srcw[min(beg + 8 + g, e1)];
    int2 sc = srcw[min(beg + 16 + g, e1)];
    int2 sd = srcw[min(beg + 24 + g, e1)];
    for (int j = beg; j < end; j += 32) {
      const float wa = (j + g < end)      ? __int_as_float(sa.y) : 0.f;
      const float wb = (j + 8 + g < end)  ? __int_as_float(sb.y) : 0.f;
      const float wc = (j + 16 + g < end) ? __int_as_float(sc.y) : 0.f;
      const float wd = (j + 24 + g < end) ? __int_as_float(sd.y) : 0.f;
      const uint4 va = h1q[(size_t)(unsigned)sa.x * 8 + fl];
      const uint4 vb = h1q[(size_t)(unsigned)sb.x * 8 + fl];
      const uint4 vc = h1q[(size_t)(unsigned)sc.x * 8 + fl];
      const uint4 vd = h1q[(size_t)(unsigned)sd.x * 8 + fl];
      const int jn = j + 32;
      if (jn < end) {
        sa = srcw[min(jn + g, e1)];
        sb = srcw[min(jn + 8 + g, e1)];
        sc = srcw[min(jn + 16 + g, e1)];
        sd = srcw[min(jn + 24 + g, e1)];
      }
      const f32x2 pa = {wa, wa};
      const f32x2 pb = {wb, wb};
      const f32x2 pc = {wc, wc};
      const f32x2 pd = {wd, wd};
      ACC8P(acc, va, pa)
      ACC8P(acc, vb, pb)
      ACC8P(acc, vc, pc)
      ACC8P(acc, vd, pd)
    }
  }

  // reduce across the 8 edge-groups (lane bits 3,4,5)
  float o[8];
#pragma unroll
  for (int i = 0; i < 4; ++i) {
    float x0 = acc[i].x, y0 = acc[i].y;
    x0 += __shfl_xor(x0, 8); x0 += __shfl_xor(x0, 16); x0 += __shfl_xor(x0, 32);
    y0 += __shfl_xor(y0, 8); y0 += __shfl_xor(y0, 16); y0 += __shfl_xor(y0, 32);
    o[2 * i] = x0; o[2 * i + 1] = y0;
  }

  const bool valid = (fl < 5);      // feats fl*8..fl*8+7 < 40
  float m = -INFINITY;
  if (valid) {
    const int f0 = fl * 8;
#pragma unroll
    for (int i = 0; i < 8; ++i) {
      o[i] += b1[f0 + i];
      m = fmaxf(m, o[i]);
    }
  }
  m = fmaxf(m, __shfl_xor(m, 1));
  m = fmaxf(m, __shfl_xor(m, 2));
  m = fmaxf(m, __shfl_xor(m, 4));

  float s = 0.f;
  if (valid) {
#pragma unroll
    for (int i = 0; i < 8; ++i) s += expf(o[i] - m);
  }
  s += __shfl_xor(s, 1);
  s += __shfl_xor(s, 2);
  s += __shfl_xor(s, 4);

  if (lane < 5) {                   // g==0 && fl<5: write all 40 outputs
    const float lse = m + logf(s);
    float* op = out + (size_t)node * OUT_FEATS + fl * 8;
    *(float4*)op       = make_float4(o[0] - lse, o[1] - lse,
                                     o[2] - lse, o[3] - lse);
    *(float4*)(op + 4) = make_float4(o[4] - lse, o[5] - lse,
                                     o[6] - lse, o[7] - lse);
  }
}

// ---------------------------------------------------------------------------
extern "C" void kernel_launch(void* const* d_in, const int* in_sizes, int n_in,
                              void* d_out, int out_size, void* d_ws, size_t ws_size,
                              hipStream_t stream) {
  const float* x   = (const float*)d_in[0];
  const float* W0  = (const float*)d_in[1];
  const float* b0  = (const float*)d_in[2];
  const float* W1  = (const float*)d_in[3];
  const float* b1  = (const float*)d_in[4];
  const float* ew  = (const float*)d_in[5];
  const int*   src = (const int*)d_in[6];
  const int*   dst = (const int*)d_in[7];
  float* out = (float*)d_out;

  // Workspace layout, peak ~90.4 MB (ws >= 102.4 MB):
  //   h0b2     [0,          25,600,000)   N*128 bf16
  //   srcw     [25,600,000, 51,200,000)   E int2, dst-sorted
  //   bucketed [51,200,000, 76,800,000)   E uint2, bucket-partitioned
  //   offsets  [76,800,000, 77,200,064)   N+1 int
  //   histG    [77,200,064, 77,506,624)   NB*NBLK int
  //   h1b      [77,506,624, 90,306,624)   N*64 bf16 (pitch-64, 128 B rows)
  //   w1f      [90,306,624, 90,318,912)   768 uint4 (pre-swizzled W1 B-frags)
  //   w0f      [90,318,912, 90,384,448)   4096 uint4 (pre-swizzled W0 B-frags)
  //   bsum     [90,384,448, 90,385,232)   NB int (per-bucket edge totals)
  char* ws = (char*)d_ws;
  unsigned int* h0b2 = (unsigned int*)(ws);
  int2*  srcw     = (int2*)(ws + 25600000);
  uint2* bucketed = (uint2*)(ws + 51200000);
  int*   offsets  = (int*)(ws + 76800000);
  int*   histG    = (int*)(ws + 77200064);
  unsigned short* h1b = (unsigned short*)(ws + 77506624);
  uint4* w1f      = (uint4*)(ws + 90306624);
  uint4* w0f      = (uint4*)(ws + 90318912);
  int*   bsum     = (int*)(ws + 90384448);

  hipMemsetAsync(bsum, 0, NB * sizeof(int), stream);
  p1hist_kernel<<<NBLK + 9, 256, 0, stream>>>(dst, histG, W1, w1f, W0, w0f, bsum);
  bscan_gemm0_kernel<<<NB + G0BLKS, 256, 0, stream>>>(
      bsum, histG, x, w0f, (unsigned short*)h0b2);
  p1scatter_kernel<<<NBLK, 256, 0, stream>>>(src, dst, ew, histG, bucketed);
  p2place_kernel<<<NB, 256, 0, stream>>>(bucketed, histG, offsets, srcw);

  gather0_gemm1_kernel<<<N_NODES / 4, 256, 0, stream>>>(
      (const uint4*)h0b2, srcw, offsets, b0, (const uint4*)w1f, h1b);
  gather1_lsm_kernel<<<N_NODES / 4, 256, 0, stream>>>(
      (const uint4*)h1b, srcw, offsets, b1, out);
}

// Round 11
// 475.637 us; speedup vs baseline: 1.6744x; 1.0570x over previous
//
#include <hip/hip_runtime.h>
#include <hip/hip_bf16.h>
#include <cstdint>
#include <cstddef>

#define N_NODES   100000
#define N_EDGES   3200000
#define IN_FEATS  256
#define N_HIDDEN  128
#define OUT_FEATS 40

// Bucket partition: bucket = dst >> 9 (512 nodes/bucket)
#define NB        196
#define EPB       8192
#define NBLK      391
#define HIST_M    (NB * NBLK)
#define N_TILES   3125            // 100000 / 32
#define TPB       2               // gemm0 tiles per block
#define G0BLKS    ((N_TILES + TPB - 1) / TPB)   // 1563

// fp8 h0 path: halves gather0 traffic (819->410 MB) + cheaper HW decode.
// Guarded: falls back to bf16 h0 (R10 behavior) if builtins are missing.
#if defined(__has_builtin)
#  if __has_builtin(__builtin_amdgcn_cvt_pk_f32_fp8) && \
      __has_builtin(__builtin_amdgcn_cvt_pk_fp8_f32)
#    define USE_FP8_H0 1
#  endif
#endif
#ifndef USE_FP8_H0
#  define USE_FP8_H0 0
#endif

typedef __attribute__((ext_vector_type(8))) __bf16 bf16x8;
typedef __attribute__((ext_vector_type(4))) float f32x4;
typedef __attribute__((ext_vector_type(2))) float f32x2;

// packed fp32 FMA: acc(2 feats) += unpack2_bf16(u) * w2 (contracts to pk_fma)
__device__ __forceinline__ void pkfma(f32x2& a, unsigned int u, f32x2 w2) {
  f32x2 b;
  b.x = __uint_as_float(u << 16);
  b.y = __uint_as_float(u & 0xFFFF0000u);
  a += b * w2;
}

// accumulate a uint4 (8 bf16 feats) into f32x2 A_[4]
#define ACC8P(A_, V_, W2_)   \
  pkfma(A_[0], (V_).x, W2_); \
  pkfma(A_[1], (V_).y, W2_); \
  pkfma(A_[2], (V_).z, W2_); \
  pkfma(A_[3], (V_).w, W2_);

#if USE_FP8_H0
// accumulate a uint4 (16 fp8 feats) into f32x2 A_[8] via HW cvt (1 op/2 feats)
#define FP8ACC(A_, V_, W2_) {                                          \
  f32x2 d_;                                                            \
  d_ = __builtin_amdgcn_cvt_pk_f32_fp8((V_).x, false); A_[0] += d_ * (W2_); \
  d_ = __builtin_amdgcn_cvt_pk_f32_fp8((V_).x, true ); A_[1] += d_ * (W2_); \
  d_ = __builtin_amdgcn_cvt_pk_f32_fp8((V_).y, false); A_[2] += d_ * (W2_); \
  d_ = __builtin_amdgcn_cvt_pk_f32_fp8((V_).y, true ); A_[3] += d_ * (W2_); \
  d_ = __builtin_amdgcn_cvt_pk_f32_fp8((V_).z, false); A_[4] += d_ * (W2_); \
  d_ = __builtin_amdgcn_cvt_pk_f32_fp8((V_).z, true ); A_[5] += d_ * (W2_); \
  d_ = __builtin_amdgcn_cvt_pk_f32_fp8((V_).w, false); A_[6] += d_ * (W2_); \
  d_ = __builtin_amdgcn_cvt_pk_f32_fp8((V_).w, true ); A_[7] += d_ * (W2_); }
#endif

// ---------------------------------------------------------------------------
// GEMM0 block body (MFMA): h0 = q(bf16(x) @ bf16(W0)), 32 rows x 128 cols per
// tile. h0 stored fp8 e4m3 (128 B rows) when available, else bf16 (256 B).
// ---------------------------------------------------------------------------
__device__ __forceinline__ void gemm0_block(
    int bid, const float* __restrict__ x, const uint4* __restrict__ w0f,
    unsigned char* __restrict__ h0) {
  __shared__ __align__(16) unsigned short xb[32 * 264];
  const int tid  = threadIdx.x;
  const int lane = tid & 63;
  const int wave = tid >> 6;
  const int rb   = wave & 1;
  const int ch   = wave >> 1;
  const int l15  = lane & 15;
  const int g    = lane >> 4;

  bf16x8 Bf[4][8];
#pragma unroll
  for (int cb = 0; cb < 4; ++cb)
#pragma unroll
    for (int q = 0; q < 8; ++q)
      Bf[cb][q] = __builtin_bit_cast(bf16x8, w0f[((ch * 4 + cb) * 8 + q) * 64 + lane]);

  for (int t = 0; t < TPB; ++t) {
    const int tile = bid * TPB + t;
    if (tile >= N_TILES) break;
    const int row0 = tile * 32;
    __syncthreads();
    for (int i = tid; i < 32 * 128; i += 256) {
      const int row = i >> 7, kp = i & 127;
      const float2 v = *(const float2*)(x + (size_t)(row0 + row) * IN_FEATS + kp * 2);
      __hip_bfloat162 p;
      p.x = __float2bfloat16(v.x);
      p.y = __float2bfloat16(v.y);
      *(unsigned int*)&xb[row * 264 + kp * 2] = *(unsigned int*)&p;
    }
    __syncthreads();

    f32x4 acc[4];
#pragma unroll
    for (int cb = 0; cb < 4; ++cb) acc[cb] = (f32x4){0.f, 0.f, 0.f, 0.f};

#pragma unroll
    for (int q = 0; q < 8; ++q) {
      const bf16x8 a = *(const bf16x8*)&xb[(rb * 16 + l15) * 264 + q * 32 + g * 8];
      acc[0] = __builtin_amdgcn_mfma_f32_16x16x32_bf16(a, Bf[0][q], acc[0], 0, 0, 0);
      acc[1] = __builtin_amdgcn_mfma_f32_16x16x32_bf16(a, Bf[1][q], acc[1], 0, 0, 0);
      acc[2] = __builtin_amdgcn_mfma_f32_16x16x32_bf16(a, Bf[2][q], acc[2], 0, 0, 0);
      acc[3] = __builtin_amdgcn_mfma_f32_16x16x32_bf16(a, Bf[3][q], acc[3], 0, 0, 0);
    }

#pragma unroll
    for (int cb = 0; cb < 4; ++cb) {
      const int col = ch * 64 + cb * 16 + l15;
#pragma unroll
      for (int r = 0; r < 4; ++r) {
        const int row = row0 + rb * 16 + g * 4 + r;
#if USE_FP8_H0
        const int pk = __builtin_amdgcn_cvt_pk_fp8_f32(acc[cb][r], acc[cb][r], 0, false);
        h0[(size_t)row * N_HIDDEN + col] = (unsigned char)(pk & 0xFF);
#else
        __hip_bfloat16 hb = __float2bfloat16(acc[cb][r]);
        ((unsigned short*)h0)[(size_t)row * N_HIDDEN + col] = *(unsigned short*)&hb;
#endif
      }
    }
  }
}

// ---------------------------------------------------------------------------
// Parallel 2-level scan: block b computes bucket b's base by reducing
// bsum[0..b-1] (L2-hit), then pair-scans its own 391 contiguous entries.
// ---------------------------------------------------------------------------
__device__ __forceinline__ void bucket_scan_block(
    int b, const int* __restrict__ bsum, int* __restrict__ histG) {
  __shared__ int sh[256];
  __shared__ int pr[256];
  const int t = threadIdx.x;

  sh[t] = (t < b) ? bsum[t] : 0;          // b <= 195 < 256
  __syncthreads();
#pragma unroll
  for (int off = 128; off > 0; off >>= 1) {
    if (t < off) sh[t] += sh[t + off];
    __syncthreads();
  }
  const int base = sh[0];

  const int row = b * NBLK;
  const int i0 = 2 * t, i1 = 2 * t + 1;
  int a = 0, c = 0;
  if (t < 196) {
    a = histG[row + i0];                  // i0 <= 390
    if (i1 < NBLK) c = histG[row + i1];
  }
  pr[t] = a + c;
  __syncthreads();
  for (int off = 1; off < 256; off <<= 1) {
    int v = (t >= off) ? pr[t - off] : 0;
    __syncthreads();
    pr[t] += v;
    __syncthreads();
  }
  if (t < 196) {
    const int ebase = (t > 0) ? pr[t - 1] : 0;
    histG[row + i0] = base + ebase;
    if (i1 < NBLK) histG[row + i1] = base + ebase + a;
  }
}

// Combo: blocks 0..195 = parallel bucket scans, blocks 196.. = gemm0.
__global__ __launch_bounds__(256) void bscan_gemm0_kernel(
    const int* __restrict__ bsum, int* __restrict__ histG,
    const float* __restrict__ x, const uint4* __restrict__ w0f,
    unsigned char* __restrict__ h0) {
  if (blockIdx.x < NB) bucket_scan_block(blockIdx.x, bsum, histG);
  else                 gemm0_block(blockIdx.x - NB, x, w0f, h0);
}

// ---------------------------------------------------------------------------
// p1hist: blocks 0..NBLK-1 = histogram (+ bsum accumulate);
// block NBLK = W1 pre-swizzle; blocks NBLK+1..NBLK+8 = W0 pre-swizzle.
// ---------------------------------------------------------------------------
__global__ __launch_bounds__(256) void p1hist_kernel(
    const int* __restrict__ dst, int* __restrict__ histG,
    const float* __restrict__ W1, uint4* __restrict__ w1f,
    const float* __restrict__ W0, uint4* __restrict__ w0f,
    int* __restrict__ bsum) {
  const int tid = threadIdx.x;
  const int blk = blockIdx.x;

  if (blk >= NBLK) {
    if (blk == NBLK) {                    // W1 fragment converter (40 cols, pad)
      for (int t = tid; t < 3 * 4 * 64; t += 256) {
        const int ln  = t & 63;
        const int qq  = (t >> 6) & 3;
        const int nt  = t >> 8;
        const int l15 = ln & 15;
        const int gg  = ln >> 4;
        const int c   = nt * 16 + l15;
        const int k0  = qq * 32 + gg * 8;
        uint4 u;
        __hip_bfloat162 p;
#define W1AT(i_) ((c < OUT_FEATS) ? W1[(size_t)(k0 + (i_)) * OUT_FEATS + c] : 0.f)
        p.x = __float2bfloat16(W1AT(0)); p.y = __float2bfloat16(W1AT(1));
        u.x = *(unsigned int*)&p;
        p.x = __float2bfloat16(W1AT(2)); p.y = __float2bfloat16(W1AT(3));
        u.y = *(unsigned int*)&p;
        p.x = __float2bfloat16(W1AT(4)); p.y = __float2bfloat16(W1AT(5));
        u.z = *(unsigned int*)&p;
        p.x = __float2bfloat16(W1AT(6)); p.y = __float2bfloat16(W1AT(7));
        u.w = *(unsigned int*)&p;
#undef W1AT
        w1f[t] = u;
      }
    } else {                              // W0 fragment converter (128 cols)
      const int pb = blk - NBLK - 1;      // 0..7
      for (int fi = pb * 512 + tid; fi < pb * 512 + 512; fi += 256) {
        const int ln  = fi & 63;
        const int qq  = (fi >> 6) & 7;
        const int ct  = fi >> 9;
        const int col = ct * 16 + (ln & 15);
        const int k0  = qq * 32 + (ln >> 4) * 8;
        uint4 u;
        __hip_bfloat162 p;
        p.x = __float2bfloat16(W0[(size_t)(k0 + 0) * N_HIDDEN + col]);
        p.y = __float2bfloat16(W0[(size_t)(k0 + 1) * N_HIDDEN + col]);
        u.x = *(unsigned int*)&p;
        p.x = __float2bfloat16(W0[(size_t)(k0 + 2) * N_HIDDEN + col]);
        p.y = __float2bfloat16(W0[(size_t)(k0 + 3) * N_HIDDEN + col]);
        u.y = *(unsigned int*)&p;
        p.x = __float2bfloat16(W0[(size_t)(k0 + 4) * N_HIDDEN + col]);
        p.y = __float2bfloat16(W0[(size_t)(k0 + 5) * N_HIDDEN + col]);
        u.z = *(unsigned int*)&p;
        p.x = __float2bfloat16(W0[(size_t)(k0 + 6) * N_HIDDEN + col]);
        p.y = __float2bfloat16(W0[(size_t)(k0 + 7) * N_HIDDEN + col]);
        u.w = *(unsigned int*)&p;
        w0f[fi] = u;
      }
    }
    return;
  }

  __shared__ int lh[NB];
  for (int i = tid; i < NB; i += 256) lh[i] = 0;
  __syncthreads();

  const int e0 = blk * EPB;
  const int e1 = min(e0 + EPB, N_EDGES);
  for (int i = e0 + tid; i < e1; i += 256)
    atomicAdd(&lh[dst[i] >> 9], 1);
  __syncthreads();

  for (int i = tid; i < NB; i += 256) {
    histG[i * NBLK + blk] = lh[i];
    atomicAdd(&bsum[i], lh[i]);
  }
}

// ---------------------------------------------------------------------------
// p1scatter: LDS-staged, bucket-contiguous global writes (R7 lesson: direct
// node-level scatter = 7.7x write amplification + cross-XCD atomic bounce).
// ---------------------------------------------------------------------------
__global__ __launch_bounds__(256) void p1scatter_kernel(
    const int* __restrict__ src, const int* __restrict__ dst,
    const float* __restrict__ ew, const int* __restrict__ histG,
    uint2* __restrict__ bucketed) {
  __shared__ uint2 stage[EPB];          // 64 KB
  __shared__ unsigned char sbkt[EPB];   // 8 KB
  __shared__ int lcnt[NB];
  __shared__ int lbase[NB];
  __shared__ int spart[256];
  const int tid = threadIdx.x;
  const int blk = blockIdx.x;
  const int e0 = blk * EPB;
  const int e1 = min(e0 + EPB, N_EDGES);

  for (int i = tid; i < NB; i += 256) lcnt[i] = 0;
  __syncthreads();

  for (int i = e0 + tid; i < e1; i += 256)
    atomicAdd(&lcnt[dst[i] >> 9], 1);
  __syncthreads();

  const int myv = (tid < NB) ? lcnt[tid] : 0;
  spart[tid] = myv;
  __syncthreads();
  for (int off = 1; off < 256; off <<= 1) {
    int u = (tid >= off) ? spart[tid - off] : 0;
    __syncthreads();
    spart[tid] += u;
    __syncthreads();
  }
  if (tid < NB) { lbase[tid] = spart[tid] - myv; lcnt[tid] = spart[tid] - myv; }
  __syncthreads();

  for (int i = e0 + tid; i < e1; i += 256) {
    const int d = dst[i];
    const int b = d >> 9;
    const int pos = atomicAdd(&lcnt[b], 1);
    stage[pos] = make_uint2((unsigned)src[i] | ((unsigned)(d & 511) << 17),
                            __float_as_uint(ew[i]));
    sbkt[pos] = (unsigned char)b;
  }
  __syncthreads();

  const int n = e1 - e0;
  for (int i = tid; i < n; i += 256) {
    const int b = sbkt[i];
    const int gpos = histG[b * NBLK + blk] + (i - lbase[b]);
    bucketed[gpos] = stage[i];
  }
}

__global__ __launch_bounds__(256) void p2place_kernel(
    const uint2* __restrict__ bucketed, const int* __restrict__ histG,
    int* __restrict__ offsets, int2* __restrict__ srcw) {
  __shared__ int cnt[512];
  __shared__ int part[256];
  const int t = threadIdx.x;
  const int b = blockIdx.x;
  const int node0 = b << 9;
  const int beg = histG[b * NBLK];
  const int end = (b == NB - 1) ? N_EDGES : histG[(b + 1) * NBLK];

  cnt[t] = 0; cnt[t + 256] = 0;
  __syncthreads();

  for (int j = beg + t; j < end; j += 256)
    atomicAdd(&cnt[bucketed[j].x >> 17], 1);
  __syncthreads();

  const int a0 = cnt[2 * t];
  const int a1 = cnt[2 * t + 1];
  part[t] = a0 + a1;
  __syncthreads();
  for (int off = 1; off < 256; off <<= 1) {
    int v = (t >= off) ? part[t - off] : 0;
    __syncthreads();
    part[t] += v;
    __syncthreads();
  }
  const int base = (t > 0) ? part[t - 1] : 0;

  const int o0 = beg + base;
  const int o1 = o0 + a0;
  cnt[2 * t]     = o0;
  cnt[2 * t + 1] = o1;
  const int n0 = node0 + 2 * t;
  if (n0 < N_NODES)     offsets[n0]     = o0;
  if (n0 + 1 < N_NODES) offsets[n0 + 1] = o1;
  if (b == NB - 1 && t == 0) offsets[N_NODES] = N_EDGES;
  __syncthreads();

  for (int j = beg + t; j < end; j += 256) {
    const uint2 en = bucketed[j];
    const int slot = atomicAdd(&cnt[en.x >> 17], 1);
    srcw[slot] = make_int2((int)(en.x & 0x1FFFFu), (int)en.y);
  }
}

// ---------------------------------------------------------------------------
// Fused gather0 + bias + ReLU + MFMA GEMM1 epilogue.
// fp8 path: 8 lanes/edge x dwordx4 covers a full 128 B fp8 row; HW
// cvt_pk_f32_fp8 decode (1 op / 2 feats). Bytes/edge halved vs bf16.
// ---------------------------------------------------------------------------
#if USE_FP8_H0
__global__ __launch_bounds__(256) void gather0_gemm1_kernel(
    const uint4* __restrict__ h0q, const int2* __restrict__ srcw,
    const int* __restrict__ offsets, const float* __restrict__ b0,
    const uint4* __restrict__ w1f, unsigned short* __restrict__ h1b) {
  __shared__ float hs[4][132];
  const int wave = threadIdx.x >> 6;
  const int lane = threadIdx.x & 63;
  const int node = blockIdx.x * 4 + wave;
  const int g  = lane >> 3;         // edge slot 0..7 within an 8-edge group
  const int fl = lane & 7;          // feature chunk: feats [fl*16, fl*16+16)

  const int beg = __builtin_amdgcn_readfirstlane(offsets[node]);
  const int end = __builtin_amdgcn_readfirstlane(offsets[node + 1]);

  f32x2 acc[8];
#pragma unroll
  for (int i = 0; i < 8; ++i) acc[i] = (f32x2){0.f, 0.f};

  if (end > beg) {
    const int e1 = end - 1;
    int2 sa = srcw[min(beg + g, e1)];
    int2 sb = srcw[min(beg + 8 + g, e1)];
    for (int j = beg; j < end; j += 16) {
      const float wa = (j + g < end)     ? __int_as_float(sa.y) : 0.f;
      const float wb = (j + 8 + g < end) ? __int_as_float(sb.y) : 0.f;
      const uint4 va = h0q[(size_t)(unsigned)sa.x * 8 + fl];
      const uint4 vb = h0q[(size_t)(unsigned)sb.x * 8 + fl];
      const int jn = j + 16;
      if (jn < end) {                 // prefetch next groups' meta
        sa = srcw[min(jn + g, e1)];
        sb = srcw[min(jn + 8 + g, e1)];
      }
      const f32x2 pa = {wa, wa};
      const f32x2 pb = {wb, wb};
      FP8ACC(acc, va, pa)
      FP8ACC(acc, vb, pb)
    }
  }

  // reduce across the 8 edge-groups (lane bits 3,4,5)
#pragma unroll
  for (int i = 0; i < 8; ++i) {
    acc[i].x += __shfl_xor(acc[i].x, 8);
    acc[i].x += __shfl_xor(acc[i].x, 16);
    acc[i].x += __shfl_xor(acc[i].x, 32);
    acc[i].y += __shfl_xor(acc[i].y, 8);
    acc[i].y += __shfl_xor(acc[i].y, 16);
    acc[i].y += __shfl_xor(acc[i].y, 32);
  }

  // bias + ReLU, one eighth-wave (8 lanes) writes the 128-float row to LDS
  if (g == 0) {
    const int f0 = fl * 16;
#pragma unroll
    for (int jj = 0; jj < 4; ++jj) {
      const float v0 = acc[2 * jj].x     + b0[f0 + 4 * jj + 0];
      const float v1 = acc[2 * jj].y     + b0[f0 + 4 * jj + 1];
      const float v2 = acc[2 * jj + 1].x + b0[f0 + 4 * jj + 2];
      const float v3 = acc[2 * jj + 1].y + b0[f0 + 4 * jj + 3];
      *(float4*)&hs[wave][f0 + 4 * jj] = make_float4(
          v0 > 0.f ? v0 : 0.f, v1 > 0.f ? v1 : 0.f,
          v2 > 0.f ? v2 : 0.f, v3 > 0.f ? v3 : 0.f);
    }
  }
  __syncthreads();

  // --- MFMA epilogue: h1 = hs(4x128) @ W1(128x40), waves 0-2 = N-tiles ---
  const int l15 = lane & 15;
  const int gg  = lane >> 4;
  if (wave < 3) {
    f32x4 c = {0.f, 0.f, 0.f, 0.f};
#pragma unroll
    for (int qq = 0; qq < 4; ++qq) {
      uint4 ua = make_uint4(0, 0, 0, 0);
      if (l15 < 4) {                      // A rows 0-3 = this block's nodes
        const float* hrow = &hs[l15][qq * 32 + gg * 8];
        __hip_bfloat162 p;
        p.x = __float2bfloat16(hrow[0]); p.y = __float2bfloat16(hrow[1]);
        ua.x = *(unsigned int*)&p;
        p.x = __float2bfloat16(hrow[2]); p.y = __float2bfloat16(hrow[3]);
        ua.y = *(unsigned int*)&p;
        p.x = __float2bfloat16(hrow[4]); p.y = __float2bfloat16(hrow[5]);
        ua.z = *(unsigned int*)&p;
        p.x = __float2bfloat16(hrow[6]); p.y = __float2bfloat16(hrow[7]);
        ua.w = *(unsigned int*)&p;
      }
      const uint4 ub = w1f[(wave * 4 + qq) * 64 + lane];
      c = __builtin_amdgcn_mfma_f32_16x16x32_bf16(
            __builtin_bit_cast(bf16x8, ua), __builtin_bit_cast(bf16x8, ub),
            c, 0, 0, 0);
    }
    if (gg == 0) {
#pragma unroll
      for (int r = 0; r < 4; ++r) {
        const int nodeR = blockIdx.x * 4 + r;
        const int f = wave * 16 + l15;    // 0..47
        __hip_bfloat16 hb = __float2bfloat16(c[r]);
        h1b[(size_t)nodeR * 64 + f] = *(unsigned short*)&hb;
      }
    }
  } else {
    if (gg == 0) {
#pragma unroll
      for (int r = 0; r < 4; ++r) {
        const int nodeR = blockIdx.x * 4 + r;
        h1b[(size_t)nodeR * 64 + 48 + l15] = 0;
      }
    }
  }
}
#else
// bf16 fallback (R10 version): 16 lanes/edge, 4 edge-groups in flight.
__global__ __launch_bounds__(256) void gather0_gemm1_kernel(
    const uint4* __restrict__ h0q, const int2* __restrict__ srcw,
    const int* __restrict__ offsets, const float* __restrict__ b0,
    const uint4* __restrict__ w1f, unsigned short* __restrict__ h1b) {
  __shared__ float hs[4][132];
  const int wave = threadIdx.x >> 6;
  const int lane = threadIdx.x & 63;
  const int node = blockIdx.x * 4 + wave;
  const int q    = lane >> 4;
  const int fl   = lane & 15;

  const int beg = __builtin_amdgcn_readfirstlane(offsets[node]);
  const int end = __builtin_amdgcn_readfirstlane(offsets[node + 1]);

  f32x2 acc[4];
#pragma unroll
  for (int i = 0; i < 4; ++i) acc[i] = (f32x2){0.f, 0.f};

  if (end > beg) {
    const int e1 = end - 1;
    int2 sa = srcw[min(beg + q, e1)];
    int2 sb = srcw[min(beg + 4 + q, e1)];
    int2 sc = srcw[min(beg + 8 + q, e1)];
    int2 sd = srcw[min(beg + 12 + q, e1)];
    for (int j = beg; j < end; j += 16) {
      const float wa = (j + q < end)      ? __int_as_float(sa.y) : 0.f;
      const float wb = (j + 4 + q < end)  ? __int_as_float(sb.y) : 0.f;
      const float wc = (j + 8 + q < end)  ? __int_as_float(sc.y) : 0.f;
      const float wd = (j + 12 + q < end) ? __int_as_float(sd.y) : 0.f;
      const uint4 va = h0q[(size_t)(unsigned)sa.x * 16 + fl];
      const uint4 vb = h0q[(size_t)(unsigned)sb.x * 16 + fl];
      const uint4 vc = h0q[(size_t)(unsigned)sc.x * 16 + fl];
      const uint4 vd = h0q[(size_t)(unsigned)sd.x * 16 + fl];
      const int jn = j + 16;
      if (jn < end) {
        sa = srcw[min(jn + q, e1)];
        sb = srcw[min(jn + 4 + q, e1)];
        sc = srcw[min(jn + 8 + q, e1)];
        sd = srcw[min(jn + 12 + q, e1)];
      }
      const f32x2 pa = {wa, wa};
      const f32x2 pb = {wb, wb};
      const f32x2 pc = {wc, wc};
      const f32x2 pd = {wd, wd};
      ACC8P(acc, va, pa)
      ACC8P(acc, vb, pb)
      ACC8P(acc, vc, pc)
      ACC8P(acc, vd, pd)
    }
  }

#pragma unroll
  for (int i = 0; i < 4; ++i) {
    acc[i].x += __shfl_xor(acc[i].x, 16);
    acc[i].x += __shfl_xor(acc[i].x, 32);
    acc[i].y += __shfl_xor(acc[i].y, 16);
    acc[i].y += __shfl_xor(acc[i].y, 32);
  }

  if (q == 0) {
    const int f0 = fl * 8;
    float t[8];
#pragma unroll
    for (int i = 0; i < 8; ++i) {
      const float a = ((i & 1) ? acc[i >> 1].y : acc[i >> 1].x);
      const float v = a + b0[f0 + i];
      t[i] = v > 0.f ? v : 0.f;
    }
    *(float4*)&hs[wave][f0]     = make_float4(t[0], t[1], t[2], t[3]);
    *(float4*)&hs[wave][f0 + 4] = make_float4(t[4], t[5], t[6], t[7]);
  }
  __syncthreads();

  const int l15 = lane & 15;
  const int gg  = lane >> 4;
  if (wave < 3) {
    f32x4 c = {0.f, 0.f, 0.f, 0.f};
#pragma unroll
    for (int qq = 0; qq < 4; ++qq) {
      uint4 ua = make_uint4(0, 0, 0, 0);
      if (l15 < 4) {
        const float* hrow = &hs[l15][qq * 32 + gg * 8];
        __hip_bfloat162 p;
        p.x = __float2bfloat16(hrow[0]); p.y = __float2bfloat16(hrow[1]);
        ua.x = *(unsigned int*)&p;
        p.x = __float2bfloat16(hrow[2]); p.y = __float2bfloat16(hrow[3]);
        ua.y = *(unsigned int*)&p;
        p.x = __float2bfloat16(hrow[4]); p.y = __float2bfloat16(hrow[5]);
        ua.z = *(unsigned int*)&p;
        p.x = __float2bfloat16(hrow[6]); p.y = __float2bfloat16(hrow[7]);
        ua.w = *(unsigned int*)&p;
      }
      const uint4 ub = w1f[(wave * 4 + qq) * 64 + lane];
      c = __builtin_amdgcn_mfma_f32_16x16x32_bf16(
            __builtin_bit_cast(bf16x8, ua), __builtin_bit_cast(bf16x8, ub),
            c, 0, 0, 0);
    }
    if (gg == 0) {
#pragma unroll
      for (int r = 0; r < 4; ++r) {
        const int nodeR = blockIdx.x * 4 + r;
        const int f = wave * 16 + l15;
        __hip_bfloat16 hb = __float2bfloat16(c[r]);
        h1b[(size_t)nodeR * 64 + f] = *(unsigned short*)&hb;
      }
    }
  } else {
    if (gg == 0) {
#pragma unroll
      for (int r = 0; r < 4; ++r) {
        const int nodeR = blockIdx.x * 4 + r;
        h1b[(size_t)nodeR * 64 + 48 + l15] = 0;
      }
    }
  }
}
#endif

// ---------------------------------------------------------------------------
// Fused gather1 + bias + log_softmax on uniform pitch-64 h1 rows (bf16).
// 8 lanes/edge x uint4, 4 edge-groups in flight (32 edges/iter).
// ---------------------------------------------------------------------------
__global__ __launch_bounds__(256) void gather1_lsm_kernel(
    const uint4* __restrict__ h1q, const int2* __restrict__ srcw,
    const int* __restrict__ offsets, const float* __restrict__ b1,
    float* __restrict__ out) {
  const int wave = threadIdx.x >> 6;
  const int lane = threadIdx.x & 63;
  const int node = blockIdx.x * 4 + wave;
  const int g  = lane >> 3;         // edge slot 0..7 within an 8-edge group
  const int fl = lane & 7;          // feats [fl*8, fl*8+8) of the 64-pitch row

  const int beg = __builtin_amdgcn_readfirstlane(offsets[node]);
  const int end = __builtin_amdgcn_readfirstlane(offsets[node + 1]);

  f32x2 acc[4];
#pragma unroll
  for (int i = 0; i < 4; ++i) acc[i] = (f32x2){0.f, 0.f};

  if (end > beg) {
    const int e1 = end - 1;
    int2 sa = srcw[min(beg + g, e1)];
    int2 sb = srcw[min(beg + 8 + g, e1)];
    int2 sc = srcw[min(beg + 16 + g, e1)];
    int2 sd = srcw[min(beg + 24 + g, e1)];
    for (int j = beg; j < end; j += 32) {
      const float wa = (j + g < end)      ? __int_as_float(sa.y) : 0.f;
      const float wb = (j + 8 + g < end)  ? __int_as_float(sb.y) : 0.f;
      const float wc = (j + 16 + g < end) ? __int_as_float(sc.y) : 0.f;
      const float wd = (j + 24 + g < end) ? __int_as_float(sd.y) : 0.f;
      const uint4 va = h1q[(size_t)(unsigned)sa.x * 8 + fl];
      const uint4 vb = h1q[(size_t)(unsigned)sb.x * 8 + fl];
      const uint4 vc = h1q[(size_t)(unsigned)sc.x * 8 + fl];
      const uint4 vd = h1q[(size_t)(unsigned)sd.x * 8 + fl];
      const int jn = j + 32;
      if (jn < end) {
        sa = srcw[min(jn + g, e1)];
        sb = srcw[min(jn + 8 + g, e1)];
        sc = srcw[min(jn + 16 + g, e1)];
        sd = srcw[min(jn + 24 + g, e1)];
      }
      const f32x2 pa = {wa, wa};
      const f32x2 pb = {wb, wb};
      const f32x2 pc = {wc, wc};
      const f32x2 pd = {wd, wd};
      ACC8P(acc, va, pa)
      ACC8P(acc, vb, pb)
      ACC8P(acc, vc, pc)
      ACC8P(acc, vd, pd)
    }
  }

  // reduce across the 8 edge-groups (lane bits 3,4,5)
  float o[8];
#pragma unroll
  for (int i = 0; i < 4; ++i) {
    float x0 = acc[i].x, y0 = acc[i].y;
    x0 += __shfl_xor(x0, 8); x0 += __shfl_xor(x0, 16); x0 += __shfl_xor(x0, 32);
    y0 += __shfl_xor(y0, 8); y0 += __shfl_xor(y0, 16); y0 += __shfl_xor(y0, 32);
    o[2 * i] = x0; o[2 * i + 1] = y0;
  }

  const bool valid = (fl < 5);      // feats fl*8..fl*8+7 < 40
  float m = -INFINITY;
  if (valid) {
    const int f0 = fl * 8;
#pragma unroll
    for (int i = 0; i < 8; ++i) {
      o[i] += b1[f0 + i];
      m = fmaxf(m, o[i]);
    }
  }
  m = fmaxf(m, __shfl_xor(m, 1));
  m = fmaxf(m, __shfl_xor(m, 2));
  m = fmaxf(m, __shfl_xor(m, 4));

  float s = 0.f;
  if (valid) {
#pragma unroll
    for (int i = 0; i < 8; ++i) s += expf(o[i] - m);
  }
  s += __shfl_xor(s, 1);
  s += __shfl_xor(s, 2);
  s += __shfl_xor(s, 4);

  if (lane < 5) {                   // g==0 && fl<5: write all 40 outputs
    const float lse = m + logf(s);
    float* op = out + (size_t)node * OUT_FEATS + fl * 8;
    *(float4*)op       = make_float4(o[0] - lse, o[1] - lse,
                                     o[2] - lse, o[3] - lse);
    *(float4*)(op + 4) = make_float4(o[4] - lse, o[5] - lse,
                                     o[6] - lse, o[7] - lse);
  }
}

// ---------------------------------------------------------------------------
extern "C" void kernel_launch(void* const* d_in, const int* in_sizes, int n_in,
                              void* d_out, int out_size, void* d_ws, size_t ws_size,
                              hipStream_t stream) {
  const float* x   = (const float*)d_in[0];
  const float* W0  = (const float*)d_in[1];
  const float* b0  = (const float*)d_in[2];
  const float* W1  = (const float*)d_in[3];
  const float* b1  = (const float*)d_in[4];
  const float* ew  = (const float*)d_in[5];
  const int*   src = (const int*)d_in[6];
  const int*   dst = (const int*)d_in[7];
  float* out = (float*)d_out;

  // Workspace layout, peak ~90.4 MB (ws >= 102.4 MB):
  //   h0       [0,          25,600,000)   N*128 fp8 (12.8 MB used) or bf16
  //   srcw     [25,600,000, 51,200,000)   E int2, dst-sorted
  //   bucketed [51,200,000, 76,800,000)   E uint2, bucket-partitioned
  //   offsets  [76,800,000, 77,200,064)   N+1 int
  //   histG    [77,200,064, 77,506,624)   NB*NBLK int
  //   h1b      [77,506,624, 90,306,624)   N*64 bf16 (pitch-64, 128 B rows)
  //   w1f      [90,306,624, 90,318,912)   768 uint4 (pre-swizzled W1 B-frags)
  //   w0f      [90,318,912, 90,384,448)   4096 uint4 (pre-swizzled W0 B-frags)
  //   bsum     [90,384,448, 90,385,232)   NB int (per-bucket edge totals)
  char* ws = (char*)d_ws;
  unsigned char* h0 = (unsigned char*)(ws);
  int2*  srcw     = (int2*)(ws + 25600000);
  uint2* bucketed = (uint2*)(ws + 51200000);
  int*   offsets  = (int*)(ws + 76800000);
  int*   histG    = (int*)(ws + 77200064);
  unsigned short* h1b = (unsigned short*)(ws + 77506624);
  uint4* w1f      = (uint4*)(ws + 90306624);
  uint4* w0f      = (uint4*)(ws + 90318912);
  int*   bsum     = (int*)(ws + 90384448);

  hipMemsetAsync(bsum, 0, NB * sizeof(int), stream);
  p1hist_kernel<<<NBLK + 9, 256, 0, stream>>>(dst, histG, W1, w1f, W0, w0f, bsum);
  bscan_gemm0_kernel<<<NB + G0BLKS, 256, 0, stream>>>(
      bsum, histG, x, w0f, h0);
  p1scatter_kernel<<<NBLK, 256, 0, stream>>>(src, dst, ew, histG, bucketed);
  p2place_kernel<<<NB, 256, 0, stream>>>(bucketed, histG, offsets, srcw);

  gather0_gemm1_kernel<<<N_NODES / 4, 256, 0, stream>>>(
      (const uint4*)h0, srcw, offsets, b0, (const uint4*)w1f, h1b);
  gather1_lsm_kernel<<<N_NODES / 4, 256, 0, stream>>>(
      (const uint4*)h1b, srcw, offsets, b1, out);
}

// Round 12
// 443.434 us; speedup vs baseline: 1.7960x; 1.0726x over previous
//
#include <hip/hip_runtime.h>
#include <hip/hip_bf16.h>
#include <cstdint>
#include <cstddef>

#define N_NODES   100000
#define N_EDGES   3200000
#define IN_FEATS  256
#define N_HIDDEN  128
#define OUT_FEATS 40

// Bucket partition: bucket = dst >> 9 (512 nodes/bucket)
#define NB        196
#define EPB       8192
#define NBLK      391
#define HIST_M    (NB * NBLK)
#define N_TILES   3125            // 100000 / 32
#define TPB       2               // gemm0 tiles per block
#define G0BLKS    ((N_TILES + TPB - 1) / TPB)   // 1563

// fp8 h0 path (R11, verified: -27 us): halves gather0 traffic + HW decode.
#if defined(__has_builtin)
#  if __has_builtin(__builtin_amdgcn_cvt_pk_f32_fp8) && \
      __has_builtin(__builtin_amdgcn_cvt_pk_fp8_f32)
#    define USE_FP8_H0 1
#  endif
#endif
#ifndef USE_FP8_H0
#  define USE_FP8_H0 0
#endif

typedef __attribute__((ext_vector_type(8))) __bf16 bf16x8;
typedef __attribute__((ext_vector_type(4))) float f32x4;
typedef __attribute__((ext_vector_type(2))) float f32x2;

// packed fp32 FMA: acc(2 feats) += unpack2_bf16(u) * w2 (contracts to pk_fma)
__device__ __forceinline__ void pkfma(f32x2& a, unsigned int u, f32x2 w2) {
  f32x2 b;
  b.x = __uint_as_float(u << 16);
  b.y = __uint_as_float(u & 0xFFFF0000u);
  a += b * w2;
}

// accumulate a uint4 (8 bf16 feats) into f32x2 A_[4]
#define ACC8P(A_, V_, W2_)   \
  pkfma(A_[0], (V_).x, W2_); \
  pkfma(A_[1], (V_).y, W2_); \
  pkfma(A_[2], (V_).z, W2_); \
  pkfma(A_[3], (V_).w, W2_);

#if USE_FP8_H0
// accumulate a uint4 (16 fp8 feats) into f32x2 A_[8] via HW cvt (1 op/2 feats)
#define FP8ACC(A_, V_, W2_) {                                          \
  f32x2 d_;                                                            \
  d_ = __builtin_amdgcn_cvt_pk_f32_fp8((V_).x, false); A_[0] += d_ * (W2_); \
  d_ = __builtin_amdgcn_cvt_pk_f32_fp8((V_).x, true ); A_[1] += d_ * (W2_); \
  d_ = __builtin_amdgcn_cvt_pk_f32_fp8((V_).y, false); A_[2] += d_ * (W2_); \
  d_ = __builtin_amdgcn_cvt_pk_f32_fp8((V_).y, true ); A_[3] += d_ * (W2_); \
  d_ = __builtin_amdgcn_cvt_pk_f32_fp8((V_).z, false); A_[4] += d_ * (W2_); \
  d_ = __builtin_amdgcn_cvt_pk_f32_fp8((V_).z, true ); A_[5] += d_ * (W2_); \
  d_ = __builtin_amdgcn_cvt_pk_f32_fp8((V_).w, false); A_[6] += d_ * (W2_); \
  d_ = __builtin_amdgcn_cvt_pk_f32_fp8((V_).w, true ); A_[7] += d_ * (W2_); }
#endif

// ---------------------------------------------------------------------------
// GEMM0 block body (MFMA): h0 = q(bf16(x) @ bf16(W0)), 32 rows x 128 cols per
// tile. h0 stored fp8 e4m3 (128 B rows) when available, else bf16 (256 B).
// ---------------------------------------------------------------------------
__device__ __forceinline__ void gemm0_block(
    int bid, const float* __restrict__ x, const uint4* __restrict__ w0f,
    unsigned char* __restrict__ h0) {
  __shared__ __align__(16) unsigned short xb[32 * 264];
  const int tid  = threadIdx.x;
  const int lane = tid & 63;
  const int wave = tid >> 6;
  const int rb   = wave & 1;
  const int ch   = wave >> 1;
  const int l15  = lane & 15;
  const int g    = lane >> 4;

  bf16x8 Bf[4][8];
#pragma unroll
  for (int cb = 0; cb < 4; ++cb)
#pragma unroll
    for (int q = 0; q < 8; ++q)
      Bf[cb][q] = __builtin_bit_cast(bf16x8, w0f[((ch * 4 + cb) * 8 + q) * 64 + lane]);

  for (int t = 0; t < TPB; ++t) {
    const int tile = bid * TPB + t;
    if (tile >= N_TILES) break;
    const int row0 = tile * 32;
    __syncthreads();
    for (int i = tid; i < 32 * 128; i += 256) {
      const int row = i >> 7, kp = i & 127;
      const float2 v = *(const float2*)(x + (size_t)(row0 + row) * IN_FEATS + kp * 2);
      __hip_bfloat162 p;
      p.x = __float2bfloat16(v.x);
      p.y = __float2bfloat16(v.y);
      *(unsigned int*)&xb[row * 264 + kp * 2] = *(unsigned int*)&p;
    }
    __syncthreads();

    f32x4 acc[4];
#pragma unroll
    for (int cb = 0; cb < 4; ++cb) acc[cb] = (f32x4){0.f, 0.f, 0.f, 0.f};

#pragma unroll
    for (int q = 0; q < 8; ++q) {
      const bf16x8 a = *(const bf16x8*)&xb[(rb * 16 + l15) * 264 + q * 32 + g * 8];
      acc[0] = __builtin_amdgcn_mfma_f32_16x16x32_bf16(a, Bf[0][q], acc[0], 0, 0, 0);
      acc[1] = __builtin_amdgcn_mfma_f32_16x16x32_bf16(a, Bf[1][q], acc[1], 0, 0, 0);
      acc[2] = __builtin_amdgcn_mfma_f32_16x16x32_bf16(a, Bf[2][q], acc[2], 0, 0, 0);
      acc[3] = __builtin_amdgcn_mfma_f32_16x16x32_bf16(a, Bf[3][q], acc[3], 0, 0, 0);
    }

#pragma unroll
    for (int cb = 0; cb < 4; ++cb) {
      const int col = ch * 64 + cb * 16 + l15;
#pragma unroll
      for (int r = 0; r < 4; ++r) {
        const int row = row0 + rb * 16 + g * 4 + r;
#if USE_FP8_H0
        const int pk = __builtin_amdgcn_cvt_pk_fp8_f32(acc[cb][r], acc[cb][r], 0, false);
        h0[(size_t)row * N_HIDDEN + col] = (unsigned char)(pk & 0xFF);
#else
        __hip_bfloat16 hb = __float2bfloat16(acc[cb][r]);
        ((unsigned short*)h0)[(size_t)row * N_HIDDEN + col] = *(unsigned short*)&hb;
#endif
      }
    }
  }
}

// ---------------------------------------------------------------------------
// Parallel 2-level scan: block b computes bucket b's base by reducing
// bsum[0..b-1] (L2-hit), then pair-scans its own 391 contiguous entries.
// ---------------------------------------------------------------------------
__device__ __forceinline__ void bucket_scan_block(
    int b, const int* __restrict__ bsum, int* __restrict__ histG) {
  __shared__ int sh[256];
  __shared__ int pr[256];
  const int t = threadIdx.x;

  sh[t] = (t < b) ? bsum[t] : 0;          // b <= 195 < 256
  __syncthreads();
#pragma unroll
  for (int off = 128; off > 0; off >>= 1) {
    if (t < off) sh[t] += sh[t + off];
    __syncthreads();
  }
  const int base = sh[0];

  const int row = b * NBLK;
  const int i0 = 2 * t, i1 = 2 * t + 1;
  int a = 0, c = 0;
  if (t < 196) {
    a = histG[row + i0];                  // i0 <= 390
    if (i1 < NBLK) c = histG[row + i1];
  }
  pr[t] = a + c;
  __syncthreads();
  for (int off = 1; off < 256; off <<= 1) {
    int v = (t >= off) ? pr[t - off] : 0;
    __syncthreads();
    pr[t] += v;
    __syncthreads();
  }
  if (t < 196) {
    const int ebase = (t > 0) ? pr[t - 1] : 0;
    histG[row + i0] = base + ebase;
    if (i1 < NBLK) histG[row + i1] = base + ebase + a;
  }
}

__global__ __launch_bounds__(256) void bscan_kernel(
    const int* __restrict__ bsum, int* __restrict__ histG) {
  bucket_scan_block(blockIdx.x, bsum, histG);
}

// ---------------------------------------------------------------------------
// p1hist: blocks 0..NBLK-1 = histogram (+ bsum accumulate);
// block NBLK = W1 pre-swizzle; blocks NBLK+1..NBLK+8 = W0 pre-swizzle.
// ---------------------------------------------------------------------------
__global__ __launch_bounds__(256) void p1hist_kernel(
    const int* __restrict__ dst, int* __restrict__ histG,
    const float* __restrict__ W1, uint4* __restrict__ w1f,
    const float* __restrict__ W0, uint4* __restrict__ w0f,
    int* __restrict__ bsum) {
  const int tid = threadIdx.x;
  const int blk = blockIdx.x;

  if (blk >= NBLK) {
    if (blk == NBLK) {                    // W1 fragment converter (40 cols, pad)
      for (int t = tid; t < 3 * 4 * 64; t += 256) {
        const int ln  = t & 63;
        const int qq  = (t >> 6) & 3;
        const int nt  = t >> 8;
        const int l15 = ln & 15;
        const int gg  = ln >> 4;
        const int c   = nt * 16 + l15;
        const int k0  = qq * 32 + gg * 8;
        uint4 u;
        __hip_bfloat162 p;
#define W1AT(i_) ((c < OUT_FEATS) ? W1[(size_t)(k0 + (i_)) * OUT_FEATS + c] : 0.f)
        p.x = __float2bfloat16(W1AT(0)); p.y = __float2bfloat16(W1AT(1));
        u.x = *(unsigned int*)&p;
        p.x = __float2bfloat16(W1AT(2)); p.y = __float2bfloat16(W1AT(3));
        u.y = *(unsigned int*)&p;
        p.x = __float2bfloat16(W1AT(4)); p.y = __float2bfloat16(W1AT(5));
        u.z = *(unsigned int*)&p;
        p.x = __float2bfloat16(W1AT(6)); p.y = __float2bfloat16(W1AT(7));
        u.w = *(unsigned int*)&p;
#undef W1AT
        w1f[t] = u;
      }
    } else {                              // W0 fragment converter (128 cols)
      const int pb = blk - NBLK - 1;      // 0..7
      for (int fi = pb * 512 + tid; fi < pb * 512 + 512; fi += 256) {
        const int ln  = fi & 63;
        const int qq  = (fi >> 6) & 7;
        const int ct  = fi >> 9;
        const int col = ct * 16 + (ln & 15);
        const int k0  = qq * 32 + (ln >> 4) * 8;
        uint4 u;
        __hip_bfloat162 p;
        p.x = __float2bfloat16(W0[(size_t)(k0 + 0) * N_HIDDEN + col]);
        p.y = __float2bfloat16(W0[(size_t)(k0 + 1) * N_HIDDEN + col]);
        u.x = *(unsigned int*)&p;
        p.x = __float2bfloat16(W0[(size_t)(k0 + 2) * N_HIDDEN + col]);
        p.y = __float2bfloat16(W0[(size_t)(k0 + 3) * N_HIDDEN + col]);
        u.y = *(unsigned int*)&p;
        p.x = __float2bfloat16(W0[(size_t)(k0 + 4) * N_HIDDEN + col]);
        p.y = __float2bfloat16(W0[(size_t)(k0 + 5) * N_HIDDEN + col]);
        u.z = *(unsigned int*)&p;
        p.x = __float2bfloat16(W0[(size_t)(k0 + 6) * N_HIDDEN + col]);
        p.y = __float2bfloat16(W0[(size_t)(k0 + 7) * N_HIDDEN + col]);
        u.w = *(unsigned int*)&p;
        w0f[fi] = u;
      }
    }
    return;
  }

  __shared__ int lh[NB];
  for (int i = tid; i < NB; i += 256) lh[i] = 0;
  __syncthreads();

  const int e0 = blk * EPB;
  const int e1 = min(e0 + EPB, N_EDGES);
  for (int i = e0 + tid; i < e1; i += 256)
    atomicAdd(&lh[dst[i] >> 9], 1);
  __syncthreads();

  for (int i = tid; i < NB; i += 256) {
    histG[i * NBLK + blk] = lh[i];
    atomicAdd(&bsum[i], lh[i]);
  }
}

// ---------------------------------------------------------------------------
// p1scatter: LDS-staged, bucket-contiguous global writes (R7 lesson: direct
// node-level scatter = 7.7x write amplification + cross-XCD atomic bounce).
// ---------------------------------------------------------------------------
__global__ __launch_bounds__(256) void p1scatter_kernel(
    const int* __restrict__ src, const int* __restrict__ dst,
    const float* __restrict__ ew, const int* __restrict__ histG,
    uint2* __restrict__ bucketed) {
  __shared__ uint2 stage[EPB];          // 64 KB
  __shared__ unsigned char sbkt[EPB];   // 8 KB
  __shared__ int lcnt[NB];
  __shared__ int lbase[NB];
  __shared__ int spart[256];
  const int tid = threadIdx.x;
  const int blk = blockIdx.x;
  const int e0 = blk * EPB;
  const int e1 = min(e0 + EPB, N_EDGES);

  for (int i = tid; i < NB; i += 256) lcnt[i] = 0;
  __syncthreads();

  for (int i = e0 + tid; i < e1; i += 256)
    atomicAdd(&lcnt[dst[i] >> 9], 1);
  __syncthreads();

  const int myv = (tid < NB) ? lcnt[tid] : 0;
  spart[tid] = myv;
  __syncthreads();
  for (int off = 1; off < 256; off <<= 1) {
    int u = (tid >= off) ? spart[tid - off] : 0;
    __syncthreads();
    spart[tid] += u;
    __syncthreads();
  }
  if (tid < NB) { lbase[tid] = spart[tid] - myv; lcnt[tid] = spart[tid] - myv; }
  __syncthreads();

  for (int i = e0 + tid; i < e1; i += 256) {
    const int d = dst[i];
    const int b = d >> 9;
    const int pos = atomicAdd(&lcnt[b], 1);
    stage[pos] = make_uint2((unsigned)src[i] | ((unsigned)(d & 511) << 17),
                            __float_as_uint(ew[i]));
    sbkt[pos] = (unsigned char)b;
  }
  __syncthreads();

  const int n = e1 - e0;
  for (int i = tid; i < n; i += 256) {
    const int b = sbkt[i];
    const int gpos = histG[b * NBLK + blk] + (i - lbase[b]);
    bucketed[gpos] = stage[i];
  }
}

// ---------------------------------------------------------------------------
// p2place block body: within-bucket counting sort -> CSR offsets + srcw.
// ---------------------------------------------------------------------------
__device__ __forceinline__ void p2place_block(
    int b, const uint2* __restrict__ bucketed, const int* __restrict__ histG,
    int* __restrict__ offsets, int2* __restrict__ srcw) {
  __shared__ int cnt[512];
  __shared__ int part[256];
  const int t = threadIdx.x;
  const int node0 = b << 9;
  const int beg = histG[b * NBLK];
  const int end = (b == NB - 1) ? N_EDGES : histG[(b + 1) * NBLK];

  cnt[t] = 0; cnt[t + 256] = 0;
  __syncthreads();

  for (int j = beg + t; j < end; j += 256)
    atomicAdd(&cnt[bucketed[j].x >> 17], 1);
  __syncthreads();

  const int a0 = cnt[2 * t];
  const int a1 = cnt[2 * t + 1];
  part[t] = a0 + a1;
  __syncthreads();
  for (int off = 1; off < 256; off <<= 1) {
    int v = (t >= off) ? part[t - off] : 0;
    __syncthreads();
    part[t] += v;
    __syncthreads();
  }
  const int base = (t > 0) ? part[t - 1] : 0;

  const int o0 = beg + base;
  const int o1 = o0 + a0;
  cnt[2 * t]     = o0;
  cnt[2 * t + 1] = o1;
  const int n0 = node0 + 2 * t;
  if (n0 < N_NODES)     offsets[n0]     = o0;
  if (n0 + 1 < N_NODES) offsets[n0 + 1] = o1;
  if (b == NB - 1 && t == 0) offsets[N_NODES] = N_EDGES;
  __syncthreads();

  for (int j = beg + t; j < end; j += 256) {
    const uint2 en = bucketed[j];
    const int slot = atomicAdd(&cnt[en.x >> 17], 1);
    srcw[slot] = make_int2((int)(en.x & 0x1FFFFu), (int)en.y);
  }
}

// Combo: blocks 0..195 = p2place, blocks 196.. = gemm0 (independent work
// overlapped in one dispatch; LDS 3KB + 17KB coexist fine).
__global__ __launch_bounds__(256) void place_gemm0_kernel(
    const uint2* __restrict__ bucketed, const int* __restrict__ histG,
    int* __restrict__ offsets, int2* __restrict__ srcw,
    const float* __restrict__ x, const uint4* __restrict__ w0f,
    unsigned char* __restrict__ h0) {
  if (blockIdx.x < NB) p2place_block(blockIdx.x, bucketed, histG, offsets, srcw);
  else                 gemm0_block(blockIdx.x - NB, x, w0f, h0);
}

// ---------------------------------------------------------------------------
// Fused gather0 + bias + ReLU + MFMA GEMM1 epilogue.
// h1 written SPLIT: h1a = feats 0-31 (64 B = 1 line/row), h1c = feats 32-39
// (16 B rows; 1.6 MB -> L2-resident for gather1). No zero padding stored.
// ---------------------------------------------------------------------------
#if USE_FP8_H0
__global__ __launch_bounds__(256) void gather0_gemm1_kernel(
    const uint4* __restrict__ h0q, const int2* __restrict__ srcw,
    const int* __restrict__ offsets, const float* __restrict__ b0,
    const uint4* __restrict__ w1f, unsigned short* __restrict__ h1a,
    unsigned short* __restrict__ h1c) {
  __shared__ float hs[4][132];
  const int wave = threadIdx.x >> 6;
  const int lane = threadIdx.x & 63;
  const int node = blockIdx.x * 4 + wave;
  const int g  = lane >> 3;         // edge slot 0..7 within an 8-edge group
  const int fl = lane & 7;          // feature chunk: feats [fl*16, fl*16+16)

  const int beg = __builtin_amdgcn_readfirstlane(offsets[node]);
  const int end = __builtin_amdgcn_readfirstlane(offsets[node + 1]);

  f32x2 acc[8];
#pragma unroll
  for (int i = 0; i < 8; ++i) acc[i] = (f32x2){0.f, 0.f};

  if (end > beg) {
    const int e1 = end - 1;
    int2 sa = srcw[min(beg + g, e1)];
    int2 sb = srcw[min(beg + 8 + g, e1)];
    for (int j = beg; j < end; j += 16) {
      const float wa = (j + g < end)     ? __int_as_float(sa.y) : 0.f;
      const float wb = (j + 8 + g < end) ? __int_as_float(sb.y) : 0.f;
      const uint4 va = h0q[(size_t)(unsigned)sa.x * 8 + fl];
      const uint4 vb = h0q[(size_t)(unsigned)sb.x * 8 + fl];
      const int jn = j + 16;
      if (jn < end) {                 // prefetch next groups' meta
        sa = srcw[min(jn + g, e1)];
        sb = srcw[min(jn + 8 + g, e1)];
      }
      const f32x2 pa = {wa, wa};
      const f32x2 pb = {wb, wb};
      FP8ACC(acc, va, pa)
      FP8ACC(acc, vb, pb)
    }
  }

  // reduce across the 8 edge-groups (lane bits 3,4,5)
#pragma unroll
  for (int i = 0; i < 8; ++i) {
    acc[i].x += __shfl_xor(acc[i].x, 8);
    acc[i].x += __shfl_xor(acc[i].x, 16);
    acc[i].x += __shfl_xor(acc[i].x, 32);
    acc[i].y += __shfl_xor(acc[i].y, 8);
    acc[i].y += __shfl_xor(acc[i].y, 16);
    acc[i].y += __shfl_xor(acc[i].y, 32);
  }

  // bias + ReLU, one eighth-wave (8 lanes) writes the 128-float row to LDS
  if (g == 0) {
    const int f0 = fl * 16;
#pragma unroll
    for (int jj = 0; jj < 4; ++jj) {
      const float v0 = acc[2 * jj].x     + b0[f0 + 4 * jj + 0];
      const float v1 = acc[2 * jj].y     + b0[f0 + 4 * jj + 1];
      const float v2 = acc[2 * jj + 1].x + b0[f0 + 4 * jj + 2];
      const float v3 = acc[2 * jj + 1].y + b0[f0 + 4 * jj + 3];
      *(float4*)&hs[wave][f0 + 4 * jj] = make_float4(
          v0 > 0.f ? v0 : 0.f, v1 > 0.f ? v1 : 0.f,
          v2 > 0.f ? v2 : 0.f, v3 > 0.f ? v3 : 0.f);
    }
  }
  __syncthreads();

  // --- MFMA epilogue: h1 = hs(4x128) @ W1(128x40), waves 0-2 = N-tiles ---
  const int l15 = lane & 15;
  const int gg  = lane >> 4;
  if (wave < 3) {
    f32x4 c = {0.f, 0.f, 0.f, 0.f};
#pragma unroll
    for (int qq = 0; qq < 4; ++qq) {
      uint4 ua = make_uint4(0, 0, 0, 0);
      if (l15 < 4) {                      // A rows 0-3 = this block's nodes
        const float* hrow = &hs[l15][qq * 32 + gg * 8];
        __hip_bfloat162 p;
        p.x = __float2bfloat16(hrow[0]); p.y = __float2bfloat16(hrow[1]);
        ua.x = *(unsigned int*)&p;
        p.x = __float2bfloat16(hrow[2]); p.y = __float2bfloat16(hrow[3]);
        ua.y = *(unsigned int*)&p;
        p.x = __float2bfloat16(hrow[4]); p.y = __float2bfloat16(hrow[5]);
        ua.z = *(unsigned int*)&p;
        p.x = __float2bfloat16(hrow[6]); p.y = __float2bfloat16(hrow[7]);
        ua.w = *(unsigned int*)&p;
      }
      const uint4 ub = w1f[(wave * 4 + qq) * 64 + lane];
      c = __builtin_amdgcn_mfma_f32_16x16x32_bf16(
            __builtin_bit_cast(bf16x8, ua), __builtin_bit_cast(bf16x8, ub),
            c, 0, 0, 0);
    }
    if (gg == 0) {
#pragma unroll
      for (int r = 0; r < 4; ++r) {
        const int nodeR = blockIdx.x * 4 + r;
        const int f = wave * 16 + l15;    // 0..47
        __hip_bfloat16 hb = __float2bfloat16(c[r]);
        const unsigned short v16 = *(unsigned short*)&hb;
        if (f < 32)              h1a[(size_t)nodeR * 32 + f] = v16;
        else if (f < OUT_FEATS)  h1c[(size_t)nodeR * 8 + (f - 32)] = v16;
      }
    }
  }
}
#else
// bf16 fallback: 16 lanes/edge, 4 edge-groups in flight.
__global__ __launch_bounds__(256) void gather0_gemm1_kernel(
    const uint4* __restrict__ h0q, const int2* __restrict__ srcw,
    const int* __restrict__ offsets, const float* __restrict__ b0,
    const uint4* __restrict__ w1f, unsigned short* __restrict__ h1a,
    unsigned short* __restrict__ h1c) {
  __shared__ float hs[4][132];
  const int wave = threadIdx.x >> 6;
  const int lane = threadIdx.x & 63;
  const int node = blockIdx.x * 4 + wave;
  const int q    = lane >> 4;
  const int fl   = lane & 15;

  const int beg = __builtin_amdgcn_readfirstlane(offsets[node]);
  const int end = __builtin_amdgcn_readfirstlane(offsets[node + 1]);

  f32x2 acc[4];
#pragma unroll
  for (int i = 0; i < 4; ++i) acc[i] = (f32x2){0.f, 0.f};

  if (end > beg) {
    const int e1 = end - 1;
    int2 sa = srcw[min(beg + q, e1)];
    int2 sb = srcw[min(beg + 4 + q, e1)];
    int2 sc = srcw[min(beg + 8 + q, e1)];
    int2 sd = srcw[min(beg + 12 + q, e1)];
    for (int j = beg; j < end; j += 16) {
      const float wa = (j + q < end)      ? __int_as_float(sa.y) : 0.f;
      const float wb = (j + 4 + q < end)  ? __int_as_float(sb.y) : 0.f;
      const float wc = (j + 8 + q < end)  ? __int_as_float(sc.y) : 0.f;
      const float wd = (j + 12 + q < end) ? __int_as_float(sd.y) : 0.f;
      const uint4 va = h0q[(size_t)(unsigned)sa.x * 16 + fl];
      const uint4 vb = h0q[(size_t)(unsigned)sb.x * 16 + fl];
      const uint4 vc = h0q[(size_t)(unsigned)sc.x * 16 + fl];
      const uint4 vd = h0q[(size_t)(unsigned)sd.x * 16 + fl];
      const int jn = j + 16;
      if (jn < end) {
        sa = srcw[min(jn + q, e1)];
        sb = srcw[min(jn + 4 + q, e1)];
        sc = srcw[min(jn + 8 + q, e1)];
        sd = srcw[min(jn + 12 + q, e1)];
      }
      const f32x2 pa = {wa, wa};
      const f32x2 pb = {wb, wb};
      const f32x2 pc = {wc, wc};
      const f32x2 pd = {wd, wd};
      ACC8P(acc, va, pa)
      ACC8P(acc, vb, pb)
      ACC8P(acc, vc, pc)
      ACC8P(acc, vd, pd)
    }
  }

#pragma unroll
  for (int i = 0; i < 4; ++i) {
    acc[i].x += __shfl_xor(acc[i].x, 16);
    acc[i].x += __shfl_xor(acc[i].x, 32);
    acc[i].y += __shfl_xor(acc[i].y, 16);
    acc[i].y += __shfl_xor(acc[i].y, 32);
  }

  if (q == 0) {
    const int f0 = fl * 8;
    float t[8];
#pragma unroll
    for (int i = 0; i < 8; ++i) {
      const float a = ((i & 1) ? acc[i >> 1].y : acc[i >> 1].x);
      const float v = a + b0[f0 + i];
      t[i] = v > 0.f ? v : 0.f;
    }
    *(float4*)&hs[wave][f0]     = make_float4(t[0], t[1], t[2], t[3]);
    *(float4*)&hs[wave][f0 + 4] = make_float4(t[4], t[5], t[6], t[7]);
  }
  __syncthreads();

  const int l15 = lane & 15;
  const int gg  = lane >> 4;
  if (wave < 3) {
    f32x4 c = {0.f, 0.f, 0.f, 0.f};
#pragma unroll
    for (int qq = 0; qq < 4; ++qq) {
      uint4 ua = make_uint4(0, 0, 0, 0);
      if (l15 < 4) {
        const float* hrow = &hs[l15][qq * 32 + gg * 8];
        __hip_bfloat162 p;
        p.x = __float2bfloat16(hrow[0]); p.y = __float2bfloat16(hrow[1]);
        ua.x = *(unsigned int*)&p;
        p.x = __float2bfloat16(hrow[2]); p.y = __float2bfloat16(hrow[3]);
        ua.y = *(unsigned int*)&p;
        p.x = __float2bfloat16(hrow[4]); p.y = __float2bfloat16(hrow[5]);
        ua.z = *(unsigned int*)&p;
        p.x = __float2bfloat16(hrow[6]); p.y = __float2bfloat16(hrow[7]);
        ua.w = *(unsigned int*)&p;
      }
      const uint4 ub = w1f[(wave * 4 + qq) * 64 + lane];
      c = __builtin_amdgcn_mfma_f32_16x16x32_bf16(
            __builtin_bit_cast(bf16x8, ua), __builtin_bit_cast(bf16x8, ub),
            c, 0, 0, 0);
    }
    if (gg == 0) {
#pragma unroll
      for (int r = 0; r < 4; ++r) {
        const int nodeR = blockIdx.x * 4 + r;
        const int f = wave * 16 + l15;
        __hip_bfloat16 hb = __float2bfloat16(c[r]);
        const unsigned short v16 = *(unsigned short*)&hb;
        if (f < 32)              h1a[(size_t)nodeR * 32 + f] = v16;
        else if (f < OUT_FEATS)  h1c[(size_t)nodeR * 8 + (f - 32)] = v16;
      }
    }
  }
}
#endif

// ---------------------------------------------------------------------------
// Fused gather1 + bias + log_softmax on SPLIT h1 with UNIFORM lane mapping:
// 4 lanes/edge; each lane loads 1 uint4 of h1a (8 feats) AND 1 dword of h1c
// (2 feats) -- no divergent side path (R8's mistake), no padding bytes.
// 16 edges per gather instr, 2 groups in flight (32 edges/iter).
// ---------------------------------------------------------------------------
__global__ __launch_bounds__(256) void gather1_lsm_kernel(
    const uint4* __restrict__ h1aq, const unsigned int* __restrict__ h1cd,
    const int2* __restrict__ srcw, const int* __restrict__ offsets,
    const float* __restrict__ b1, float* __restrict__ out) {
  const int wave = threadIdx.x >> 6;
  const int lane = threadIdx.x & 63;
  const int node = blockIdx.x * 4 + wave;
  const int g  = lane >> 2;         // edge slot 0..15 within a 16-edge group
  const int fl = lane & 3;          // feats [fl*8,fl*8+8) + [32+2fl,32+2fl+2)

  const int beg = __builtin_amdgcn_readfirstlane(offsets[node]);
  const int end = __builtin_amdgcn_readfirstlane(offsets[node + 1]);

  f32x2 acc[4];
  f32x2 accc = {0.f, 0.f};
#pragma unroll
  for (int i = 0; i < 4; ++i) acc[i] = (f32x2){0.f, 0.f};

  if (end > beg) {
    const int e1 = end - 1;
    int2 sa = srcw[min(beg + g, e1)];
    int2 sb = srcw[min(beg + 16 + g, e1)];
    for (int j = beg; j < end; j += 32) {
      const float wa = (j + g < end)      ? __int_as_float(sa.y) : 0.f;
      const float wb = (j + 16 + g < end) ? __int_as_float(sb.y) : 0.f;
      const uint4 va = h1aq[(size_t)(unsigned)sa.x * 4 + fl];
      const uint4 vb = h1aq[(size_t)(unsigned)sb.x * 4 + fl];
      const unsigned int ca = h1cd[(size_t)(unsigned)sa.x * 4 + fl];
      const unsigned int cb = h1cd[(size_t)(unsigned)sb.x * 4 + fl];
      const int jn = j + 32;
      if (jn < end) {
        sa = srcw[min(jn + g, e1)];
        sb = srcw[min(jn + 16 + g, e1)];
      }
      const f32x2 pa = {wa, wa};
      const f32x2 pb = {wb, wb};
      ACC8P(acc, va, pa)
      pkfma(accc, ca, pa);
      ACC8P(acc, vb, pb)
      pkfma(accc, cb, pb);
    }
  }

  // reduce across the 16 edge-groups (lane bits 2,3,4,5)
  float o[8], oc0, oc1;
#pragma unroll
  for (int i = 0; i < 4; ++i) {
    float x0 = acc[i].x, y0 = acc[i].y;
    x0 += __shfl_xor(x0, 4); x0 += __shfl_xor(x0, 8);
    x0 += __shfl_xor(x0, 16); x0 += __shfl_xor(x0, 32);
    y0 += __shfl_xor(y0, 4); y0 += __shfl_xor(y0, 8);
    y0 += __shfl_xor(y0, 16); y0 += __shfl_xor(y0, 32);
    o[2 * i] = x0; o[2 * i + 1] = y0;
  }
  {
    float x0 = accc.x, y0 = accc.y;
    x0 += __shfl_xor(x0, 4); x0 += __shfl_xor(x0, 8);
    x0 += __shfl_xor(x0, 16); x0 += __shfl_xor(x0, 32);
    y0 += __shfl_xor(y0, 4); y0 += __shfl_xor(y0, 8);
    y0 += __shfl_xor(y0, 16); y0 += __shfl_xor(y0, 32);
    oc0 = x0; oc1 = y0;
  }

  // bias + per-lane max over this lane's 10 feats
  const int f0 = fl * 8;
  float m = -INFINITY;
#pragma unroll
  for (int i = 0; i < 8; ++i) {
    o[i] += b1[f0 + i];
    m = fmaxf(m, o[i]);
  }
  oc0 += b1[32 + 2 * fl];
  oc1 += b1[33 + 2 * fl];
  m = fmaxf(m, oc0);
  m = fmaxf(m, oc1);
  m = fmaxf(m, __shfl_xor(m, 1));
  m = fmaxf(m, __shfl_xor(m, 2));

  float s = 0.f;
#pragma unroll
  for (int i = 0; i < 8; ++i) s += expf(o[i] - m);
  s += expf(oc0 - m) + expf(oc1 - m);
  s += __shfl_xor(s, 1);
  s += __shfl_xor(s, 2);

  if (lane < 4) {                   // g==0: lane fl writes its 10 feats
    const float lse = m + logf(s);
    float* op = out + (size_t)node * OUT_FEATS;
    *(float4*)(op + f0)     = make_float4(o[0] - lse, o[1] - lse,
                                          o[2] - lse, o[3] - lse);
    *(float4*)(op + f0 + 4) = make_float4(o[4] - lse, o[5] - lse,
                                          o[6] - lse, o[7] - lse);
    *(float2*)(op + 32 + 2 * fl) = make_float2(oc0 - lse, oc1 - lse);
  }
}

// ---------------------------------------------------------------------------
extern "C" void kernel_launch(void* const* d_in, const int* in_sizes, int n_in,
                              void* d_out, int out_size, void* d_ws, size_t ws_size,
                              hipStream_t stream) {
  const float* x   = (const float*)d_in[0];
  const float* W0  = (const float*)d_in[1];
  const float* b0  = (const float*)d_in[2];
  const float* W1  = (const float*)d_in[3];
  const float* b1  = (const float*)d_in[4];
  const float* ew  = (const float*)d_in[5];
  const int*   src = (const int*)d_in[6];
  const int*   dst = (const int*)d_in[7];
  float* out = (float*)d_out;

  // Workspace layout, peak ~85.6 MB (ws >= 102.4 MB):
  //   h0       [0,          25,600,000)   N*128 fp8 (12.8 MB used) or bf16
  //   srcw     [25,600,000, 51,200,000)   E int2, dst-sorted
  //   bucketed [51,200,000, 76,800,000)   E uint2, bucket-partitioned
  //   offsets  [76,800,000, 77,200,064)   N+1 int
  //   histG    [77,200,064, 77,506,624)   NB*NBLK int
  //   h1a      [77,506,624, 83,906,624)   N*32 bf16 (64 B rows, feats 0-31)
  //   h1c      [83,906,624, 85,506,624)   N*8  bf16 (16 B rows, feats 32-39)
  //   w1f      [85,506,624, 85,518,912)   768 uint4 (pre-swizzled W1 B-frags)
  //   w0f      [85,518,912, 85,584,448)   4096 uint4 (pre-swizzled W0 B-frags)
  //   bsum     [85,584,448, 85,585,232)   NB int (per-bucket edge totals)
  char* ws = (char*)d_ws;
  unsigned char* h0 = (unsigned char*)(ws);
  int2*  srcw     = (int2*)(ws + 25600000);
  uint2* bucketed = (uint2*)(ws + 51200000);
  int*   offsets  = (int*)(ws + 76800000);
  int*   histG    = (int*)(ws + 77200064);
  unsigned short* h1a = (unsigned short*)(ws + 77506624);
  unsigned short* h1c = (unsigned short*)(ws + 83906624);
  uint4* w1f      = (uint4*)(ws + 85506624);
  uint4* w0f      = (uint4*)(ws + 85518912);
  int*   bsum     = (int*)(ws + 85584448);

  hipMemsetAsync(bsum, 0, NB * sizeof(int), stream);
  p1hist_kernel<<<NBLK + 9, 256, 0, stream>>>(dst, histG, W1, w1f, W0, w0f, bsum);
  bscan_kernel<<<NB, 256, 0, stream>>>(bsum, histG);
  p1scatter_kernel<<<NBLK, 256, 0, stream>>>(src, dst, ew, histG, bucketed);
  // p2place (196 blocks) overlapped with gemm0 (1563 blocks): independent.
  place_gemm0_kernel<<<NB + G0BLKS, 256, 0, stream>>>(
      bucketed, histG, offsets, srcw, x, w0f, h0);
  gather0_gemm1_kernel<<<N_NODES / 4, 256, 0, stream>>>(
      (const uint4*)h0, srcw, offsets, b0, (const uint4*)w1f, h1a, h1c);
  gather1_lsm_kernel<<<N_NODES / 4, 256, 0, stream>>>(
      (const uint4*)h1a, (const unsigned int*)h1c, srcw, offsets, b1, out);
}

// Round 13
// 436.934 us; speedup vs baseline: 1.8228x; 1.0149x over previous
//
#include <hip/hip_runtime.h>
#include <hip/hip_bf16.h>
#include <cstdint>
#include <cstddef>

#define N_NODES   100000
#define N_EDGES   3200000
#define IN_FEATS  256
#define N_HIDDEN  128
#define OUT_FEATS 40

// Bucket partition: bucket = dst >> 9 (512 nodes/bucket)
#define NB        196
#define EPB       8192
#define NBLK      391
#define HIST_M    (NB * NBLK)
#define N_TILES   3125            // 100000 / 32
#define TPB       2               // gemm0 tiles per block
#define G0BLKS    ((N_TILES + TPB - 1) / TPB)   // 1563
#define STCAP     8960            // LDS stage capacity per half-bucket
                                  // (mean 8192, +8.5 sigma; guarded overflow)

// fp8 h0 path (R11, verified: -27 us): halves gather0 traffic + HW decode.
#if defined(__has_builtin)
#  if __has_builtin(__builtin_amdgcn_cvt_pk_f32_fp8) && \
      __has_builtin(__builtin_amdgcn_cvt_pk_fp8_f32)
#    define USE_FP8_H0 1
#  endif
#endif
#ifndef USE_FP8_H0
#  define USE_FP8_H0 0
#endif

typedef __attribute__((ext_vector_type(8))) __bf16 bf16x8;
typedef __attribute__((ext_vector_type(4))) float f32x4;
typedef __attribute__((ext_vector_type(2))) float f32x2;

// packed fp32 FMA: acc(2 feats) += unpack2_bf16(u) * w2 (contracts to pk_fma)
__device__ __forceinline__ void pkfma(f32x2& a, unsigned int u, f32x2 w2) {
  f32x2 b;
  b.x = __uint_as_float(u << 16);
  b.y = __uint_as_float(u & 0xFFFF0000u);
  a += b * w2;
}

// accumulate a uint4 (8 bf16 feats) into f32x2 A_[4]
#define ACC8P(A_, V_, W2_)   \
  pkfma(A_[0], (V_).x, W2_); \
  pkfma(A_[1], (V_).y, W2_); \
  pkfma(A_[2], (V_).z, W2_); \
  pkfma(A_[3], (V_).w, W2_);

#if USE_FP8_H0
// accumulate a uint4 (16 fp8 feats) into f32x2 A_[8] via HW cvt (1 op/2 feats)
#define FP8ACC(A_, V_, W2_) {                                          \
  f32x2 d_;                                                            \
  d_ = __builtin_amdgcn_cvt_pk_f32_fp8((V_).x, false); A_[0] += d_ * (W2_); \
  d_ = __builtin_amdgcn_cvt_pk_f32_fp8((V_).x, true ); A_[1] += d_ * (W2_); \
  d_ = __builtin_amdgcn_cvt_pk_f32_fp8((V_).y, false); A_[2] += d_ * (W2_); \
  d_ = __builtin_amdgcn_cvt_pk_f32_fp8((V_).y, true ); A_[3] += d_ * (W2_); \
  d_ = __builtin_amdgcn_cvt_pk_f32_fp8((V_).z, false); A_[4] += d_ * (W2_); \
  d_ = __builtin_amdgcn_cvt_pk_f32_fp8((V_).z, true ); A_[5] += d_ * (W2_); \
  d_ = __builtin_amdgcn_cvt_pk_f32_fp8((V_).w, false); A_[6] += d_ * (W2_); \
  d_ = __builtin_amdgcn_cvt_pk_f32_fp8((V_).w, true ); A_[7] += d_ * (W2_); }
#endif

// ---------------------------------------------------------------------------
// GEMM0 block body, 512-thread / 8-wave version. Each wave owns a 16-row x
// 32-col sub-tile (Bf[2][8], ~64 fewer VGPRs than the 4-wave version).
// h0 stored fp8 e4m3 (128 B rows) when available, else bf16.
// smem: uses first 32*264*2 = 16896 B of the shared union.
// ---------------------------------------------------------------------------
__device__ __forceinline__ void gemm0_block(
    int bid, const float* __restrict__ x, const uint4* __restrict__ w0f,
    unsigned char* __restrict__ h0, char* smem) {
  unsigned short* xb = (unsigned short*)smem;   // [32 * 264]
  const int tid  = threadIdx.x;    // 0..511
  const int lane = tid & 63;
  const int wave = tid >> 6;       // 0..7
  const int rb   = wave & 1;       // row half (16 rows)
  const int ch   = wave >> 1;      // col chunk 0..3 (32 cols each)
  const int l15  = lane & 15;
  const int g    = lane >> 4;

  bf16x8 Bf[2][8];
#pragma unroll
  for (int cb = 0; cb < 2; ++cb)
#pragma unroll
    for (int q = 0; q < 8; ++q)
      Bf[cb][q] = __builtin_bit_cast(bf16x8, w0f[((ch * 2 + cb) * 8 + q) * 64 + lane]);

  for (int t = 0; t < TPB; ++t) {
    const int tile = bid * TPB + t;
    if (tile >= N_TILES) break;
    const int row0 = tile * 32;
    __syncthreads();
    for (int i = tid; i < 32 * 128; i += 512) {
      const int row = i >> 7, kp = i & 127;
      const float2 v = *(const float2*)(x + (size_t)(row0 + row) * IN_FEATS + kp * 2);
      __hip_bfloat162 p;
      p.x = __float2bfloat16(v.x);
      p.y = __float2bfloat16(v.y);
      *(unsigned int*)&xb[row * 264 + kp * 2] = *(unsigned int*)&p;
    }
    __syncthreads();

    f32x4 acc[2];
#pragma unroll
    for (int cb = 0; cb < 2; ++cb) acc[cb] = (f32x4){0.f, 0.f, 0.f, 0.f};

#pragma unroll
    for (int q = 0; q < 8; ++q) {
      const bf16x8 a = *(const bf16x8*)&xb[(rb * 16 + l15) * 264 + q * 32 + g * 8];
      acc[0] = __builtin_amdgcn_mfma_f32_16x16x32_bf16(a, Bf[0][q], acc[0], 0, 0, 0);
      acc[1] = __builtin_amdgcn_mfma_f32_16x16x32_bf16(a, Bf[1][q], acc[1], 0, 0, 0);
    }

#pragma unroll
    for (int cb = 0; cb < 2; ++cb) {
      const int col = ch * 32 + cb * 16 + l15;
#pragma unroll
      for (int r = 0; r < 4; ++r) {
        const int row = row0 + rb * 16 + g * 4 + r;
#if USE_FP8_H0
        const int pk = __builtin_amdgcn_cvt_pk_fp8_f32(acc[cb][r], acc[cb][r], 0, false);
        h0[(size_t)row * N_HIDDEN + col] = (unsigned char)(pk & 0xFF);
#else
        __hip_bfloat16 hb = __float2bfloat16(acc[cb][r]);
        ((unsigned short*)h0)[(size_t)row * N_HIDDEN + col] = *(unsigned short*)&hb;
#endif
      }
    }
  }
}

// ---------------------------------------------------------------------------
// p2place v3 (512 threads): per-node counting sort of one 512-node bucket.
// Slots assigned by LDS atomics; edges staged node-sorted in LDS (two
// half-bucket passes, ~8.2K edges each) then written to srcw FULLY COALESCED
// (R12 counters: scattered 8B srcw stores caused 2x+ write amplification and
// a 4-wave latency-bound tail). Overflow past STCAP degrades gracefully.
// ---------------------------------------------------------------------------
__device__ __forceinline__ void p2place_block(
    int b, const uint2* __restrict__ bucketed, const int* __restrict__ histG,
    int* __restrict__ offsets, int2* __restrict__ srcw, char* smem) {
  int*   cnt   = (int*)smem;                 // 512 ints: counts -> cursors
  int*   part  = (int*)(smem + 2048);        // 512 ints: scan workspace
  int*   sb    = (int*)(smem + 4096);        // 4 ints
  uint2* stage = (uint2*)(smem + 4112);      // STCAP uint2
  const int t = threadIdx.x;                 // 0..511
  const int node0 = b << 9;
  const int beg = histG[b * NBLK];
  const int end = (b == NB - 1) ? N_EDGES : histG[(b + 1) * NBLK];

  cnt[t] = 0;
  __syncthreads();

  // pass A: per-local-node counts
  for (int j = beg + t; j < end; j += 512)
    atomicAdd(&cnt[bucketed[j].x >> 17], 1);
  __syncthreads();

  // inclusive scan over the 512 counts (Hillis-Steele)
  const int myv = cnt[t];
  part[t] = myv;
  __syncthreads();
  for (int off = 1; off < 512; off <<= 1) {
    int v = (t >= off) ? part[t - off] : 0;
    __syncthreads();
    part[t] += v;
    __syncthreads();
  }
  const int excl = part[t] - myv;            // bucket-local exclusive offset

  const int nd = node0 + t;
  if (nd < N_NODES) offsets[nd] = beg + excl;
  if (b == NB - 1 && t == 0) offsets[N_NODES] = N_EDGES;
  if (t == 255) sb[0] = part[255];           // edge count of half 0
  __syncthreads();
  const int h0cnt = sb[0];
  const int h1cnt = (end - beg) - h0cnt;

  cnt[t] = excl;                             // cursors (bucket-local)
  __syncthreads();

  // half 0 (nodes 0..255): stage node-sorted, then coalesced write-out
  for (int j = beg + t; j < end; j += 512) {
    const uint2 e = bucketed[j];
    const int ln = e.x >> 17;
    if (ln < 256) {
      const int pos = atomicAdd(&cnt[ln], 1);          // bucket-local slot
      if (pos < STCAP) stage[pos] = e;
      else srcw[beg + pos] = make_int2((int)(e.x & 0x1FFFFu), (int)e.y);
    }
  }
  __syncthreads();
  const int w0 = min(h0cnt, STCAP);
  for (int i = t; i < w0; i += 512) {
    const uint2 e = stage[i];
    srcw[beg + i] = make_int2((int)(e.x & 0x1FFFFu), (int)e.y);
  }
  __syncthreads();

  // half 1 (nodes 256..511)
  for (int j = beg + t; j < end; j += 512) {
    const uint2 e = bucketed[j];
    const int ln = e.x >> 17;
    if (ln >= 256) {
      const int pos = atomicAdd(&cnt[ln], 1);          // bucket-local slot
      const int ph = pos - h0cnt;                      // half-local
      if (ph < STCAP) stage[ph] = e;
      else srcw[beg + pos] = make_int2((int)(e.x & 0x1FFFFu), (int)e.y);
    }
  }
  __syncthreads();
  const int w1 = min(h1cnt, STCAP);
  for (int i = t; i < w1; i += 512) {
    const uint2 e = stage[i];
    srcw[beg + h0cnt + i] = make_int2((int)(e.x & 0x1FFFFu), (int)e.y);
  }
}

// Combo (512 threads): blocks 0..195 = p2place v3, blocks 196.. = gemm0.
// Shared-memory UNION (75.8 KB) -> 2 blocks/CU for both branches.
__global__ __launch_bounds__(512) void place_gemm0_kernel(
    const uint2* __restrict__ bucketed, const int* __restrict__ histG,
    int* __restrict__ offsets, int2* __restrict__ srcw,
    const float* __restrict__ x, const uint4* __restrict__ w0f,
    unsigned char* __restrict__ h0) {
  __shared__ __align__(16) char smem[4112 + STCAP * 8];
  if (blockIdx.x < NB)
    p2place_block(blockIdx.x, bucketed, histG, offsets, srcw, smem);
  else
    gemm0_block(blockIdx.x - NB, x, w0f, h0, smem);
}

// ---------------------------------------------------------------------------
// Parallel 2-level scan: block b computes bucket b's base by reducing
// bsum[0..b-1] (L2-hit), then pair-scans its own 391 contiguous entries.
// ---------------------------------------------------------------------------
__global__ __launch_bounds__(256) void bscan_kernel(
    const int* __restrict__ bsum, int* __restrict__ histG) {
  __shared__ int sh[256];
  __shared__ int pr[256];
  const int b = blockIdx.x;
  const int t = threadIdx.x;

  sh[t] = (t < b) ? bsum[t] : 0;          // b <= 195 < 256
  __syncthreads();
#pragma unroll
  for (int off = 128; off > 0; off >>= 1) {
    if (t < off) sh[t] += sh[t + off];
    __syncthreads();
  }
  const int base = sh[0];

  const int row = b * NBLK;
  const int i0 = 2 * t, i1 = 2 * t + 1;
  int a = 0, c = 0;
  if (t < 196) {
    a = histG[row + i0];                  // i0 <= 390
    if (i1 < NBLK) c = histG[row + i1];
  }
  pr[t] = a + c;
  __syncthreads();
  for (int off = 1; off < 256; off <<= 1) {
    int v = (t >= off) ? pr[t - off] : 0;
    __syncthreads();
    pr[t] += v;
    __syncthreads();
  }
  if (t < 196) {
    const int ebase = (t > 0) ? pr[t - 1] : 0;
    histG[row + i0] = base + ebase;
    if (i1 < NBLK) histG[row + i1] = base + ebase + a;
  }
}

// ---------------------------------------------------------------------------
// p1hist: blocks 0..NBLK-1 = histogram (+ bsum accumulate);
// block NBLK = W1 pre-swizzle; blocks NBLK+1..NBLK+8 = W0 pre-swizzle.
// ---------------------------------------------------------------------------
__global__ __launch_bounds__(256) void p1hist_kernel(
    const int* __restrict__ dst, int* __restrict__ histG,
    const float* __restrict__ W1, uint4* __restrict__ w1f,
    const float* __restrict__ W0, uint4* __restrict__ w0f,
    int* __restrict__ bsum) {
  const int tid = threadIdx.x;
  const int blk = blockIdx.x;

  if (blk >= NBLK) {
    if (blk == NBLK) {                    // W1 fragment converter (40 cols, pad)
      for (int t = tid; t < 3 * 4 * 64; t += 256) {
        const int ln  = t & 63;
        const int qq  = (t >> 6) & 3;
        const int nt  = t >> 8;
        const int l15 = ln & 15;
        const int gg  = ln >> 4;
        const int c   = nt * 16 + l15;
        const int k0  = qq * 32 + gg * 8;
        uint4 u;
        __hip_bfloat162 p;
#define W1AT(i_) ((c < OUT_FEATS) ? W1[(size_t)(k0 + (i_)) * OUT_FEATS + c] : 0.f)
        p.x = __float2bfloat16(W1AT(0)); p.y = __float2bfloat16(W1AT(1));
        u.x = *(unsigned int*)&p;
        p.x = __float2bfloat16(W1AT(2)); p.y = __float2bfloat16(W1AT(3));
        u.y = *(unsigned int*)&p;
        p.x = __float2bfloat16(W1AT(4)); p.y = __float2bfloat16(W1AT(5));
        u.z = *(unsigned int*)&p;
        p.x = __float2bfloat16(W1AT(6)); p.y = __float2bfloat16(W1AT(7));
        u.w = *(unsigned int*)&p;
#undef W1AT
        w1f[t] = u;
      }
    } else {                              // W0 fragment converter (128 cols)
      const int pb = blk - NBLK - 1;      // 0..7
      for (int fi = pb * 512 + tid; fi < pb * 512 + 512; fi += 256) {
        const int ln  = fi & 63;
        const int qq  = (fi >> 6) & 7;
        const int ct  = fi >> 9;
        const int col = ct * 16 + (ln & 15);
        const int k0  = qq * 32 + (ln >> 4) * 8;
        uint4 u;
        __hip_bfloat162 p;
        p.x = __float2bfloat16(W0[(size_t)(k0 + 0) * N_HIDDEN + col]);
        p.y = __float2bfloat16(W0[(size_t)(k0 + 1) * N_HIDDEN + col]);
        u.x = *(unsigned int*)&p;
        p.x = __float2bfloat16(W0[(size_t)(k0 + 2) * N_HIDDEN + col]);
        p.y = __float2bfloat16(W0[(size_t)(k0 + 3) * N_HIDDEN + col]);
        u.y = *(unsigned int*)&p;
        p.x = __float2bfloat16(W0[(size_t)(k0 + 4) * N_HIDDEN + col]);
        p.y = __float2bfloat16(W0[(size_t)(k0 + 5) * N_HIDDEN + col]);
        u.z = *(unsigned int*)&p;
        p.x = __float2bfloat16(W0[(size_t)(k0 + 6) * N_HIDDEN + col]);
        p.y = __float2bfloat16(W0[(size_t)(k0 + 7) * N_HIDDEN + col]);
        u.w = *(unsigned int*)&p;
        w0f[fi] = u;
      }
    }
    return;
  }

  __shared__ int lh[NB];
  for (int i = tid; i < NB; i += 256) lh[i] = 0;
  __syncthreads();

  const int e0 = blk * EPB;
  const int e1 = min(e0 + EPB, N_EDGES);
  for (int i = e0 + tid; i < e1; i += 256)
    atomicAdd(&lh[dst[i] >> 9], 1);
  __syncthreads();

  for (int i = tid; i < NB; i += 256) {
    histG[i * NBLK + blk] = lh[i];
    atomicAdd(&bsum[i], lh[i]);
  }
}

// ---------------------------------------------------------------------------
// p1scatter: LDS-staged, bucket-contiguous global writes (R7 lesson: direct
// node-level scatter = 7.7x write amplification + cross-XCD atomic bounce).
// ---------------------------------------------------------------------------
__global__ __launch_bounds__(256) void p1scatter_kernel(
    const int* __restrict__ src, const int* __restrict__ dst,
    const float* __restrict__ ew, const int* __restrict__ histG,
    uint2* __restrict__ bucketed) {
  __shared__ uint2 stage[EPB];          // 64 KB
  __shared__ unsigned char sbkt[EPB];   // 8 KB
  __shared__ int lcnt[NB];
  __shared__ int lbase[NB];
  __shared__ int spart[256];
  const int tid = threadIdx.x;
  const int blk = blockIdx.x;
  const int e0 = blk * EPB;
  const int e1 = min(e0 + EPB, N_EDGES);

  for (int i = tid; i < NB; i += 256) lcnt[i] = 0;
  __syncthreads();

  for (int i = e0 + tid; i < e1; i += 256)
    atomicAdd(&lcnt[dst[i] >> 9], 1);
  __syncthreads();

  const int myv = (tid < NB) ? lcnt[tid] : 0;
  spart[tid] = myv;
  __syncthreads();
  for (int off = 1; off < 256; off <<= 1) {
    int u = (tid >= off) ? spart[tid - off] : 0;
    __syncthreads();
    spart[tid] += u;
    __syncthreads();
  }
  if (tid < NB) { lbase[tid] = spart[tid] - myv; lcnt[tid] = spart[tid] - myv; }
  __syncthreads();

  for (int i = e0 + tid; i < e1; i += 256) {
    const int d = dst[i];
    const int b = d >> 9;
    const int pos = atomicAdd(&lcnt[b], 1);
    stage[pos] = make_uint2((unsigned)src[i] | ((unsigned)(d & 511) << 17),
                            __float_as_uint(ew[i]));
    sbkt[pos] = (unsigned char)b;
  }
  __syncthreads();

  const int n = e1 - e0;
  for (int i = tid; i < n; i += 256) {
    const int b = sbkt[i];
    const int gpos = histG[b * NBLK + blk] + (i - lbase[b]);
    bucketed[gpos] = stage[i];
  }
}

// ---------------------------------------------------------------------------
// Fused gather0 + bias + ReLU + MFMA GEMM1 epilogue.
// h1 written SPLIT: h1a = feats 0-31 (64 B = 1 line/row), h1c = feats 32-39
// (16 B rows; 1.6 MB -> L2-resident for gather1). No zero padding stored.
// ---------------------------------------------------------------------------
#if USE_FP8_H0
__global__ __launch_bounds__(256) void gather0_gemm1_kernel(
    const uint4* __restrict__ h0q, const int2* __restrict__ srcw,
    const int* __restrict__ offsets, const float* __restrict__ b0,
    const uint4* __restrict__ w1f, unsigned short* __restrict__ h1a,
    unsigned short* __restrict__ h1c) {
  __shared__ float hs[4][132];
  const int wave = threadIdx.x >> 6;
  const int lane = threadIdx.x & 63;
  const int node = blockIdx.x * 4 + wave;
  const int g  = lane >> 3;         // edge slot 0..7 within an 8-edge group
  const int fl = lane & 7;          // feature chunk: feats [fl*16, fl*16+16)

  const int beg = __builtin_amdgcn_readfirstlane(offsets[node]);
  const int end = __builtin_amdgcn_readfirstlane(offsets[node + 1]);

  f32x2 acc[8];
#pragma unroll
  for (int i = 0; i < 8; ++i) acc[i] = (f32x2){0.f, 0.f};

  if (end > beg) {
    const int e1 = end - 1;
    int2 sa = srcw[min(beg + g, e1)];
    int2 sb = srcw[min(beg + 8 + g, e1)];
    for (int j = beg; j < end; j += 16) {
      const float wa = (j + g < end)     ? __int_as_float(sa.y) : 0.f;
      const float wb = (j + 8 + g < end) ? __int_as_float(sb.y) : 0.f;
      const uint4 va = h0q[(size_t)(unsigned)sa.x * 8 + fl];
      const uint4 vb = h0q[(size_t)(unsigned)sb.x * 8 + fl];
      const int jn = j + 16;
      if (jn < end) {                 // prefetch next groups' meta
        sa = srcw[min(jn + g, e1)];
        sb = srcw[min(jn + 8 + g, e1)];
      }
      const f32x2 pa = {wa, wa};
      const f32x2 pb = {wb, wb};
      FP8ACC(acc, va, pa)
      FP8ACC(acc, vb, pb)
    }
  }

  // reduce across the 8 edge-groups (lane bits 3,4,5)
#pragma unroll
  for (int i = 0; i < 8; ++i) {
    acc[i].x += __shfl_xor(acc[i].x, 8);
    acc[i].x += __shfl_xor(acc[i].x, 16);
    acc[i].x += __shfl_xor(acc[i].x, 32);
    acc[i].y += __shfl_xor(acc[i].y, 8);
    acc[i].y += __shfl_xor(acc[i].y, 16);
    acc[i].y += __shfl_xor(acc[i].y, 32);
  }

  // bias + ReLU, one eighth-wave (8 lanes) writes the 128-float row to LDS
  if (g == 0) {
    const int f0 = fl * 16;
#pragma unroll
    for (int jj = 0; jj < 4; ++jj) {
      const float v0 = acc[2 * jj].x     + b0[f0 + 4 * jj + 0];
      const float v1 = acc[2 * jj].y     + b0[f0 + 4 * jj + 1];
      const float v2 = acc[2 * jj + 1].x + b0[f0 + 4 * jj + 2];
      const float v3 = acc[2 * jj + 1].y + b0[f0 + 4 * jj + 3];
      *(float4*)&hs[wave][f0 + 4 * jj] = make_float4(
          v0 > 0.f ? v0 : 0.f, v1 > 0.f ? v1 : 0.f,
          v2 > 0.f ? v2 : 0.f, v3 > 0.f ? v3 : 0.f);
    }
  }
  __syncthreads();

  // --- MFMA epilogue: h1 = hs(4x128) @ W1(128x40), waves 0-2 = N-tiles ---
  const int l15 = lane & 15;
  const int gg  = lane >> 4;
  if (wave < 3) {
    f32x4 c = {0.f, 0.f, 0.f, 0.f};
#pragma unroll
    for (int qq = 0; qq < 4; ++qq) {
      uint4 ua = make_uint4(0, 0, 0, 0);
      if (l15 < 4) {                      // A rows 0-3 = this block's nodes
        const float* hrow = &hs[l15][qq * 32 + gg * 8];
        __hip_bfloat162 p;
        p.x = __float2bfloat16(hrow[0]); p.y = __float2bfloat16(hrow[1]);
        ua.x = *(unsigned int*)&p;
        p.x = __float2bfloat16(hrow[2]); p.y = __float2bfloat16(hrow[3]);
        ua.y = *(unsigned int*)&p;
        p.x = __float2bfloat16(hrow[4]); p.y = __float2bfloat16(hrow[5]);
        ua.z = *(unsigned int*)&p;
        p.x = __float2bfloat16(hrow[6]); p.y = __float2bfloat16(hrow[7]);
        ua.w = *(unsigned int*)&p;
      }
      const uint4 ub = w1f[(wave * 4 + qq) * 64 + lane];
      c = __builtin_amdgcn_mfma_f32_16x16x32_bf16(
            __builtin_bit_cast(bf16x8, ua), __builtin_bit_cast(bf16x8, ub),
            c, 0, 0, 0);
    }
    if (gg == 0) {
#pragma unroll
      for (int r = 0; r < 4; ++r) {
        const int nodeR = blockIdx.x * 4 + r;
        const int f = wave * 16 + l15;    // 0..47
        __hip_bfloat16 hb = __float2bfloat16(c[r]);
        const unsigned short v16 = *(unsigned short*)&hb;
        if (f < 32)              h1a[(size_t)nodeR * 32 + f] = v16;
        else if (f < OUT_FEATS)  h1c[(size_t)nodeR * 8 + (f - 32)] = v16;
      }
    }
  }
}
#else
// bf16 fallback: 16 lanes/edge, 4 edge-groups in flight.
__global__ __launch_bounds__(256) void gather0_gemm1_kernel(
    const uint4* __restrict__ h0q, const int2* __restrict__ srcw,
    const int* __restrict__ offsets, const float* __restrict__ b0,
    const uint4* __restrict__ w1f, unsigned short* __restrict__ h1a,
    unsigned short* __restrict__ h1c) {
  __shared__ float hs[4][132];
  const int wave = threadIdx.x >> 6;
  const int lane = threadIdx.x & 63;
  const int node = blockIdx.x * 4 + wave;
  const int q    = lane >> 4;
  const int fl   = lane & 15;

  const int beg = __builtin_amdgcn_readfirstlane(offsets[node]);
  const int end = __builtin_amdgcn_readfirstlane(offsets[node + 1]);

  f32x2 acc[4];
#pragma unroll
  for (int i = 0; i < 4; ++i) acc[i] = (f32x2){0.f, 0.f};

  if (end > beg) {
    const int e1 = end - 1;
    int2 sa = srcw[min(beg + q, e1)];
    int2 sb = srcw[min(beg + 4 + q, e1)];
    int2 sc = srcw[min(beg + 8 + q, e1)];
    int2 sd = srcw[min(beg + 12 + q, e1)];
    for (int j = beg; j < end; j += 16) {
      const float wa = (j + q < end)      ? __int_as_float(sa.y) : 0.f;
      const float wb = (j + 4 + q < end)  ? __int_as_float(sb.y) : 0.f;
      const float wc = (j + 8 + q < end)  ? __int_as_float(sc.y) : 0.f;
      const float wd = (j + 12 + q < end) ? __int_as_float(sd.y) : 0.f;
      const uint4 va = h0q[(size_t)(unsigned)sa.x * 16 + fl];
      const uint4 vb = h0q[(size_t)(unsigned)sb.x * 16 + fl];
      const uint4 vc = h0q[(size_t)(unsigned)sc.x * 16 + fl];
      const uint4 vd = h0q[(size_t)(unsigned)sd.x * 16 + fl];
      const int jn = j + 16;
      if (jn < end) {
        sa = srcw[min(jn + q, e1)];
        sb = srcw[min(jn + 4 + q, e1)];
        sc = srcw[min(jn + 8 + q, e1)];
        sd = srcw[min(jn + 12 + q, e1)];
      }
      const f32x2 pa = {wa, wa};
      const f32x2 pb = {wb, wb};
      const f32x2 pc = {wc, wc};
      const f32x2 pd = {wd, wd};
      ACC8P(acc, va, pa)
      ACC8P(acc, vb, pb)
      ACC8P(acc, vc, pc)
      ACC8P(acc, vd, pd)
    }
  }

#pragma unroll
  for (int i = 0; i < 4; ++i) {
    acc[i].x += __shfl_xor(acc[i].x, 16);
    acc[i].x += __shfl_xor(acc[i].x, 32);
    acc[i].y += __shfl_xor(acc[i].y, 16);
    acc[i].y += __shfl_xor(acc[i].y, 32);
  }

  if (q == 0) {
    const int f0 = fl * 8;
    float t[8];
#pragma unroll
    for (int i = 0; i < 8; ++i) {
      const float a = ((i & 1) ? acc[i >> 1].y : acc[i >> 1].x);
      const float v = a + b0[f0 + i];
      t[i] = v > 0.f ? v : 0.f;
    }
    *(float4*)&hs[wave][f0]     = make_float4(t[0], t[1], t[2], t[3]);
    *(float4*)&hs[wave][f0 + 4] = make_float4(t[4], t[5], t[6], t[7]);
  }
  __syncthreads();

  const int l15 = lane & 15;
  const int gg  = lane >> 4;
  if (wave < 3) {
    f32x4 c = {0.f, 0.f, 0.f, 0.f};
#pragma unroll
    for (int qq = 0; qq < 4; ++qq) {
      uint4 ua = make_uint4(0, 0, 0, 0);
      if (l15 < 4) {
        const float* hrow = &hs[l15][qq * 32 + gg * 8];
        __hip_bfloat162 p;
        p.x = __float2bfloat16(hrow[0]); p.y = __float2bfloat16(hrow[1]);
        ua.x = *(unsigned int*)&p;
        p.x = __float2bfloat16(hrow[2]); p.y = __float2bfloat16(hrow[3]);
        ua.y = *(unsigned int*)&p;
        p.x = __float2bfloat16(hrow[4]); p.y = __float2bfloat16(hrow[5]);
        ua.z = *(unsigned int*)&p;
        p.x = __float2bfloat16(hrow[6]); p.y = __float2bfloat16(hrow[7]);
        ua.w = *(unsigned int*)&p;
      }
      const uint4 ub = w1f[(wave * 4 + qq) * 64 + lane];
      c = __builtin_amdgcn_mfma_f32_16x16x32_bf16(
            __builtin_bit_cast(bf16x8, ua), __builtin_bit_cast(bf16x8, ub),
            c, 0, 0, 0);
    }
    if (gg == 0) {
#pragma unroll
      for (int r = 0; r < 4; ++r) {
        const int nodeR = blockIdx.x * 4 + r;
        const int f = wave * 16 + l15;
        __hip_bfloat16 hb = __float2bfloat16(c[r]);
        const unsigned short v16 = *(unsigned short*)&hb;
        if (f < 32)              h1a[(size_t)nodeR * 32 + f] = v16;
        else if (f < OUT_FEATS)  h1c[(size_t)nodeR * 8 + (f - 32)] = v16;
      }
    }
  }
}
#endif

// ---------------------------------------------------------------------------
// Fused gather1 + bias + log_softmax on SPLIT h1 with UNIFORM lane mapping:
// 4 lanes/edge; each lane loads 1 uint4 of h1a (8 feats) AND 1 dword of h1c
// (2 feats) -- no divergent side path, no padding bytes.
// ---------------------------------------------------------------------------
__global__ __launch_bounds__(256) void gather1_lsm_kernel(
    const uint4* __restrict__ h1aq, const unsigned int* __restrict__ h1cd,
    const int2* __restrict__ srcw, const int* __restrict__ offsets,
    const float* __restrict__ b1, float* __restrict__ out) {
  const int wave = threadIdx.x >> 6;
  const int lane = threadIdx.x & 63;
  const int node = blockIdx.x * 4 + wave;
  const int g  = lane >> 2;         // edge slot 0..15 within a 16-edge group
  const int fl = lane & 3;          // feats [fl*8,fl*8+8) + [32+2fl,32+2fl+2)

  const int beg = __builtin_amdgcn_readfirstlane(offsets[node]);
  const int end = __builtin_amdgcn_readfirstlane(offsets[node + 1]);

  f32x2 acc[4];
  f32x2 accc = {0.f, 0.f};
#pragma unroll
  for (int i = 0; i < 4; ++i) acc[i] = (f32x2){0.f, 0.f};

  if (end > beg) {
    const int e1 = end - 1;
    int2 sa = srcw[min(beg + g, e1)];
    int2 sb = srcw[min(beg + 16 + g, e1)];
    for (int j = beg; j < end; j += 32) {
      const float wa = (j + g < end)      ? __int_as_float(sa.y) : 0.f;
      const float wb = (j + 16 + g < end) ? __int_as_float(sb.y) : 0.f;
      const uint4 va = h1aq[(size_t)(unsigned)sa.x * 4 + fl];
      const uint4 vb = h1aq[(size_t)(unsigned)sb.x * 4 + fl];
      const unsigned int ca = h1cd[(size_t)(unsigned)sa.x * 4 + fl];
      const unsigned int cb = h1cd[(size_t)(unsigned)sb.x * 4 + fl];
      const int jn = j + 32;
      if (jn < end) {
        sa = srcw[min(jn + g, e1)];
        sb = srcw[min(jn + 16 + g, e1)];
      }
      const f32x2 pa = {wa, wa};
      const f32x2 pb = {wb, wb};
      ACC8P(acc, va, pa)
      pkfma(accc, ca, pa);
      ACC8P(acc, vb, pb)
      pkfma(accc, cb, pb);
    }
  }

  // reduce across the 16 edge-groups (lane bits 2,3,4,5)
  float o[8], oc0, oc1;
#pragma unroll
  for (int i = 0; i < 4; ++i) {
    float x0 = acc[i].x, y0 = acc[i].y;
    x0 += __shfl_xor(x0, 4); x0 += __shfl_xor(x0, 8);
    x0 += __shfl_xor(x0, 16); x0 += __shfl_xor(x0, 32);
    y0 += __shfl_xor(y0, 4); y0 += __shfl_xor(y0, 8);
    y0 += __shfl_xor(y0, 16); y0 += __shfl_xor(y0, 32);
    o[2 * i] = x0; o[2 * i + 1] = y0;
  }
  {
    float x0 = accc.x, y0 = accc.y;
    x0 += __shfl_xor(x0, 4); x0 += __shfl_xor(x0, 8);
    x0 += __shfl_xor(x0, 16); x0 += __shfl_xor(x0, 32);
    y0 += __shfl_xor(y0, 4); y0 += __shfl_xor(y0, 8);
    y0 += __shfl_xor(y0, 16); y0 += __shfl_xor(y0, 32);
    oc0 = x0; oc1 = y0;
  }

  // bias + per-lane max over this lane's 10 feats
  const int f0 = fl * 8;
  float m = -INFINITY;
#pragma unroll
  for (int i = 0; i < 8; ++i) {
    o[i] += b1[f0 + i];
    m = fmaxf(m, o[i]);
  }
  oc0 += b1[32 + 2 * fl];
  oc1 += b1[33 + 2 * fl];
  m = fmaxf(m, oc0);
  m = fmaxf(m, oc1);
  m = fmaxf(m, __shfl_xor(m, 1));
  m = fmaxf(m, __shfl_xor(m, 2));

  float s = 0.f;
#pragma unroll
  for (int i = 0; i < 8; ++i) s += expf(o[i] - m);
  s += expf(oc0 - m) + expf(oc1 - m);
  s += __shfl_xor(s, 1);
  s += __shfl_xor(s, 2);

  if (lane < 4) {                   // g==0: lane fl writes its 10 feats
    const float lse = m + logf(s);
    float* op = out + (size_t)node * OUT_FEATS;
    *(float4*)(op + f0)     = make_float4(o[0] - lse, o[1] - lse,
                                          o[2] - lse, o[3] - lse);
    *(float4*)(op + f0 + 4) = make_float4(o[4] - lse, o[5] - lse,
                                          o[6] - lse, o[7] - lse);
    *(float2*)(op + 32 + 2 * fl) = make_float2(oc0 - lse, oc1 - lse);
  }
}

// ---------------------------------------------------------------------------
extern "C" void kernel_launch(void* const* d_in, const int* in_sizes, int n_in,
                              void* d_out, int out_size, void* d_ws, size_t ws_size,
                              hipStream_t stream) {
  const float* x   = (const float*)d_in[0];
  const float* W0  = (const float*)d_in[1];
  const float* b0  = (const float*)d_in[2];
  const float* W1  = (const float*)d_in[3];
  const float* b1  = (const float*)d_in[4];
  const float* ew  = (const float*)d_in[5];
  const int*   src = (const int*)d_in[6];
  const int*   dst = (const int*)d_in[7];
  float* out = (float*)d_out;

  // Workspace layout, peak ~85.6 MB (ws >= 102.4 MB):
  //   h0       [0,          25,600,000)   N*128 fp8 (12.8 MB used) or bf16
  //   srcw     [25,600,000, 51,200,000)   E int2, dst-sorted
  //   bucketed [51,200,000, 76,800,000)   E uint2, bucket-partitioned
  //   offsets  [76,800,000, 77,200,064)   N+1 int
  //   histG    [77,200,064, 77,506,624)   NB*NBLK int
  //   h1a      [77,506,624, 83,906,624)   N*32 bf16 (64 B rows, feats 0-31)
  //   h1c      [83,906,624, 85,506,624)   N*8  bf16 (16 B rows, feats 32-39)
  //   w1f      [85,506,624, 85,518,912)   768 uint4 (pre-swizzled W1 B-frags)
  //   w0f      [85,518,912, 85,584,448)   4096 uint4 (pre-swizzled W0 B-frags)
  //   bsum     [85,584,448, 85,585,232)   NB int (per-bucket edge totals)
  char* ws = (char*)d_ws;
  unsigned char* h0 = (unsigned char*)(ws);
  int2*  srcw     = (int2*)(ws + 25600000);
  uint2* bucketed = (uint2*)(ws + 51200000);
  int*   offsets  = (int*)(ws + 76800000);
  int*   histG    = (int*)(ws + 77200064);
  unsigned short* h1a = (unsigned short*)(ws + 77506624);
  unsigned short* h1c = (unsigned short*)(ws + 83906624);
  uint4* w1f      = (uint4*)(ws + 85506624);
  uint4* w0f      = (uint4*)(ws + 85518912);
  int*   bsum     = (int*)(ws + 85584448);

  hipMemsetAsync(bsum, 0, NB * sizeof(int), stream);
  p1hist_kernel<<<NBLK + 9, 256, 0, stream>>>(dst, histG, W1, w1f, W0, w0f, bsum);
  bscan_kernel<<<NB, 256, 0, stream>>>(bsum, histG);
  p1scatter_kernel<<<NBLK, 256, 0, stream>>>(src, dst, ew, histG, bucketed);
  // p2place v3 (196 blocks, LDS-staged coalesced) overlapped with gemm0.
  place_gemm0_kernel<<<NB + G0BLKS, 512, 0, stream>>>(
      bucketed, histG, offsets, srcw, x, w0f, h0);
  gather0_gemm1_kernel<<<N_NODES / 4, 256, 0, stream>>>(
      (const uint4*)h0, srcw, offsets, b0, (const uint4*)w1f, h1a, h1c);
  gather1_lsm_kernel<<<N_NODES / 4, 256, 0, stream>>>(
      (const uint4*)h1a, (const unsigned int*)h1c, srcw, offsets, b1, out);
}